// Round 7
// baseline (348.579 us; speedup 1.0000x reference)
//
#include <hip/hip_runtime.h>
#include <stdint.h>

#define L1C 256
#define L2C 320
#define BC  64
#define DC  1024

typedef __bf16 bf16_t;
typedef __bf16 bf16x8 __attribute__((ext_vector_type(8)));
typedef __bf16 bf16x4 __attribute__((ext_vector_type(4)));
typedef float  f32x4  __attribute__((ext_vector_type(4)));

__device__ __forceinline__ void gload16(const void* g, void* l) {
  __builtin_amdgcn_global_load_lds(
      (__attribute__((address_space(1))) void*)g,
      (__attribute__((address_space(3))) void*)l, 16, 0, 0);
}

__device__ __forceinline__ bf16x8 cvt8(f32x4 a, f32x4 b) {
  return bf16x8{ (bf16_t)a[0], (bf16_t)a[1], (bf16_t)a[2], (bf16_t)a[3],
                 (bf16_t)b[0], (bf16_t)b[1], (bf16_t)b[2], (bf16_t)b[3] };
}

// ---------------- fp32 -> bf16 convert (weights only) ----------------
__global__ __launch_bounds__(256)
void conv_kernel(const float* __restrict__ src, bf16_t* __restrict__ dst, int n4) {
  int i = blockIdx.x * 256 + threadIdx.x;
  const int stride = gridDim.x * 256;
  for (; i < n4; i += stride) {
    float4 v = ((const float4*)src)[i];
    bf16x4 o = { (__bf16)v.x, (__bf16)v.y, (__bf16)v.z, (__bf16)v.w };
    ((bf16x4*)dst)[i] = o;
  }
}

// ---------------- transpose W2 (fp32 1024x1024) -> bf16 W2T ----------------
__global__ __launch_bounds__(256)
void w2t_kernel(const float* __restrict__ W2, bf16_t* __restrict__ W2T) {
  __shared__ float tile[32][33];
  const int tx = threadIdx.x & 31, ty = threadIdx.x >> 5;  // 32 x 8
  const int x0 = blockIdx.x * 32, y0 = blockIdx.y * 32;
#pragma unroll
  for (int k = 0; k < 32; k += 8)
    tile[ty + k][tx] = W2[(size_t)(y0 + ty + k) * 1024 + x0 + tx];
  __syncthreads();
#pragma unroll
  for (int k = 0; k < 32; k += 8)
    W2T[(size_t)(x0 + ty + k) * 1024 + y0 + tx] = (bf16_t)tile[tx][ty + k];
}

// ---------------- w2b[d] = sum_k W2[k,d] * b2[k] ----------------
__global__ __launch_bounds__(256)
void wb_kernel(const float* __restrict__ W2, const float* __restrict__ b2,
               float* __restrict__ w2b) {
  const int dt = threadIdx.x & 15, kg = threadIdx.x >> 4;   // 16 d x 16 kgroups
  const int d = blockIdx.x * 16 + dt;
  float s = 0.f;
  for (int k = kg * 64; k < kg * 64 + 64; ++k)
    s += W2[(size_t)k * 1024 + d] * b2[k];
  __shared__ float red[16][17];
  red[kg][dt] = s;
  __syncthreads();
  if (kg == 0) {
    float t = 0.f;
#pragma unroll
    for (int g = 0; g < 16; ++g) t += red[g][dt];
    w2b[d] = t;
  }
}

// ---------------- GEMM1: fp32-A (reg-staged -> bf16 LDS), 256x256, 8-wave ----
// C[m,n] = relu(sum_k A[m,k]*W[n,k] + bias[n]); A fp32 rows: r1 0..16383,
// r2 16384..36863; W bf16 row-major; C bf16.
// LDS per buffer: A-bf16 16KB (proven swizzled layout) + B 16KB; 3-deep ring.
// A staged via regs: fp32 global_load (phase 0) -> cvt -> linear ds_write_b128
// (phase 1); the chunk swizzle chunk^=(row>>1)&3 is applied on the SOURCE side
// so the read addressing is identical to the measured-0-conflict bf16 kernel.
__global__ __launch_bounds__(512, 2)
void mlp_gemm_f32a(const float* __restrict__ R1, const float* __restrict__ R2,
                   const bf16_t* __restrict__ W, const float* __restrict__ bias,
                   bf16_t* __restrict__ C, int Mtiles) {
  const int nwg = Mtiles * 4;
  const int cpx = nwg >> 3;
  const int wg  = ((int)blockIdx.x & 7) * cpx + ((int)blockIdx.x >> 3);
  const int mt = wg >> 2, nt = wg & 3;

  __shared__ __align__(16) char lds[98304];   // 3 x (A 16KB + B 16KB)

  const int t    = threadIdx.x;
  const int lane = t & 63, wid = t >> 6;
  const int wm = wid >> 2, wn = wid & 3;
  const int rsel = lane & 15, hi = lane >> 4;
  const int t16 = t * 16;

  // --- A staging: thread t owns LDS slots t*16 (row rW) and 8192+t*16 (row rW+128)
  const int rW = t >> 2;                               // 0..127
  const int k0 = ((t & 3) ^ ((rW >> 1) & 3)) * 8;      // logical k-chunk (source swizzle)
  const float* Abase = (mt < 64) ? (R1 + (size_t)mt * 256 * 1024)
                                 : (R2 + (size_t)(mt - 64) * 256 * 1024);
  const float* pAg0 = Abase + (size_t)rW * 1024 + k0;
  const float* pAg1 = Abase + (size_t)(rW + 128) * 1024 + k0;

  // --- B staging source (bf16, proven swizzle) ---
  const int P0 = t16, P1 = 8192 + t16;
  const int Lg0 = P0 ^ ((P0 >> 3) & 0x30);
  const int Lg1 = P1 ^ ((P1 >> 3) & 0x30);
  const bf16_t* pB0 = W + (size_t)(nt * 256 + (Lg0 >> 6)) * 1024 + ((Lg0 & 63) >> 1);
  const bf16_t* pB1 = W + (size_t)(nt * 256 + (Lg1 >> 6)) * 1024 + ((Lg1 & 63) >> 1);

  // --- ds_read addressing (identical to proven bf16 kernel) ---
  const int kchunk = (hi ^ ((rsel >> 1) & 3)) << 4;
  const int offA = ((wm * 128 + rsel) << 6) + kchunk;
  const int offB = 16384 + ((wn * 64 + rsel) << 6) + kchunk;

  f32x4 acc[8][4] = {};
  bf16x8 bfr[4];

  // prologue: stage tiles 0,1
  {
    f32x4 a0 = *(const f32x4*)(pAg0);
    f32x4 a1 = *(const f32x4*)(pAg0 + 4);
    f32x4 a2 = *(const f32x4*)(pAg1);
    f32x4 a3 = *(const f32x4*)(pAg1 + 4);
    f32x4 a4 = *(const f32x4*)(pAg0 + 32);
    f32x4 a5 = *(const f32x4*)(pAg0 + 36);
    f32x4 a6 = *(const f32x4*)(pAg1 + 32);
    f32x4 a7 = *(const f32x4*)(pAg1 + 36);
    gload16(pB0,      lds + 16384 + t16);
    gload16(pB1,      lds + 24576 + t16);
    gload16(pB0 + 32, lds + 32768 + 16384 + t16);
    gload16(pB1 + 32, lds + 32768 + 24576 + t16);
    *(bf16x8*)(lds + t16)                = cvt8(a0, a1);
    *(bf16x8*)(lds + 8192 + t16)         = cvt8(a2, a3);
    *(bf16x8*)(lds + 32768 + t16)        = cvt8(a4, a5);
    *(bf16x8*)(lds + 32768 + 8192 + t16) = cvt8(a6, a7);
  }
  asm volatile("s_waitcnt vmcnt(0) lgkmcnt(0)" ::: "memory");
  __builtin_amdgcn_s_barrier();
  __builtin_amdgcn_sched_barrier(0);

  int cur = 0;
#pragma unroll 1
  for (int tt = 0; tt < 32; ++tt) {
    const char* rb = lds + cur * 32768;
    int nx = cur + 2; if (nx >= 3) nx -= 3;
    char* sb = lds + nx * 32768;             // holds tile tt-1 (dead) -> tile tt+2
    const int ks = (tt + 2) * 32;
    f32x4 L0, L1, L2, L3;
    // ---- phase 0: ds_read A m0-3 + B; issue next-A f32 loads + B gloads ----
    bf16x8 af[4];
#pragma unroll
    for (int m = 0; m < 4; ++m) af[m] = *(const bf16x8*)(rb + offA + m * 1024);
#pragma unroll
    for (int n = 0; n < 4; ++n) bfr[n] = *(const bf16x8*)(rb + offB + n * 1024);
    if (tt < 30) {
      L0 = *(const f32x4*)(pAg0 + ks);
      L1 = *(const f32x4*)(pAg0 + ks + 4);
      L2 = *(const f32x4*)(pAg1 + ks);
      L3 = *(const f32x4*)(pAg1 + ks + 4);
      gload16(pB0 + ks, sb + 16384 + t16);
      gload16(pB1 + ks, sb + 24576 + t16);
    }
    __builtin_amdgcn_s_setprio(1);
#pragma unroll
    for (int m = 0; m < 4; ++m)
#pragma unroll
      for (int n = 0; n < 4; ++n)
        acc[m][n] = __builtin_amdgcn_mfma_f32_16x16x32_bf16(af[m], bfr[n], acc[m][n], 0, 0, 0);
    __builtin_amdgcn_s_setprio(0);
    __builtin_amdgcn_s_barrier();
    __builtin_amdgcn_sched_barrier(0);
    // ---- phase 1: ds_read A m4-7; vmcnt-retire A loads; cvt + ds_write ----
#pragma unroll
    for (int m = 0; m < 4; ++m) af[m] = *(const bf16x8*)(rb + offA + (m + 4) * 1024);
    if (tt < 30) {
      asm volatile("s_waitcnt vmcnt(2)" ::: "memory");  // A f32 done; newest 2 B stay
      *(bf16x8*)(sb + t16)        = cvt8(L0, L1);
      *(bf16x8*)(sb + 8192 + t16) = cvt8(L2, L3);
    }
    __builtin_amdgcn_s_setprio(1);
#pragma unroll
    for (int m = 0; m < 4; ++m)
#pragma unroll
      for (int n = 0; n < 4; ++n)
        acc[m + 4][n] = __builtin_amdgcn_mfma_f32_16x16x32_bf16(af[m], bfr[n], acc[m + 4][n], 0, 0, 0);
    __builtin_amdgcn_s_setprio(0);
    if (tt == 30) asm volatile("s_waitcnt vmcnt(0)" ::: "memory");
    asm volatile("s_waitcnt lgkmcnt(0)" ::: "memory");  // drain ds_writes pre-barrier
    __builtin_amdgcn_s_barrier();
    __builtin_amdgcn_sched_barrier(0);
    cur = (cur + 1 == 3) ? 0 : cur + 1;
  }

  const int row0 = mt * 256 + wm * 128 + hi * 4;
  const int col0 = nt * 256 + wn * 64 + rsel;
  float bv[4];
#pragma unroll
  for (int n = 0; n < 4; ++n) bv[n] = bias[col0 + n * 16];
#pragma unroll
  for (int m = 0; m < 8; ++m) {
#pragma unroll
    for (int q = 0; q < 4; ++q) {
      const size_t rr = (size_t)(row0 + m * 16 + q) * 1024;
#pragma unroll
      for (int n = 0; n < 4; ++n) {
        float v = fmaxf(acc[m][n][q] + bv[n], 0.f);
        C[rr + col0 + n * 16] = (bf16_t)v;
      }
    }
  }
}

// ---------------- bf16 MLP GEMM, 256x256 tile, 8-wave (r2/r3 proven) ----------
__global__ __launch_bounds__(512, 2)
void mlp_gemm8(const bf16_t* __restrict__ A, const bf16_t* __restrict__ W,
               const float* __restrict__ bias, bf16_t* __restrict__ C,
               int Mtiles, int relu) {
  const int nwg = Mtiles * 4;
  const int cpx = nwg >> 3;
  const int wg  = ((int)blockIdx.x & 7) * cpx + ((int)blockIdx.x >> 3);
  const int mt = wg >> 2, nt = wg & 3;

  __shared__ __align__(16) char lds[131072];

  const int t    = threadIdx.x;
  const int lane = t & 63, wid = t >> 6;
  const int wm = wid >> 2, wn = wid & 3;
  const int rsel = lane & 15, hi = lane >> 4;
  const int t16 = t * 16;

  const int P0 = t16, P1 = 8192 + t16;
  const int Lg0 = P0 ^ ((P0 >> 3) & 0x30);
  const int Lg1 = P1 ^ ((P1 >> 3) & 0x30);
  const int rS0 = Lg0 >> 6, cS0 = (Lg0 & 63) >> 1;
  const int rS1 = Lg1 >> 6, cS1 = (Lg1 & 63) >> 1;
  const bf16_t* pA0 = A + (size_t)(mt * 256 + rS0) * 1024 + cS0;
  const bf16_t* pA1 = A + (size_t)(mt * 256 + rS1) * 1024 + cS1;
  const bf16_t* pB0 = W + (size_t)(nt * 256 + rS0) * 1024 + cS0;
  const bf16_t* pB1 = W + (size_t)(nt * 256 + rS1) * 1024 + cS1;

  const int kchunk = (hi ^ ((rsel >> 1) & 3)) << 4;
  const int offA = ((wm * 128 + rsel) << 6) + kchunk;
  const int offB = 16384 + ((wn * 64 + rsel) << 6) + kchunk;

  f32x4 acc[8][4] = {};
  bf16x8 bfr[4];

#pragma unroll
  for (int p = 0; p < 3; ++p) {
    char* db = lds + p * 32768;
    gload16(pA0 + p * 32, db + t16);
    gload16(pA1 + p * 32, db + 8192 + t16);
    gload16(pB0 + p * 32, db + 16384 + t16);
    gload16(pB1 + p * 32, db + 24576 + t16);
  }
  asm volatile("s_waitcnt vmcnt(8)" ::: "memory");
  __builtin_amdgcn_s_barrier();
  __builtin_amdgcn_sched_barrier(0);

#pragma unroll 1
  for (int tt = 0; tt < 32; ++tt) {
    const char* rb = lds + (tt & 3) * 32768;
    char* sb = lds + ((tt + 3) & 3) * 32768;
    const int ks = (tt + 3) * 32;
    bf16x8 af[4];
#pragma unroll
    for (int m = 0; m < 4; ++m) af[m] = *(const bf16x8*)(rb + offA + m * 1024);
#pragma unroll
    for (int n = 0; n < 4; ++n) bfr[n] = *(const bf16x8*)(rb + offB + n * 1024);
    if (tt < 29) {
      gload16(pA0 + ks, sb + t16);
      gload16(pA1 + ks, sb + 8192 + t16);
    }
    __builtin_amdgcn_s_setprio(1);
#pragma unroll
    for (int m = 0; m < 4; ++m)
#pragma unroll
      for (int n = 0; n < 4; ++n)
        acc[m][n] = __builtin_amdgcn_mfma_f32_16x16x32_bf16(af[m], bfr[n], acc[m][n], 0, 0, 0);
    __builtin_amdgcn_s_setprio(0);
    __builtin_amdgcn_s_barrier();
    __builtin_amdgcn_sched_barrier(0);
#pragma unroll
    for (int m = 0; m < 4; ++m) af[m] = *(const bf16x8*)(rb + offA + (m + 4) * 1024);
    if (tt < 29) {
      gload16(pB0 + ks, sb + 16384 + t16);
      gload16(pB1 + ks, sb + 24576 + t16);
    }
    __builtin_amdgcn_s_setprio(1);
#pragma unroll
    for (int m = 0; m < 4; ++m)
#pragma unroll
      for (int n = 0; n < 4; ++n)
        acc[m + 4][n] = __builtin_amdgcn_mfma_f32_16x16x32_bf16(af[m], bfr[n], acc[m + 4][n], 0, 0, 0);
    __builtin_amdgcn_s_setprio(0);
    if (tt < 29)       asm volatile("s_waitcnt vmcnt(8)" ::: "memory");
    else if (tt == 29) asm volatile("s_waitcnt vmcnt(4)" ::: "memory");
    else if (tt == 30) asm volatile("s_waitcnt vmcnt(0)" ::: "memory");
    __builtin_amdgcn_s_barrier();
    __builtin_amdgcn_sched_barrier(0);
  }

  const int row0 = mt * 256 + wm * 128 + hi * 4;
  const int col0 = nt * 256 + wn * 64 + rsel;
  float bv[4];
#pragma unroll
  for (int n = 0; n < 4; ++n) bv[n] = bias[col0 + n * 16];
#pragma unroll
  for (int m = 0; m < 8; ++m) {
#pragma unroll
    for (int q = 0; q < 4; ++q) {
      const size_t rr = (size_t)(row0 + m * 16 + q) * 1024;
#pragma unroll
      for (int n = 0; n < 4; ++n) {
        float v = acc[m][n][q] + bv[n];
        if (relu) v = fmaxf(v, 0.f);
        C[rr + col0 + n * 16] = (bf16_t)v;
      }
    }
  }
}

// ---------------- 128x128 split-K GEMM ----------------
__global__ __launch_bounds__(256)
void gemmK(const bf16_t* __restrict__ A, const bf16_t* __restrict__ W,
           float* __restrict__ P, int KS) {
  const int slice = (int)blockIdx.x >> 6;
  const int tl = (int)blockIdx.x & 63;
  const int mt = tl >> 3, nt = tl & 7;
  const int koff = slice * KS;

  const int f = threadIdx.x;
  const int lane = f & 63, w = f >> 6;
  const int sRow = f >> 2, sCol8 = (f & 3) * 8;

  const bf16_t* Ab = A + (size_t)mt * 128 * 1024 + (size_t)sRow * 1024 + sCol8;
  const bf16_t* Bb = W + (size_t)nt * 128 * 1024 + (size_t)sRow * 1024 + sCol8;

  __shared__ __align__(16) bf16_t sA[128 * 32];
  __shared__ __align__(16) bf16_t sB[128 * 32];
  bf16_t* sAp = sA + sRow * 32 + sCol8;
  bf16_t* sBp = sB + sRow * 32 + sCol8;

  const int wr = (w >> 1) * 64, wc = (w & 1) * 64;
  const int rsel = lane & 15, koff2 = (lane >> 4) * 8;
  const bf16_t* rA = sA + (wr + rsel) * 32 + koff2;
  const bf16_t* rB = sB + (wc + rsel) * 32 + koff2;

  f32x4 acc[4][4] = {};
  for (int kt = koff; kt < koff + KS; kt += 32) {
    __syncthreads();
    gload16(Ab + kt,             sAp);
    gload16(Ab + kt + 64 * 1024, sAp + 64 * 32);
    gload16(Bb + kt,             sBp);
    gload16(Bb + kt + 64 * 1024, sBp + 64 * 32);
    asm volatile("s_waitcnt vmcnt(0)" ::: "memory");
    __syncthreads();
    bf16x8 af[4], bfv[4];
#pragma unroll
    for (int m = 0; m < 4; ++m) af[m] = *(const bf16x8*)(rA + m * 16 * 32);
#pragma unroll
    for (int n = 0; n < 4; ++n) bfv[n] = *(const bf16x8*)(rB + n * 16 * 32);
#pragma unroll
    for (int m = 0; m < 4; ++m)
#pragma unroll
      for (int n = 0; n < 4; ++n)
        acc[m][n] = __builtin_amdgcn_mfma_f32_16x16x32_bf16(af[m], bfv[n], acc[m][n], 0, 0, 0);
  }

  float* Pb = P + (size_t)slice * 1048576;
  const int row0 = mt * 128 + wr + (lane >> 4) * 4;
  const int col0 = nt * 128 + wc + rsel;
#pragma unroll
  for (int n = 0; n < 4; ++n) {
    const int c = col0 + n * 16;
#pragma unroll
    for (int m = 0; m < 4; ++m) {
      const int r = row0 + m * 16;
#pragma unroll
      for (int q = 0; q < 4; ++q)
        Pb[(size_t)(r + q) * 1024 + c] = acc[m][n][q];
    }
  }
}

// reduce 4 G-partials -> bf16 G
__global__ __launch_bounds__(256)
void g_reduce(const float* __restrict__ Gp, bf16_t* __restrict__ GB) {
  const int i4 = blockIdx.x * 256 + threadIdx.x;
  float4 a = ((const float4*)Gp)[i4];
  float4 b = ((const float4*)(Gp + 1048576))[i4];
  float4 c = ((const float4*)(Gp + 2097152))[i4];
  float4 d = ((const float4*)(Gp + 3145728))[i4];
  bf16x4 o = { (bf16_t)(a.x + b.x + c.x + d.x), (bf16_t)(a.y + b.y + c.y + d.y),
               (bf16_t)(a.z + b.z + c.z + d.z), (bf16_t)(a.w + b.w + c.w + d.w) };
  ((bf16x4*)GB)[i4] = o;
}

// ---------------- pool split-K GEMM: U(256x1024) * W2^T, 8 K-slices ----------
__global__ __launch_bounds__(256)
void pool_gemmK(const bf16_t* __restrict__ A, const bf16_t* __restrict__ W,
                float* __restrict__ P) {
  const int slice = (int)blockIdx.x >> 4;
  const int tl = (int)blockIdx.x & 15;
  const int mt = tl >> 3, nt = tl & 7;
  const int koff = slice * 128;

  const int f = threadIdx.x;
  const int lane = f & 63, w = f >> 6;
  const int sRow = f >> 2, sCol8 = (f & 3) * 8;

  const bf16_t* Ab = A + (size_t)mt * 128 * 1024 + (size_t)sRow * 1024 + sCol8;
  const bf16_t* Bb = W + (size_t)nt * 128 * 1024 + (size_t)sRow * 1024 + sCol8;

  __shared__ __align__(16) bf16_t sA[128 * 32];
  __shared__ __align__(16) bf16_t sB[128 * 32];
  bf16_t* sAp = sA + sRow * 32 + sCol8;
  bf16_t* sBp = sB + sRow * 32 + sCol8;

  const int wr = (w >> 1) * 64, wc = (w & 1) * 64;
  const int rsel = lane & 15, koff2 = (lane >> 4) * 8;
  const bf16_t* rA = sA + (wr + rsel) * 32 + koff2;
  const bf16_t* rB = sB + (wc + rsel) * 32 + koff2;

  f32x4 acc[4][4] = {};
  for (int kt = koff; kt < koff + 128; kt += 32) {
    __syncthreads();
    gload16(Ab + kt,             sAp);
    gload16(Ab + kt + 64 * 1024, sAp + 64 * 32);
    gload16(Bb + kt,             sBp);
    gload16(Bb + kt + 64 * 1024, sBp + 64 * 32);
    asm volatile("s_waitcnt vmcnt(0)" ::: "memory");
    __syncthreads();
    bf16x8 af[4], bfv[4];
#pragma unroll
    for (int m = 0; m < 4; ++m) af[m] = *(const bf16x8*)(rA + m * 16 * 32);
#pragma unroll
    for (int n = 0; n < 4; ++n) bfv[n] = *(const bf16x8*)(rB + n * 16 * 32);
#pragma unroll
    for (int m = 0; m < 4; ++m)
#pragma unroll
      for (int n = 0; n < 4; ++n)
        acc[m][n] = __builtin_amdgcn_mfma_f32_16x16x32_bf16(af[m], bfv[n], acc[m][n], 0, 0, 0);
  }

  float* Pb = P + (size_t)slice * 262144;
  const int row0 = mt * 128 + wr + (lane >> 4) * 4;
  const int col0 = nt * 128 + wc + rsel;
#pragma unroll
  for (int n = 0; n < 4; ++n) {
    const int c = col0 + n * 16;
#pragma unroll
    for (int m = 0; m < 4; ++m) {
      const int r = row0 + m * 16;
#pragma unroll
      for (int q = 0; q < 4; ++q)
        Pb[(size_t)(r + q) * 1024 + c] = acc[m][n][q];
    }
  }
}

// reduce 8 pool partials + bias, remap rows -> d_out
__global__ __launch_bounds__(256)
void pool_reduce(const float* __restrict__ Pp, const float* __restrict__ b2,
                 float* __restrict__ out) {
  const int idx = blockIdx.x * 256 + threadIdx.x;
  const int r = idx >> 10, c = idx & 1023;
  float s = b2[c];
#pragma unroll
  for (int sl = 0; sl < 8; ++sl) s += Pp[(size_t)sl * 262144 + idx];
  const int g = r >> 6, b = r & 63;
  out[(size_t)(g >> 1) * 131072 + (size_t)b * 2048 + (g & 1) * 1024 + c] = s;
}

// ---------------- t[r] = h[r,:] . w2b ----------------
__global__ __launch_bounds__(256)
void t_kernel(const bf16_t* __restrict__ H, const float* __restrict__ w2b,
              float* __restrict__ tT1, float* __restrict__ tT2) {
  const int wv = threadIdx.x >> 6, lane = threadIdx.x & 63;
  const int r = blockIdx.x * 4 + wv;
  const bf16_t* hrow = H + (size_t)r * 1024;
  float s = 0.f;
#pragma unroll
  for (int h = 0; h < 2; ++h) {
    bf16x8 v = *(const bf16x8*)(hrow + h * 512 + lane * 8);
#pragma unroll
    for (int e = 0; e < 8; ++e) s += (float)v[e] * w2b[h * 512 + lane * 8 + e];
  }
#pragma unroll
  for (int off = 32; off; off >>= 1) s += __shfl_xor(s, off);
  if (lane == 0) {
    const int b = r & 63;
    if (r < 16384) tT1[b * L1C + (r >> 6)] = s;
    else           tT2[b * L2C + ((r - 16384) >> 6)] = s;
  }
}

// ---------------- logits: oz[b,i,j] = z1[b,i,:].h2[b,j,:] ----------------
__global__ __launch_bounds__(256)
void logits_gemm(const bf16_t* __restrict__ Y1, const bf16_t* __restrict__ Y2,
                 float* __restrict__ O) {
  const int wg = ((int)blockIdx.x & 7) * 48 + ((int)blockIdx.x >> 3);
  const int b = wg / 6, t = wg % 6;
  const int mt = t / 3, nt = t % 3;

  const int f = threadIdx.x;
  const int lane = f & 63, w = f >> 6;
  const int sRow = f >> 2, sCol8 = (f & 3) * 8;

  const int i0 = mt * 128 + sRow;
  const int i1 = i0 + 64;
  int j0 = nt * 128 + sRow;      if (j0 > L2C - 1) j0 = L2C - 1;
  int j1 = nt * 128 + sRow + 64; if (j1 > L2C - 1) j1 = L2C - 1;
  const bf16_t* A0 = Y1 + ((size_t)i0 * BC + b) * DC + sCol8;
  const bf16_t* A1 = Y1 + ((size_t)i1 * BC + b) * DC + sCol8;
  const bf16_t* B0 = Y2 + ((size_t)j0 * BC + b) * DC + sCol8;
  const bf16_t* B1 = Y2 + ((size_t)j1 * BC + b) * DC + sCol8;

  __shared__ __align__(16) bf16_t sA[128 * 32];
  __shared__ __align__(16) bf16_t sB[128 * 32];
  bf16_t* sAp = sA + sRow * 32 + sCol8;
  bf16_t* sBp = sB + sRow * 32 + sCol8;

  const int wr = (w >> 1) * 64, wc = (w & 1) * 64;
  const int rsel = lane & 15, koff = (lane >> 4) * 8;
  const bf16_t* rA = sA + (wr + rsel) * 32 + koff;
  const bf16_t* rB = sB + (wc + rsel) * 32 + koff;

  f32x4 acc[4][4] = {};
  for (int kt = 0; kt < 1024; kt += 32) {
    __syncthreads();
    gload16(A0 + kt, sAp);
    gload16(A1 + kt, sAp + 64 * 32);
    gload16(B0 + kt, sBp);
    gload16(B1 + kt, sBp + 64 * 32);
    asm volatile("s_waitcnt vmcnt(0)" ::: "memory");
    __syncthreads();
    bf16x8 af[4], bfv[4];
#pragma unroll
    for (int m = 0; m < 4; ++m) af[m] = *(const bf16x8*)(rA + m * 16 * 32);
#pragma unroll
    for (int n = 0; n < 4; ++n) bfv[n] = *(const bf16x8*)(rB + n * 16 * 32);
#pragma unroll
    for (int m = 0; m < 4; ++m)
#pragma unroll
      for (int n = 0; n < 4; ++n)
        acc[m][n] = __builtin_amdgcn_mfma_f32_16x16x32_bf16(af[m], bfv[n], acc[m][n], 0, 0, 0);
  }

  float* Ob = O + (size_t)b * L1C * L2C;
  const int row0 = mt * 128 + wr + (lane >> 4) * 4;
  const int col0 = nt * 128 + wc + rsel;
#pragma unroll
  for (int n = 0; n < 4; ++n) {
    const int c = col0 + n * 16;
    if (c < L2C) {
#pragma unroll
      for (int m = 0; m < 4; ++m) {
        const int r = row0 + m * 16;
#pragma unroll
        for (int q = 0; q < 4; ++q)
          Ob[(size_t)(r + q) * L2C + c] = acc[m][n][q];
      }
    }
  }
}

// ---------------- softmax stats (with rank-1 terms t1,t2) ----------------
__global__ __launch_bounds__(256)
void row_stats(const float* __restrict__ O, const float* __restrict__ tT2,
               float* __restrict__ rowM, float* __restrict__ rowInv) {
  const int gw = blockIdx.x * 4 + (threadIdx.x >> 6);
  const int lane = threadIdx.x & 63;
  const int b = gw >> 8;
  const float* row = O + (size_t)gw * L2C;
  const float* t2 = tT2 + b * L2C;
  float v[5];
  float m = -1e30f;
#pragma unroll
  for (int t = 0; t < 5; ++t) { v[t] = row[t * 64 + lane] + t2[t * 64 + lane]; m = fmaxf(m, v[t]); }
#pragma unroll
  for (int off = 32; off; off >>= 1) m = fmaxf(m, __shfl_xor(m, off));
  float s = 0.f;
#pragma unroll
  for (int t = 0; t < 5; ++t) s += __expf(v[t] - m);
#pragma unroll
  for (int off = 32; off; off >>= 1) s += __shfl_xor(s, off);
  if (lane == 0) { rowM[gw] = m; rowInv[gw] = 1.f / s; }
}

__global__ __launch_bounds__(256)
void col_stats_c1(const float* __restrict__ O, const float* __restrict__ tT1,
                  const float* __restrict__ tT2,
                  const float* __restrict__ rowM, const float* __restrict__ rowInv,
                  float* __restrict__ colM, float* __restrict__ colInv,
                  float* __restrict__ c1) {
  const int b = blockIdx.x / 5, jb = blockIdx.x % 5;
  const int jl = threadIdx.x & 63, ig = threadIdx.x >> 6;
  const int j = jb * 64 + jl;
  const float* Ob = O + (size_t)b * L1C * L2C + j;
  const float* rM = rowM + b * L1C;
  const float* rI = rowInv + b * L1C;
  const float* t1 = tT1 + b * L1C;
  const float t2j = tT2[b * L2C + j];
  float m = -1e30f, s = 0.f, cp = 0.f;
  for (int i = ig; i < L1C; i += 4) {
    float ov = Ob[(size_t)i * L2C];
    float v = ov + t1[i];
    float mn = fmaxf(m, v);
    s = s * __expf(m - mn) + __expf(v - mn);
    m = mn;
    cp += __expf(ov + t2j - rM[i]) * rI[i];
  }
  __shared__ float sm[4][64], ss[4][64], sc[4][64];
  sm[ig][jl] = m; ss[ig][jl] = s; sc[ig][jl] = cp;
  __syncthreads();
  if (ig == 0) {
    for (int g = 1; g < 4; ++g) {
      float mg = sm[g][jl], sg = ss[g][jl];
      float mn = fmaxf(m, mg);
      s = s * __expf(m - mn) + sg * __expf(mg - mn);
      m = mn;
      cp += sc[g][jl];
    }
    colM[b * L2C + j] = m;
    colInv[b * L2C + j] = 1.f / s;
    c1[b * L2C + j] = cp;
  }
}

__global__ __launch_bounds__(256)
void c2_kernel(const float* __restrict__ O, const float* __restrict__ tT1,
               const float* __restrict__ colM, const float* __restrict__ colInv,
               float* __restrict__ c2) {
  const int gw = blockIdx.x * 4 + (threadIdx.x >> 6);
  const int lane = threadIdx.x & 63;
  const int b = gw >> 8;
  const float* row = O + (size_t)gw * L2C;
  const float* cM = colM + b * L2C;
  const float* cI = colInv + b * L2C;
  const float t1i = tT1[b * L1C + (gw & 255)];
  float s = 0.f;
#pragma unroll
  for (int t = 0; t < 5; ++t) {
    const int j = t * 64 + lane;
    s += __expf(row[j] + t1i - cM[j]) * cI[j];
  }
#pragma unroll
  for (int off = 32; off; off >>= 1) s += __shfl_xor(s, off);
  if (lane == 0) c2[gw] = s;
}

// ---------------- weighted h-sums -> U (256x1024 bf16) ----------------
__global__ __launch_bounds__(256)
void u_kernel(const bf16_t* __restrict__ H, const float* __restrict__ c1,
              const float* __restrict__ c2, bf16_t* __restrict__ Ub) {
  const int b = blockIdx.x >> 2;
  const int d = (blockIdx.x & 3) * 256 + threadIdx.x;
  const bf16_t* H2 = H + (size_t)L1C * BC * DC;
  float s1 = 0.f, s1c = 0.f, s2 = 0.f, s2c = 0.f;
  const float* c2b = c2 + b * L1C;
  for (int i = 0; i < L1C; ++i) {
    float v = (float)H[((size_t)i * BC + b) * DC + d];
    s1 += v; s1c += c2b[i] * v;
  }
  const float* c1b = c1 + b * L2C;
  for (int j = 0; j < L2C; ++j) {
    float v = (float)H2[((size_t)j * BC + b) * DC + d];
    s2 += v; s2c += c1b[j] * v;
  }
  Ub[(size_t)(0 * 64 + b) * 1024 + d] = (bf16_t)(s1  * (1.f / L1C));
  Ub[(size_t)(1 * 64 + b) * 1024 + d] = (bf16_t)(s2c * (1.f / L1C));
  Ub[(size_t)(2 * 64 + b) * 1024 + d] = (bf16_t)(s2  * (1.f / L2C));
  Ub[(size_t)(3 * 64 + b) * 1024 + d] = (bf16_t)(s1c * (1.f / L2C));
}

// ---------------- host ----------------
extern "C" void kernel_launch(void* const* d_in, const int* in_sizes, int n_in,
                              void* d_out, int out_size, void* d_ws, size_t ws_size,
                              hipStream_t stream) {
  const float* r1 = (const float*)d_in[0];
  const float* r2 = (const float*)d_in[1];
  const float* W1 = (const float*)d_in[2];
  const float* b1 = (const float*)d_in[3];
  const float* W2 = (const float*)d_in[4];
  const float* b2 = (const float*)d_in[5];
  float* out = (float*)d_out;
  char* ws = (char*)d_ws;

  const size_t M1 = (size_t)L1C * BC;   // 16384
  const size_t M2 = (size_t)L2C * BC;   // 20480
  const size_t Mt = M1 + M2;            // 36864

  size_t off = 0;
  bf16_t* XB  = (bf16_t*)(ws + off); off += Mt * DC * 2;        // 72MB: Z + O + Gpart
  bf16_t* HB  = (bf16_t*)(ws + off); off += Mt * DC * 2;        // 72MB, h; head reused as Ppart
  bf16_t* WB1 = (bf16_t*)(ws + off); off += (size_t)DC * DC * 2;
  bf16_t* WB2 = (bf16_t*)(ws + off); off += (size_t)DC * DC * 2;
  bf16_t* W2T = (bf16_t*)(ws + off); off += (size_t)DC * DC * 2;
  bf16_t* GB  = (bf16_t*)(ws + off); off += (size_t)DC * DC * 2;
  float* w2b   = (float*)(ws + off); off += 4096;
  float* zb    = (float*)(ws + off); off += 4096;
  float* tT1   = (float*)(ws + off); off += BC * L1C * 4;
  float* tT2   = (float*)(ws + off); off += BC * L2C * 4;
  float* rowM  = (float*)(ws + off); off += BC * L1C * 4;
  float* rowIv = (float*)(ws + off); off += BC * L1C * 4;
  float* colM  = (float*)(ws + off); off += BC * L2C * 4;
  float* colIv = (float*)(ws + off); off += BC * L2C * 4;
  float* c1v   = (float*)(ws + off); off += BC * L2C * 4;
  float* c2v   = (float*)(ws + off); off += BC * L1C * 4;
  bf16_t* Ub   = (bf16_t*)(ws + off); off += 256 * DC * 2;

  bf16_t* Z = XB;                                   // 16384x1024 bf16 (32MB)
  float*  O = (float*)((char*)XB + 35651584);       // 21MB logits
  float*  Gpart = (float*)((char*)XB + 58720256);   // 16MB (4 slices)
  float*  Ppart = (float*)HB;                       // 8MB (8 slices), HB dead then
  bf16_t* H2 = HB + M1 * DC;

  // 1. weight prep only (r1/r2 consumed fp32-direct by GEMM1)
  conv_kernel<<<512, 256, 0, stream>>>(W1, WB1, (int)((size_t)DC * DC / 4));
  conv_kernel<<<512, 256, 0, stream>>>(W2, WB2, (int)((size_t)DC * DC / 4));
  w2t_kernel<<<dim3(32, 32), 256, 0, stream>>>(W2, W2T);
  wb_kernel<<<64, 256, 0, stream>>>(W2, b2, w2b);
  (void)hipMemsetAsync(zb, 0, 4096, stream);

  // 2. h = relu(x W1^T + b1), A read fp32-direct, reg-staged to bf16 LDS
  mlp_gemm_f32a<<<576, 512, 0, stream>>>(r1, r2, WB1, b1, HB, 144);

  // 3. G = W2^T W2 split-K;  t = h . (W2^T b2)
  gemmK<<<256, 256, 0, stream>>>(W2T, W2T, Gpart, 256);
  t_kernel<<<9216, 256, 0, stream>>>(HB, w2b, tT1, tT2);
  g_reduce<<<1024, 256, 0, stream>>>(Gpart, GB);

  // 4. z1 = h1 G
  mlp_gemm8<<<256, 512, 0, stream>>>(HB, GB, zb, Z, 64, 0);

  // 5. oz[b,i,j] = z1 . h2
  logits_gemm<<<384, 256, 0, stream>>>(Z, H2, O);

  // 6. softmax stats with rank-1 corrections
  row_stats<<<4096, 256, 0, stream>>>(O, tT2, rowM, rowIv);
  col_stats_c1<<<320, 256, 0, stream>>>(O, tT1, tT2, rowM, rowIv, colM, colIv, c1v);
  c2_kernel<<<4096, 256, 0, stream>>>(O, tT1, colM, colIv, c2v);

  // 7. weighted h pools -> U;  out = U W2^T + b2, split-K + reduce
  u_kernel<<<256, 256, 0, stream>>>(HB, c1v, c2v, Ub);
  pool_gemmK<<<128, 256, 0, stream>>>(Ub, WB2, Ppart);
  pool_reduce<<<1024, 256, 0, stream>>>(Ppart, b2, out);
}

// Round 8
// 333.859 us; speedup vs baseline: 1.0441x; 1.0441x over previous
//
#include <hip/hip_runtime.h>
#include <stdint.h>

#define L1C 256
#define L2C 320
#define BC  64
#define DC  1024

typedef __bf16 bf16_t;
typedef __bf16 bf16x8 __attribute__((ext_vector_type(8)));
typedef __bf16 bf16x4 __attribute__((ext_vector_type(4)));
typedef float  f32x4  __attribute__((ext_vector_type(4)));

__device__ __forceinline__ void gload16(const void* g, void* l) {
  __builtin_amdgcn_global_load_lds(
      (__attribute__((address_space(1))) void*)g,
      (__attribute__((address_space(3))) void*)l, 16, 0, 0);
}

__device__ __forceinline__ bf16x8 cvt8(f32x4 a, f32x4 b) {
  return bf16x8{ (bf16_t)a[0], (bf16_t)a[1], (bf16_t)a[2], (bf16_t)a[3],
                 (bf16_t)b[0], (bf16_t)b[1], (bf16_t)b[2], (bf16_t)b[3] };
}

// ---------------- fp32 -> bf16 convert (weights only) ----------------
__global__ __launch_bounds__(256)
void conv_kernel(const float* __restrict__ src, bf16_t* __restrict__ dst, int n4) {
  int i = blockIdx.x * 256 + threadIdx.x;
  const int stride = gridDim.x * 256;
  for (; i < n4; i += stride) {
    float4 v = ((const float4*)src)[i];
    bf16x4 o = { (__bf16)v.x, (__bf16)v.y, (__bf16)v.z, (__bf16)v.w };
    ((bf16x4*)dst)[i] = o;
  }
}

// ---------------- transpose W2 (fp32 1024x1024) -> bf16 W2T ----------------
__global__ __launch_bounds__(256)
void w2t_kernel(const float* __restrict__ W2, bf16_t* __restrict__ W2T) {
  __shared__ float tile[32][33];
  const int tx = threadIdx.x & 31, ty = threadIdx.x >> 5;  // 32 x 8
  const int x0 = blockIdx.x * 32, y0 = blockIdx.y * 32;
#pragma unroll
  for (int k = 0; k < 32; k += 8)
    tile[ty + k][tx] = W2[(size_t)(y0 + ty + k) * 1024 + x0 + tx];
  __syncthreads();
#pragma unroll
  for (int k = 0; k < 32; k += 8)
    W2T[(size_t)(x0 + ty + k) * 1024 + y0 + tx] = (bf16_t)tile[tx][ty + k];
}

// ---------------- w2b[d] = sum_k W2[k,d] * b2[k] ----------------
__global__ __launch_bounds__(256)
void wb_kernel(const float* __restrict__ W2, const float* __restrict__ b2,
               float* __restrict__ w2b) {
  const int dt = threadIdx.x & 15, kg = threadIdx.x >> 4;   // 16 d x 16 kgroups
  const int d = blockIdx.x * 16 + dt;
  float s = 0.f;
  for (int k = kg * 64; k < kg * 64 + 64; ++k)
    s += W2[(size_t)k * 1024 + d] * b2[k];
  __shared__ float red[16][17];
  red[kg][dt] = s;
  __syncthreads();
  if (kg == 0) {
    float t = 0.f;
#pragma unroll
    for (int g = 0; g < 16; ++g) t += red[g][dt];
    w2b[d] = t;
  }
}

// ---------------- GEMM1: fp32-A (reg-staged -> bf16 LDS), 256x256, 8-wave ----
// Deep A pipeline: regs Lo hold tile tt+2 (issued at tile tt-1 phase 0);
// new loads Ln for tile tt+3 issue at tile tt phase 0; Lo written to LDS at
// tile tt phase 1 after vmcnt(6) (retires Lo's loads AND previous tile's B).
// LDS layout & ds_read addressing identical to the proven 0-conflict kernel.
__global__ __launch_bounds__(512, 2)
void mlp_gemm_f32a(const float* __restrict__ R1, const float* __restrict__ R2,
                   const bf16_t* __restrict__ W, const float* __restrict__ bias,
                   bf16_t* __restrict__ C, int Mtiles) {
  const int nwg = Mtiles * 4;
  const int cpx = nwg >> 3;
  const int wg  = ((int)blockIdx.x & 7) * cpx + ((int)blockIdx.x >> 3);
  const int mt = wg >> 2, nt = wg & 3;

  __shared__ __align__(16) char lds[98304];   // 3 x (A 16KB + B 16KB)

  const int t    = threadIdx.x;
  const int lane = t & 63, wid = t >> 6;
  const int wm = wid >> 2, wn = wid & 3;
  const int rsel = lane & 15, hi = lane >> 4;
  const int t16 = t * 16;

  // --- A staging: thread t owns LDS slots t*16 (row rW) and 8192+t*16 (row rW+128)
  const int rW = t >> 2;                               // 0..127
  const int k0 = ((t & 3) ^ ((rW >> 1) & 3)) * 8;      // logical k-chunk (source swizzle)
  const float* Abase = (mt < 64) ? (R1 + (size_t)mt * 256 * 1024)
                                 : (R2 + (size_t)(mt - 64) * 256 * 1024);
  const float* pAg0 = Abase + (size_t)rW * 1024 + k0;
  const float* pAg1 = Abase + (size_t)(rW + 128) * 1024 + k0;

  // --- B staging source (bf16, proven swizzle) ---
  const int P0 = t16, P1 = 8192 + t16;
  const int Lg0 = P0 ^ ((P0 >> 3) & 0x30);
  const int Lg1 = P1 ^ ((P1 >> 3) & 0x30);
  const bf16_t* pB0 = W + (size_t)(nt * 256 + (Lg0 >> 6)) * 1024 + ((Lg0 & 63) >> 1);
  const bf16_t* pB1 = W + (size_t)(nt * 256 + (Lg1 >> 6)) * 1024 + ((Lg1 & 63) >> 1);

  // --- ds_read addressing (identical to proven bf16 kernel) ---
  const int kchunk = (hi ^ ((rsel >> 1) & 3)) << 4;
  const int offA = ((wm * 128 + rsel) << 6) + kchunk;
  const int offB = 16384 + ((wn * 64 + rsel) << 6) + kchunk;

  f32x4 acc[8][4] = {};
  bf16x8 bfr[4];
  f32x4 Lo0, Lo1, Lo2, Lo3, Ln0, Ln1, Ln2, Ln3;

  // prologue: stage tiles 0,1 (A regs->LDS, B gload)
  {
    f32x4 a0 = *(const f32x4*)(pAg0);
    f32x4 a1 = *(const f32x4*)(pAg0 + 4);
    f32x4 a2 = *(const f32x4*)(pAg1);
    f32x4 a3 = *(const f32x4*)(pAg1 + 4);
    f32x4 a4 = *(const f32x4*)(pAg0 + 32);
    f32x4 a5 = *(const f32x4*)(pAg0 + 36);
    f32x4 a6 = *(const f32x4*)(pAg1 + 32);
    f32x4 a7 = *(const f32x4*)(pAg1 + 36);
    gload16(pB0,      lds + 16384 + t16);
    gload16(pB1,      lds + 24576 + t16);
    gload16(pB0 + 32, lds + 32768 + 16384 + t16);
    gload16(pB1 + 32, lds + 32768 + 24576 + t16);
    *(bf16x8*)(lds + t16)                = cvt8(a0, a1);
    *(bf16x8*)(lds + 8192 + t16)         = cvt8(a2, a3);
    *(bf16x8*)(lds + 32768 + t16)        = cvt8(a4, a5);
    *(bf16x8*)(lds + 32768 + 8192 + t16) = cvt8(a6, a7);
  }
  asm volatile("s_waitcnt vmcnt(0) lgkmcnt(0)" ::: "memory");
  // issue A(2) into Lo; stays in flight across the barrier
  Lo0 = *(const f32x4*)(pAg0 + 64);
  Lo1 = *(const f32x4*)(pAg0 + 68);
  Lo2 = *(const f32x4*)(pAg1 + 64);
  Lo3 = *(const f32x4*)(pAg1 + 68);
  __builtin_amdgcn_s_barrier();
  __builtin_amdgcn_sched_barrier(0);

  int cur = 0;
#pragma unroll 1
  for (int tt = 0; tt < 32; ++tt) {
    const char* rb = lds + cur * 32768;
    int nx = cur + 2; if (nx >= 3) nx -= 3;
    char* sb = lds + nx * 32768;             // buffer of tile tt-1 (dead) -> tile tt+2
    const int ksA = (tt + 3) * 32;
    const int ksB = (tt + 2) * 32;
    // ---- phase 0: ds_read A m0-3 + B; issue A(tt+3) regs + B(tt+2) gloads ----
    bf16x8 af[4];
#pragma unroll
    for (int m = 0; m < 4; ++m) af[m] = *(const bf16x8*)(rb + offA + m * 1024);
#pragma unroll
    for (int n = 0; n < 4; ++n) bfr[n] = *(const bf16x8*)(rb + offB + n * 1024);
    if (tt < 29) {
      Ln0 = *(const f32x4*)(pAg0 + ksA);
      Ln1 = *(const f32x4*)(pAg0 + ksA + 4);
      Ln2 = *(const f32x4*)(pAg1 + ksA);
      Ln3 = *(const f32x4*)(pAg1 + ksA + 4);
    }
    if (tt < 30) {
      gload16(pB0 + ksB, sb + 16384 + t16);
      gload16(pB1 + ksB, sb + 24576 + t16);
    }
    __builtin_amdgcn_s_setprio(1);
#pragma unroll
    for (int m = 0; m < 4; ++m)
#pragma unroll
      for (int n = 0; n < 4; ++n)
        acc[m][n] = __builtin_amdgcn_mfma_f32_16x16x32_bf16(af[m], bfr[n], acc[m][n], 0, 0, 0);
    __builtin_amdgcn_s_setprio(0);
    __builtin_amdgcn_s_barrier();
    __builtin_amdgcn_sched_barrier(0);
    // ---- phase 1: ds_read A m4-7; counted vmcnt; write Lo (tile tt+2) ----
#pragma unroll
    for (int m = 0; m < 4; ++m) af[m] = *(const bf16x8*)(rb + offA + (m + 4) * 1024);
    if (tt < 29) {
      asm volatile("s_waitcnt vmcnt(6)" ::: "memory");  // Lo + prev B retired
      *(bf16x8*)(sb + t16)        = cvt8(Lo0, Lo1);
      *(bf16x8*)(sb + 8192 + t16) = cvt8(Lo2, Lo3);
    } else if (tt == 29) {
      asm volatile("s_waitcnt vmcnt(2)" ::: "memory");  // retire A(31)+B(30)
      *(bf16x8*)(sb + t16)        = cvt8(Lo0, Lo1);
      *(bf16x8*)(sb + 8192 + t16) = cvt8(Lo2, Lo3);
    } else if (tt == 30) {
      asm volatile("s_waitcnt vmcnt(0)" ::: "memory");  // B(31) resident
    }
    __builtin_amdgcn_s_setprio(1);
#pragma unroll
    for (int m = 0; m < 4; ++m)
#pragma unroll
      for (int n = 0; n < 4; ++n)
        acc[m + 4][n] = __builtin_amdgcn_mfma_f32_16x16x32_bf16(af[m], bfr[n], acc[m + 4][n], 0, 0, 0);
    __builtin_amdgcn_s_setprio(0);
    asm volatile("s_waitcnt lgkmcnt(0)" ::: "memory");  // drain ds_writes pre-barrier
    __builtin_amdgcn_s_barrier();
    __builtin_amdgcn_sched_barrier(0);
    Lo0 = Ln0; Lo1 = Ln1; Lo2 = Ln2; Lo3 = Ln3;
    cur = (cur + 1 == 3) ? 0 : cur + 1;
  }

  const int row0 = mt * 256 + wm * 128 + hi * 4;
  const int col0 = nt * 256 + wn * 64 + rsel;
  float bv[4];
#pragma unroll
  for (int n = 0; n < 4; ++n) bv[n] = bias[col0 + n * 16];
#pragma unroll
  for (int m = 0; m < 8; ++m) {
#pragma unroll
    for (int q = 0; q < 4; ++q) {
      const size_t rr = (size_t)(row0 + m * 16 + q) * 1024;
#pragma unroll
      for (int n = 0; n < 4; ++n) {
        float v = fmaxf(acc[m][n][q] + bv[n], 0.f);
        C[rr + col0 + n * 16] = (bf16_t)v;
      }
    }
  }
}

// ---------------- bf16 MLP GEMM, 256x256 tile, 8-wave (r2/r3 proven) ----------
__global__ __launch_bounds__(512, 2)
void mlp_gemm8(const bf16_t* __restrict__ A, const bf16_t* __restrict__ W,
               const float* __restrict__ bias, bf16_t* __restrict__ C,
               int Mtiles, int relu) {
  const int nwg = Mtiles * 4;
  const int cpx = nwg >> 3;
  const int wg  = ((int)blockIdx.x & 7) * cpx + ((int)blockIdx.x >> 3);
  const int mt = wg >> 2, nt = wg & 3;

  __shared__ __align__(16) char lds[131072];

  const int t    = threadIdx.x;
  const int lane = t & 63, wid = t >> 6;
  const int wm = wid >> 2, wn = wid & 3;
  const int rsel = lane & 15, hi = lane >> 4;
  const int t16 = t * 16;

  const int P0 = t16, P1 = 8192 + t16;
  const int Lg0 = P0 ^ ((P0 >> 3) & 0x30);
  const int Lg1 = P1 ^ ((P1 >> 3) & 0x30);
  const int rS0 = Lg0 >> 6, cS0 = (Lg0 & 63) >> 1;
  const int rS1 = Lg1 >> 6, cS1 = (Lg1 & 63) >> 1;
  const bf16_t* pA0 = A + (size_t)(mt * 256 + rS0) * 1024 + cS0;
  const bf16_t* pA1 = A + (size_t)(mt * 256 + rS1) * 1024 + cS1;
  const bf16_t* pB0 = W + (size_t)(nt * 256 + rS0) * 1024 + cS0;
  const bf16_t* pB1 = W + (size_t)(nt * 256 + rS1) * 1024 + cS1;

  const int kchunk = (hi ^ ((rsel >> 1) & 3)) << 4;
  const int offA = ((wm * 128 + rsel) << 6) + kchunk;
  const int offB = 16384 + ((wn * 64 + rsel) << 6) + kchunk;

  f32x4 acc[8][4] = {};
  bf16x8 bfr[4];

#pragma unroll
  for (int p = 0; p < 3; ++p) {
    char* db = lds + p * 32768;
    gload16(pA0 + p * 32, db + t16);
    gload16(pA1 + p * 32, db + 8192 + t16);
    gload16(pB0 + p * 32, db + 16384 + t16);
    gload16(pB1 + p * 32, db + 24576 + t16);
  }
  asm volatile("s_waitcnt vmcnt(8)" ::: "memory");
  __builtin_amdgcn_s_barrier();
  __builtin_amdgcn_sched_barrier(0);

#pragma unroll 1
  for (int tt = 0; tt < 32; ++tt) {
    const char* rb = lds + (tt & 3) * 32768;
    char* sb = lds + ((tt + 3) & 3) * 32768;
    const int ks = (tt + 3) * 32;
    bf16x8 af[4];
#pragma unroll
    for (int m = 0; m < 4; ++m) af[m] = *(const bf16x8*)(rb + offA + m * 1024);
#pragma unroll
    for (int n = 0; n < 4; ++n) bfr[n] = *(const bf16x8*)(rb + offB + n * 1024);
    if (tt < 29) {
      gload16(pA0 + ks, sb + t16);
      gload16(pA1 + ks, sb + 8192 + t16);
    }
    __builtin_amdgcn_s_setprio(1);
#pragma unroll
    for (int m = 0; m < 4; ++m)
#pragma unroll
      for (int n = 0; n < 4; ++n)
        acc[m][n] = __builtin_amdgcn_mfma_f32_16x16x32_bf16(af[m], bfr[n], acc[m][n], 0, 0, 0);
    __builtin_amdgcn_s_setprio(0);
    __builtin_amdgcn_s_barrier();
    __builtin_amdgcn_sched_barrier(0);
#pragma unroll
    for (int m = 0; m < 4; ++m) af[m] = *(const bf16x8*)(rb + offA + (m + 4) * 1024);
    if (tt < 29) {
      gload16(pB0 + ks, sb + 16384 + t16);
      gload16(pB1 + ks, sb + 24576 + t16);
    }
    __builtin_amdgcn_s_setprio(1);
#pragma unroll
    for (int m = 0; m < 4; ++m)
#pragma unroll
      for (int n = 0; n < 4; ++n)
        acc[m + 4][n] = __builtin_amdgcn_mfma_f32_16x16x32_bf16(af[m], bfr[n], acc[m + 4][n], 0, 0, 0);
    __builtin_amdgcn_s_setprio(0);
    if (tt < 29)       asm volatile("s_waitcnt vmcnt(8)" ::: "memory");
    else if (tt == 29) asm volatile("s_waitcnt vmcnt(4)" ::: "memory");
    else if (tt == 30) asm volatile("s_waitcnt vmcnt(0)" ::: "memory");
    __builtin_amdgcn_s_barrier();
    __builtin_amdgcn_sched_barrier(0);
  }

  const int row0 = mt * 256 + wm * 128 + hi * 4;
  const int col0 = nt * 256 + wn * 64 + rsel;
  float bv[4];
#pragma unroll
  for (int n = 0; n < 4; ++n) bv[n] = bias[col0 + n * 16];
#pragma unroll
  for (int m = 0; m < 8; ++m) {
#pragma unroll
    for (int q = 0; q < 4; ++q) {
      const size_t rr = (size_t)(row0 + m * 16 + q) * 1024;
#pragma unroll
      for (int n = 0; n < 4; ++n) {
        float v = acc[m][n][q] + bv[n];
        if (relu) v = fmaxf(v, 0.f);
        C[rr + col0 + n * 16] = (bf16_t)v;
      }
    }
  }
}

// ---------------- 128x128 split-K GEMM ----------------
__global__ __launch_bounds__(256)
void gemmK(const bf16_t* __restrict__ A, const bf16_t* __restrict__ W,
           float* __restrict__ P, int KS) {
  const int slice = (int)blockIdx.x >> 6;
  const int tl = (int)blockIdx.x & 63;
  const int mt = tl >> 3, nt = tl & 7;
  const int koff = slice * KS;

  const int f = threadIdx.x;
  const int lane = f & 63, w = f >> 6;
  const int sRow = f >> 2, sCol8 = (f & 3) * 8;

  const bf16_t* Ab = A + (size_t)mt * 128 * 1024 + (size_t)sRow * 1024 + sCol8;
  const bf16_t* Bb = W + (size_t)nt * 128 * 1024 + (size_t)sRow * 1024 + sCol8;

  __shared__ __align__(16) bf16_t sA[128 * 32];
  __shared__ __align__(16) bf16_t sB[128 * 32];
  bf16_t* sAp = sA + sRow * 32 + sCol8;
  bf16_t* sBp = sB + sRow * 32 + sCol8;

  const int wr = (w >> 1) * 64, wc = (w & 1) * 64;
  const int rsel = lane & 15, koff2 = (lane >> 4) * 8;
  const bf16_t* rA = sA + (wr + rsel) * 32 + koff2;
  const bf16_t* rB = sB + (wc + rsel) * 32 + koff2;

  f32x4 acc[4][4] = {};
  for (int kt = koff; kt < koff + KS; kt += 32) {
    __syncthreads();
    gload16(Ab + kt,             sAp);
    gload16(Ab + kt + 64 * 1024, sAp + 64 * 32);
    gload16(Bb + kt,             sBp);
    gload16(Bb + kt + 64 * 1024, sBp + 64 * 32);
    asm volatile("s_waitcnt vmcnt(0)" ::: "memory");
    __syncthreads();
    bf16x8 af[4], bfv[4];
#pragma unroll
    for (int m = 0; m < 4; ++m) af[m] = *(const bf16x8*)(rA + m * 16 * 32);
#pragma unroll
    for (int n = 0; n < 4; ++n) bfv[n] = *(const bf16x8*)(rB + n * 16 * 32);
#pragma unroll
    for (int m = 0; m < 4; ++m)
#pragma unroll
      for (int n = 0; n < 4; ++n)
        acc[m][n] = __builtin_amdgcn_mfma_f32_16x16x32_bf16(af[m], bfv[n], acc[m][n], 0, 0, 0);
  }

  float* Pb = P + (size_t)slice * 1048576;
  const int row0 = mt * 128 + wr + (lane >> 4) * 4;
  const int col0 = nt * 128 + wc + rsel;
#pragma unroll
  for (int n = 0; n < 4; ++n) {
    const int c = col0 + n * 16;
#pragma unroll
    for (int m = 0; m < 4; ++m) {
      const int r = row0 + m * 16;
#pragma unroll
      for (int q = 0; q < 4; ++q)
        Pb[(size_t)(r + q) * 1024 + c] = acc[m][n][q];
    }
  }
}

// reduce 4 G-partials -> bf16 G
__global__ __launch_bounds__(256)
void g_reduce(const float* __restrict__ Gp, bf16_t* __restrict__ GB) {
  const int i4 = blockIdx.x * 256 + threadIdx.x;
  float4 a = ((const float4*)Gp)[i4];
  float4 b = ((const float4*)(Gp + 1048576))[i4];
  float4 c = ((const float4*)(Gp + 2097152))[i4];
  float4 d = ((const float4*)(Gp + 3145728))[i4];
  bf16x4 o = { (bf16_t)(a.x + b.x + c.x + d.x), (bf16_t)(a.y + b.y + c.y + d.y),
               (bf16_t)(a.z + b.z + c.z + d.z), (bf16_t)(a.w + b.w + c.w + d.w) };
  ((bf16x4*)GB)[i4] = o;
}

// ---------------- pool split-K GEMM: U(256x1024) * W2^T, 8 K-slices ----------
__global__ __launch_bounds__(256)
void pool_gemmK(const bf16_t* __restrict__ A, const bf16_t* __restrict__ W,
                float* __restrict__ P) {
  const int slice = (int)blockIdx.x >> 4;
  const int tl = (int)blockIdx.x & 15;
  const int mt = tl >> 3, nt = tl & 7;
  const int koff = slice * 128;

  const int f = threadIdx.x;
  const int lane = f & 63, w = f >> 6;
  const int sRow = f >> 2, sCol8 = (f & 3) * 8;

  const bf16_t* Ab = A + (size_t)mt * 128 * 1024 + (size_t)sRow * 1024 + sCol8;
  const bf16_t* Bb = W + (size_t)nt * 128 * 1024 + (size_t)sRow * 1024 + sCol8;

  __shared__ __align__(16) bf16_t sA[128 * 32];
  __shared__ __align__(16) bf16_t sB[128 * 32];
  bf16_t* sAp = sA + sRow * 32 + sCol8;
  bf16_t* sBp = sB + sRow * 32 + sCol8;

  const int wr = (w >> 1) * 64, wc = (w & 1) * 64;
  const int rsel = lane & 15, koff2 = (lane >> 4) * 8;
  const bf16_t* rA = sA + (wr + rsel) * 32 + koff2;
  const bf16_t* rB = sB + (wc + rsel) * 32 + koff2;

  f32x4 acc[4][4] = {};
  for (int kt = koff; kt < koff + 128; kt += 32) {
    __syncthreads();
    gload16(Ab + kt,             sAp);
    gload16(Ab + kt + 64 * 1024, sAp + 64 * 32);
    gload16(Bb + kt,             sBp);
    gload16(Bb + kt + 64 * 1024, sBp + 64 * 32);
    asm volatile("s_waitcnt vmcnt(0)" ::: "memory");
    __syncthreads();
    bf16x8 af[4], bfv[4];
#pragma unroll
    for (int m = 0; m < 4; ++m) af[m] = *(const bf16x8*)(rA + m * 16 * 32);
#pragma unroll
    for (int n = 0; n < 4; ++n) bfv[n] = *(const bf16x8*)(rB + n * 16 * 32);
#pragma unroll
    for (int m = 0; m < 4; ++m)
#pragma unroll
      for (int n = 0; n < 4; ++n)
        acc[m][n] = __builtin_amdgcn_mfma_f32_16x16x32_bf16(af[m], bfv[n], acc[m][n], 0, 0, 0);
  }

  float* Pb = P + (size_t)slice * 262144;
  const int row0 = mt * 128 + wr + (lane >> 4) * 4;
  const int col0 = nt * 128 + wc + rsel;
#pragma unroll
  for (int n = 0; n < 4; ++n) {
    const int c = col0 + n * 16;
#pragma unroll
    for (int m = 0; m < 4; ++m) {
      const int r = row0 + m * 16;
#pragma unroll
      for (int q = 0; q < 4; ++q)
        Pb[(size_t)(r + q) * 1024 + c] = acc[m][n][q];
    }
  }
}

// reduce 8 pool partials + bias, remap rows -> d_out
__global__ __launch_bounds__(256)
void pool_reduce(const float* __restrict__ Pp, const float* __restrict__ b2,
                 float* __restrict__ out) {
  const int idx = blockIdx.x * 256 + threadIdx.x;
  const int r = idx >> 10, c = idx & 1023;
  float s = b2[c];
#pragma unroll
  for (int sl = 0; sl < 8; ++sl) s += Pp[(size_t)sl * 262144 + idx];
  const int g = r >> 6, b = r & 63;
  out[(size_t)(g >> 1) * 131072 + (size_t)b * 2048 + (g & 1) * 1024 + c] = s;
}

// ---------------- t[r] = h[r,:] . w2b ----------------
__global__ __launch_bounds__(256)
void t_kernel(const bf16_t* __restrict__ H, const float* __restrict__ w2b,
              float* __restrict__ tT1, float* __restrict__ tT2) {
  const int wv = threadIdx.x >> 6, lane = threadIdx.x & 63;
  const int r = blockIdx.x * 4 + wv;
  const bf16_t* hrow = H + (size_t)r * 1024;
  float s = 0.f;
#pragma unroll
  for (int h = 0; h < 2; ++h) {
    bf16x8 v = *(const bf16x8*)(hrow + h * 512 + lane * 8);
#pragma unroll
    for (int e = 0; e < 8; ++e) s += (float)v[e] * w2b[h * 512 + lane * 8 + e];
  }
#pragma unroll
  for (int off = 32; off; off >>= 1) s += __shfl_xor(s, off);
  if (lane == 0) {
    const int b = r & 63;
    if (r < 16384) tT1[b * L1C + (r >> 6)] = s;
    else           tT2[b * L2C + ((r - 16384) >> 6)] = s;
  }
}

// ---------------- logits: oz[b,i,j] = z1[b,i,:].h2[b,j,:] ----------------
__global__ __launch_bounds__(256)
void logits_gemm(const bf16_t* __restrict__ Y1, const bf16_t* __restrict__ Y2,
                 float* __restrict__ O) {
  const int wg = ((int)blockIdx.x & 7) * 48 + ((int)blockIdx.x >> 3);
  const int b = wg / 6, t = wg % 6;
  const int mt = t / 3, nt = t % 3;

  const int f = threadIdx.x;
  const int lane = f & 63, w = f >> 6;
  const int sRow = f >> 2, sCol8 = (f & 3) * 8;

  const int i0 = mt * 128 + sRow;
  const int i1 = i0 + 64;
  int j0 = nt * 128 + sRow;      if (j0 > L2C - 1) j0 = L2C - 1;
  int j1 = nt * 128 + sRow + 64; if (j1 > L2C - 1) j1 = L2C - 1;
  const bf16_t* A0 = Y1 + ((size_t)i0 * BC + b) * DC + sCol8;
  const bf16_t* A1 = Y1 + ((size_t)i1 * BC + b) * DC + sCol8;
  const bf16_t* B0 = Y2 + ((size_t)j0 * BC + b) * DC + sCol8;
  const bf16_t* B1 = Y2 + ((size_t)j1 * BC + b) * DC + sCol8;

  __shared__ __align__(16) bf16_t sA[128 * 32];
  __shared__ __align__(16) bf16_t sB[128 * 32];
  bf16_t* sAp = sA + sRow * 32 + sCol8;
  bf16_t* sBp = sB + sRow * 32 + sCol8;

  const int wr = (w >> 1) * 64, wc = (w & 1) * 64;
  const int rsel = lane & 15, koff = (lane >> 4) * 8;
  const bf16_t* rA = sA + (wr + rsel) * 32 + koff;
  const bf16_t* rB = sB + (wc + rsel) * 32 + koff;

  f32x4 acc[4][4] = {};
  for (int kt = 0; kt < 1024; kt += 32) {
    __syncthreads();
    gload16(A0 + kt, sAp);
    gload16(A1 + kt, sAp + 64 * 32);
    gload16(B0 + kt, sBp);
    gload16(B1 + kt, sBp + 64 * 32);
    asm volatile("s_waitcnt vmcnt(0)" ::: "memory");
    __syncthreads();
    bf16x8 af[4], bfv[4];
#pragma unroll
    for (int m = 0; m < 4; ++m) af[m] = *(const bf16x8*)(rA + m * 16 * 32);
#pragma unroll
    for (int n = 0; n < 4; ++n) bfv[n] = *(const bf16x8*)(rB + n * 16 * 32);
#pragma unroll
    for (int m = 0; m < 4; ++m)
#pragma unroll
      for (int n = 0; n < 4; ++n)
        acc[m][n] = __builtin_amdgcn_mfma_f32_16x16x32_bf16(af[m], bfv[n], acc[m][n], 0, 0, 0);
  }

  float* Ob = O + (size_t)b * L1C * L2C;
  const int row0 = mt * 128 + wr + (lane >> 4) * 4;
  const int col0 = nt * 128 + wc + rsel;
#pragma unroll
  for (int n = 0; n < 4; ++n) {
    const int c = col0 + n * 16;
    if (c < L2C) {
#pragma unroll
      for (int m = 0; m < 4; ++m) {
        const int r = row0 + m * 16;
#pragma unroll
        for (int q = 0; q < 4; ++q)
          Ob[(size_t)(r + q) * L2C + c] = acc[m][n][q];
      }
    }
  }
}

// ---------------- softmax stats (with rank-1 terms t1,t2) ----------------
__global__ __launch_bounds__(256)
void row_stats(const float* __restrict__ O, const float* __restrict__ tT2,
               float* __restrict__ rowM, float* __restrict__ rowInv) {
  const int gw = blockIdx.x * 4 + (threadIdx.x >> 6);
  const int lane = threadIdx.x & 63;
  const int b = gw >> 8;
  const float* row = O + (size_t)gw * L2C;
  const float* t2 = tT2 + b * L2C;
  float v[5];
  float m = -1e30f;
#pragma unroll
  for (int t = 0; t < 5; ++t) { v[t] = row[t * 64 + lane] + t2[t * 64 + lane]; m = fmaxf(m, v[t]); }
#pragma unroll
  for (int off = 32; off; off >>= 1) m = fmaxf(m, __shfl_xor(m, off));
  float s = 0.f;
#pragma unroll
  for (int t = 0; t < 5; ++t) s += __expf(v[t] - m);
#pragma unroll
  for (int off = 32; off; off >>= 1) s += __shfl_xor(s, off);
  if (lane == 0) { rowM[gw] = m; rowInv[gw] = 1.f / s; }
}

__global__ __launch_bounds__(256)
void col_stats_c1(const float* __restrict__ O, const float* __restrict__ tT1,
                  const float* __restrict__ tT2,
                  const float* __restrict__ rowM, const float* __restrict__ rowInv,
                  float* __restrict__ colM, float* __restrict__ colInv,
                  float* __restrict__ c1) {
  const int b = blockIdx.x / 5, jb = blockIdx.x % 5;
  const int jl = threadIdx.x & 63, ig = threadIdx.x >> 6;
  const int j = jb * 64 + jl;
  const float* Ob = O + (size_t)b * L1C * L2C + j;
  const float* rM = rowM + b * L1C;
  const float* rI = rowInv + b * L1C;
  const float* t1 = tT1 + b * L1C;
  const float t2j = tT2[b * L2C + j];
  float m = -1e30f, s = 0.f, cp = 0.f;
  for (int i = ig; i < L1C; i += 4) {
    float ov = Ob[(size_t)i * L2C];
    float v = ov + t1[i];
    float mn = fmaxf(m, v);
    s = s * __expf(m - mn) + __expf(v - mn);
    m = mn;
    cp += __expf(ov + t2j - rM[i]) * rI[i];
  }
  __shared__ float sm[4][64], ss[4][64], sc[4][64];
  sm[ig][jl] = m; ss[ig][jl] = s; sc[ig][jl] = cp;
  __syncthreads();
  if (ig == 0) {
    for (int g = 1; g < 4; ++g) {
      float mg = sm[g][jl], sg = ss[g][jl];
      float mn = fmaxf(m, mg);
      s = s * __expf(m - mn) + sg * __expf(mg - mn);
      m = mn;
      cp += sc[g][jl];
    }
    colM[b * L2C + j] = m;
    colInv[b * L2C + j] = 1.f / s;
    c1[b * L2C + j] = cp;
  }
}

__global__ __launch_bounds__(256)
void c2_kernel(const float* __restrict__ O, const float* __restrict__ tT1,
               const float* __restrict__ colM, const float* __restrict__ colInv,
               float* __restrict__ c2) {
  const int gw = blockIdx.x * 4 + (threadIdx.x >> 6);
  const int lane = threadIdx.x & 63;
  const int b = gw >> 8;
  const float* row = O + (size_t)gw * L2C;
  const float* cM = colM + b * L2C;
  const float* cI = colInv + b * L2C;
  const float t1i = tT1[b * L1C + (gw & 255)];
  float s = 0.f;
#pragma unroll
  for (int t = 0; t < 5; ++t) {
    const int j = t * 64 + lane;
    s += __expf(row[j] + t1i - cM[j]) * cI[j];
  }
#pragma unroll
  for (int off = 32; off; off >>= 1) s += __shfl_xor(s, off);
  if (lane == 0) c2[gw] = s;
}

// ---------------- weighted h-sums -> U (256x1024 bf16) ----------------
__global__ __launch_bounds__(256)
void u_kernel(const bf16_t* __restrict__ H, const float* __restrict__ c1,
              const float* __restrict__ c2, bf16_t* __restrict__ Ub) {
  const int b = blockIdx.x >> 2;
  const int d = (blockIdx.x & 3) * 256 + threadIdx.x;
  const bf16_t* H2 = H + (size_t)L1C * BC * DC;
  float s1 = 0.f, s1c = 0.f, s2 = 0.f, s2c = 0.f;
  const float* c2b = c2 + b * L1C;
  for (int i = 0; i < L1C; ++i) {
    float v = (float)H[((size_t)i * BC + b) * DC + d];
    s1 += v; s1c += c2b[i] * v;
  }
  const float* c1b = c1 + b * L2C;
  for (int j = 0; j < L2C; ++j) {
    float v = (float)H2[((size_t)j * BC + b) * DC + d];
    s2 += v; s2c += c1b[j] * v;
  }
  Ub[(size_t)(0 * 64 + b) * 1024 + d] = (bf16_t)(s1  * (1.f / L1C));
  Ub[(size_t)(1 * 64 + b) * 1024 + d] = (bf16_t)(s2c * (1.f / L1C));
  Ub[(size_t)(2 * 64 + b) * 1024 + d] = (bf16_t)(s2  * (1.f / L2C));
  Ub[(size_t)(3 * 64 + b) * 1024 + d] = (bf16_t)(s1c * (1.f / L2C));
}

// ---------------- host ----------------
extern "C" void kernel_launch(void* const* d_in, const int* in_sizes, int n_in,
                              void* d_out, int out_size, void* d_ws, size_t ws_size,
                              hipStream_t stream) {
  const float* r1 = (const float*)d_in[0];
  const float* r2 = (const float*)d_in[1];
  const float* W1 = (const float*)d_in[2];
  const float* b1 = (const float*)d_in[3];
  const float* W2 = (const float*)d_in[4];
  const float* b2 = (const float*)d_in[5];
  float* out = (float*)d_out;
  char* ws = (char*)d_ws;

  const size_t M1 = (size_t)L1C * BC;   // 16384
  const size_t M2 = (size_t)L2C * BC;   // 20480
  const size_t Mt = M1 + M2;            // 36864

  size_t off = 0;
  bf16_t* XB  = (bf16_t*)(ws + off); off += Mt * DC * 2;        // 72MB: Z + O + Gpart
  bf16_t* HB  = (bf16_t*)(ws + off); off += Mt * DC * 2;        // 72MB, h; head reused as Ppart
  bf16_t* WB1 = (bf16_t*)(ws + off); off += (size_t)DC * DC * 2;
  bf16_t* WB2 = (bf16_t*)(ws + off); off += (size_t)DC * DC * 2;
  bf16_t* W2T = (bf16_t*)(ws + off); off += (size_t)DC * DC * 2;
  bf16_t* GB  = (bf16_t*)(ws + off); off += (size_t)DC * DC * 2;
  float* w2b   = (float*)(ws + off); off += 4096;
  float* zb    = (float*)(ws + off); off += 4096;
  float* tT1   = (float*)(ws + off); off += BC * L1C * 4;
  float* tT2   = (float*)(ws + off); off += BC * L2C * 4;
  float* rowM  = (float*)(ws + off); off += BC * L1C * 4;
  float* rowIv = (float*)(ws + off); off += BC * L1C * 4;
  float* colM  = (float*)(ws + off); off += BC * L2C * 4;
  float* colIv = (float*)(ws + off); off += BC * L2C * 4;
  float* c1v   = (float*)(ws + off); off += BC * L2C * 4;
  float* c2v   = (float*)(ws + off); off += BC * L1C * 4;
  bf16_t* Ub   = (bf16_t*)(ws + off); off += 256 * DC * 2;

  bf16_t* Z = XB;                                   // 16384x1024 bf16 (32MB)
  float*  O = (float*)((char*)XB + 35651584);       // 21MB logits
  float*  Gpart = (float*)((char*)XB + 58720256);   // 16MB (4 slices)
  float*  Ppart = (float*)HB;                       // 8MB (8 slices), HB dead then
  bf16_t* H2 = HB + M1 * DC;

  // 1. weight prep only (r1/r2 consumed fp32-direct by GEMM1)
  conv_kernel<<<512, 256, 0, stream>>>(W1, WB1, (int)((size_t)DC * DC / 4));
  conv_kernel<<<512, 256, 0, stream>>>(W2, WB2, (int)((size_t)DC * DC / 4));
  w2t_kernel<<<dim3(32, 32), 256, 0, stream>>>(W2, W2T);
  wb_kernel<<<64, 256, 0, stream>>>(W2, b2, w2b);
  (void)hipMemsetAsync(zb, 0, 4096, stream);

  // 2. h = relu(x W1^T + b1), A fp32-direct, deep reg-staged pipeline
  mlp_gemm_f32a<<<576, 512, 0, stream>>>(r1, r2, WB1, b1, HB, 144);

  // 3. G = W2^T W2 split-K;  t = h . (W2^T b2)
  gemmK<<<256, 256, 0, stream>>>(W2T, W2T, Gpart, 256);
  t_kernel<<<9216, 256, 0, stream>>>(HB, w2b, tT1, tT2);
  g_reduce<<<1024, 256, 0, stream>>>(Gpart, GB);

  // 4. z1 = h1 G
  mlp_gemm8<<<256, 512, 0, stream>>>(HB, GB, zb, Z, 64, 0);

  // 5. oz[b,i,j] = z1 . h2
  logits_gemm<<<384, 256, 0, stream>>>(Z, H2, O);

  // 6. softmax stats with rank-1 corrections
  row_stats<<<4096, 256, 0, stream>>>(O, tT2, rowM, rowIv);
  col_stats_c1<<<320, 256, 0, stream>>>(O, tT1, tT2, rowM, rowIv, colM, colIv, c1v);
  c2_kernel<<<4096, 256, 0, stream>>>(O, tT1, colM, colIv, c2v);

  // 7. weighted h pools -> U;  out = U W2^T + b2, split-K + reduce
  u_kernel<<<256, 256, 0, stream>>>(HB, c1v, c2v, Ub);
  pool_gemmK<<<128, 256, 0, stream>>>(Ub, WB2, Ppart);
  pool_reduce<<<1024, 256, 0, stream>>>(Ppart, b2, out);
}

// Round 10
// 303.962 us; speedup vs baseline: 1.1468x; 1.0984x over previous
//
#include <hip/hip_runtime.h>
#include <stdint.h>

#define L1C 256
#define L2C 320
#define BC  64
#define DC  1024

typedef __bf16 bf16_t;
typedef __bf16 bf16x8 __attribute__((ext_vector_type(8)));
typedef __bf16 bf16x4 __attribute__((ext_vector_type(4)));
typedef float  f32x4  __attribute__((ext_vector_type(4)));

__device__ __forceinline__ void gload16(const void* g, void* l) {
  __builtin_amdgcn_global_load_lds(
      (__attribute__((address_space(1))) void*)g,
      (__attribute__((address_space(3))) void*)l, 16, 0, 0);
}

// ---------------- fp32 -> bf16 convert (weights only) ----------------
__global__ __launch_bounds__(256)
void conv_kernel(const float* __restrict__ src, bf16_t* __restrict__ dst, int n4) {
  int i = blockIdx.x * 256 + threadIdx.x;
  const int stride = gridDim.x * 256;
  for (; i < n4; i += stride) {
    float4 v = ((const float4*)src)[i];
    bf16x4 o = { (__bf16)v.x, (__bf16)v.y, (__bf16)v.z, (__bf16)v.w };
    ((bf16x4*)dst)[i] = o;
  }
}

// ---------------- transpose W2 (fp32 1024x1024) -> bf16 W2T ----------------
__global__ __launch_bounds__(256)
void w2t_kernel(const float* __restrict__ W2, bf16_t* __restrict__ W2T) {
  __shared__ float tile[32][33];
  const int tx = threadIdx.x & 31, ty = threadIdx.x >> 5;  // 32 x 8
  const int x0 = blockIdx.x * 32, y0 = blockIdx.y * 32;
#pragma unroll
  for (int k = 0; k < 32; k += 8)
    tile[ty + k][tx] = W2[(size_t)(y0 + ty + k) * 1024 + x0 + tx];
  __syncthreads();
#pragma unroll
  for (int k = 0; k < 32; k += 8)
    W2T[(size_t)(x0 + ty + k) * 1024 + y0 + tx] = (bf16_t)tile[tx][ty + k];
}

// ---------------- w2b[d] = sum_k W2[k,d] * b2[k] ----------------
__global__ __launch_bounds__(256)
void wb_kernel(const float* __restrict__ W2, const float* __restrict__ b2,
               float* __restrict__ w2b) {
  const int dt = threadIdx.x & 15, kg = threadIdx.x >> 4;   // 16 d x 16 kgroups
  const int d = blockIdx.x * 16 + dt;
  float s = 0.f;
  for (int k = kg * 64; k < kg * 64 + 64; ++k)
    s += W2[(size_t)k * 1024 + d] * b2[k];
  __shared__ float red[16][17];
  red[kg][dt] = s;
  __syncthreads();
  if (kg == 0) {
    float t = 0.f;
#pragma unroll
    for (int g = 0; g < 16; ++g) t += red[g][dt];
    w2b[d] = t;
  }
}

// ---------------- GEMM1: fp32-A 256x256-tile 8-wave, 3-deep LDS ring -------
// (R6 verbatim — empirically fastest GEMM1 variant.)
// C[m,n] = relu(sum_k A[m,k]*W[n,k] + bias[n]); A fp32 via global_load_lds.
// Fused t-partials: tpart[(nt*4+wn)*36864 + row] = per-wave 64-col partial of
// sum_c bf16(C[row,c])*w2b[c]  (each slot written exactly once; t_red sums 16).
__global__ __launch_bounds__(512, 2)
void mlp_gemm_f32a(const float* __restrict__ R1, const float* __restrict__ R2,
                   const bf16_t* __restrict__ W, const float* __restrict__ bias,
                   bf16_t* __restrict__ C, int Mtiles,
                   const float* __restrict__ w2b, float* __restrict__ tpart) {
  const int nwg = Mtiles * 4;
  const int cpx = nwg >> 3;
  const int wg  = ((int)blockIdx.x & 7) * cpx + ((int)blockIdx.x >> 3);
  const int mt = wg >> 2, nt = wg & 3;

  __shared__ __align__(16) char lds[147456];   // 3 bufs x (A 32KB + B 16KB)

  const int t    = threadIdx.x;
  const int lane = t & 63, wid = t >> 6;
  const int wm = wid >> 2, wn = wid & 3;
  const int rsel = lane & 15, hi = lane >> 4;
  const int t16 = t * 16;

  // --- A staging source (fp32, inverse-swizzled 16B granules) ---
  const int rT = t >> 3;                       // row within 64-row group
  const int gT = (t & 7) ^ (rT & 7);           // logical granule (4 fp32)
  const float* Abase = (mt < 64) ? (R1 + (size_t)mt * 256 * 1024)
                                 : (R2 + (size_t)(mt - 64) * 256 * 1024);
  const float* pA[4];
#pragma unroll
  for (int l = 0; l < 4; ++l)
    pA[l] = Abase + (size_t)(l * 64 + rT) * 1024 + gT * 4;

  // --- B staging source (bf16, proven swizzle) ---
  const int P0 = t16, P1 = 8192 + t16;
  const int Lg0 = P0 ^ ((P0 >> 3) & 0x30);
  const int Lg1 = P1 ^ ((P1 >> 3) & 0x30);
  const bf16_t* pB0 = W + (size_t)(nt * 256 + (Lg0 >> 6)) * 1024 + ((Lg0 & 63) >> 1);
  const bf16_t* pB1 = W + (size_t)(nt * 256 + (Lg1 >> 6)) * 1024 + ((Lg1 & 63) >> 1);

  // --- ds_read addressing ---
  const int rowA = wm * 128 + rsel;
  const int offA0 = (rowA << 7) + (((2 * hi)     ^ (rsel & 7)) << 4);
  const int offA1 = (rowA << 7) + (((2 * hi + 1) ^ (rsel & 7)) << 4);
  const int kchunk = (hi ^ ((rsel >> 1) & 3)) << 4;
  const int offB = 32768 + ((wn * 64 + rsel) << 6) + kchunk;

  f32x4 acc[8][4] = {};
  bf16x8 bfr[4];

  // prologue: stage tiles 0,1
#pragma unroll
  for (int p = 0; p < 2; ++p) {
    char* db = lds + p * 49152;
#pragma unroll
    for (int l = 0; l < 4; ++l) gload16(pA[l] + p * 32, db + l * 8192 + t16);
    gload16(pB0 + p * 32, db + 32768 + t16);
    gload16(pB1 + p * 32, db + 40960 + t16);
  }
  asm volatile("s_waitcnt vmcnt(6)" ::: "memory");  // tile 0 resident
  __builtin_amdgcn_s_barrier();
  __builtin_amdgcn_sched_barrier(0);

  int cur = 0;
#pragma unroll 1
  for (int tt = 0; tt < 32; ++tt) {
    const char* rb = lds + cur * 49152;
    int nx = cur + 2; if (nx >= 3) nx -= 3;
    char* sb = lds + nx * 49152;               // buffer of tile tt-1 (free)
    const int ks = (tt + 2) * 32;
    // ---- phase 0: A frags m0-3 + all B frags; stage next A; MFMA quad 0 ----
    bf16x8 af[4];
#pragma unroll
    for (int m = 0; m < 4; ++m) {
      f32x4 a0 = *(const f32x4*)(rb + offA0 + m * 2048);
      f32x4 a1 = *(const f32x4*)(rb + offA1 + m * 2048);
      af[m] = bf16x8{ (bf16_t)a0[0], (bf16_t)a0[1], (bf16_t)a0[2], (bf16_t)a0[3],
                      (bf16_t)a1[0], (bf16_t)a1[1], (bf16_t)a1[2], (bf16_t)a1[3] };
    }
#pragma unroll
    for (int n = 0; n < 4; ++n) bfr[n] = *(const bf16x8*)(rb + offB + n * 1024);
    if (tt < 30) {
#pragma unroll
      for (int l = 0; l < 4; ++l) gload16(pA[l] + ks, sb + l * 8192 + t16);
    }
    __builtin_amdgcn_s_setprio(1);
#pragma unroll
    for (int m = 0; m < 4; ++m)
#pragma unroll
      for (int n = 0; n < 4; ++n)
        acc[m][n] = __builtin_amdgcn_mfma_f32_16x16x32_bf16(af[m], bfr[n], acc[m][n], 0, 0, 0);
    __builtin_amdgcn_s_setprio(0);
    __builtin_amdgcn_s_barrier();
    __builtin_amdgcn_sched_barrier(0);
    // ---- phase 1: A frags m4-7; stage next B; MFMA quad 1 ----
#pragma unroll
    for (int m = 0; m < 4; ++m) {
      f32x4 a0 = *(const f32x4*)(rb + offA0 + (m + 4) * 2048);
      f32x4 a1 = *(const f32x4*)(rb + offA1 + (m + 4) * 2048);
      af[m] = bf16x8{ (bf16_t)a0[0], (bf16_t)a0[1], (bf16_t)a0[2], (bf16_t)a0[3],
                      (bf16_t)a1[0], (bf16_t)a1[1], (bf16_t)a1[2], (bf16_t)a1[3] };
    }
    if (tt < 30) {
      gload16(pB0 + ks, sb + 32768 + t16);
      gload16(pB1 + ks, sb + 40960 + t16);
    }
    __builtin_amdgcn_s_setprio(1);
#pragma unroll
    for (int m = 0; m < 4; ++m)
#pragma unroll
      for (int n = 0; n < 4; ++n)
        acc[m + 4][n] = __builtin_amdgcn_mfma_f32_16x16x32_bf16(af[m], bfr[n], acc[m + 4][n], 0, 0, 0);
    __builtin_amdgcn_s_setprio(0);
    if (tt < 30)       asm volatile("s_waitcnt vmcnt(6)" ::: "memory");
    else if (tt == 30) asm volatile("s_waitcnt vmcnt(0)" ::: "memory");
    __builtin_amdgcn_s_barrier();
    __builtin_amdgcn_sched_barrier(0);
    cur = (cur + 1 == 3) ? 0 : cur + 1;
  }

  const int row0 = mt * 256 + wm * 128 + hi * 4;
  const int col0 = nt * 256 + wn * 64 + rsel;
  float bv[4];
#pragma unroll
  for (int n = 0; n < 4; ++n) bv[n] = bias[col0 + n * 16];
#pragma unroll
  for (int m = 0; m < 8; ++m) {
#pragma unroll
    for (int q = 0; q < 4; ++q) {
      const size_t rr = (size_t)(row0 + m * 16 + q) * 1024;
#pragma unroll
      for (int n = 0; n < 4; ++n) {
        float v = fmaxf(acc[m][n][q] + bv[n], 0.f);
        C[rr + col0 + n * 16] = (bf16_t)v;
      }
    }
  }

  // fused t-partials: per-(nt,wn) slice, each slot written exactly once
  {
    float wv[4];
#pragma unroll
    for (int n = 0; n < 4; ++n) wv[n] = w2b[col0 + n * 16];
    float* tp = tpart + (size_t)(nt * 4 + wn) * 36864;
#pragma unroll
    for (int m = 0; m < 8; ++m) {
#pragma unroll
      for (int q = 0; q < 4; ++q) {
        float s = 0.f;
#pragma unroll
        for (int n = 0; n < 4; ++n) {
          float v = fmaxf(acc[m][n][q] + bv[n], 0.f);
          v = (float)(bf16_t)v;
          s += v * wv[n];
        }
        s += __shfl_xor(s, 1);
        s += __shfl_xor(s, 2);
        s += __shfl_xor(s, 4);
        s += __shfl_xor(s, 8);
        if (rsel == 0)
          tp[row0 + m * 16 + q] = s;
      }
    }
  }
}

// reduce 16 t-partials -> transposed tT1/tT2
__global__ __launch_bounds__(256)
void t_red(const float* __restrict__ tp, float* __restrict__ tT1,
           float* __restrict__ tT2) {
  const int r = blockIdx.x * 256 + threadIdx.x;    // 144 blocks
  float s = 0.f;
#pragma unroll
  for (int k = 0; k < 16; ++k) s += tp[(size_t)k * 36864 + r];
  if (r < 16384) tT1[(r & 63) * L1C + (r >> 6)] = s;
  else {
    const int r2 = r - 16384;
    tT2[(r2 & 63) * L2C + (r2 >> 6)] = s;
  }
}

// ---------------- bf16 MLP GEMM, 256x256 tile, 8-wave (r2/r3 proven) ----------
__global__ __launch_bounds__(512, 2)
void mlp_gemm8(const bf16_t* __restrict__ A, const bf16_t* __restrict__ W,
               const float* __restrict__ bias, bf16_t* __restrict__ C,
               int Mtiles, int relu) {
  const int nwg = Mtiles * 4;
  const int cpx = nwg >> 3;
  const int wg  = ((int)blockIdx.x & 7) * cpx + ((int)blockIdx.x >> 3);
  const int mt = wg >> 2, nt = wg & 3;

  __shared__ __align__(16) char lds[131072];

  const int t    = threadIdx.x;
  const int lane = t & 63, wid = t >> 6;
  const int wm = wid >> 2, wn = wid & 3;
  const int rsel = lane & 15, hi = lane >> 4;
  const int t16 = t * 16;

  const int P0 = t16, P1 = 8192 + t16;
  const int Lg0 = P0 ^ ((P0 >> 3) & 0x30);
  const int Lg1 = P1 ^ ((P1 >> 3) & 0x30);
  const int rS0 = Lg0 >> 6, cS0 = (Lg0 & 63) >> 1;
  const int rS1 = Lg1 >> 6, cS1 = (Lg1 & 63) >> 1;
  const bf16_t* pA0 = A + (size_t)(mt * 256 + rS0) * 1024 + cS0;
  const bf16_t* pA1 = A + (size_t)(mt * 256 + rS1) * 1024 + cS1;
  const bf16_t* pB0 = W + (size_t)(nt * 256 + rS0) * 1024 + cS0;
  const bf16_t* pB1 = W + (size_t)(nt * 256 + rS1) * 1024 + cS1;

  const int kchunk = (hi ^ ((rsel >> 1) & 3)) << 4;
  const int offA = ((wm * 128 + rsel) << 6) + kchunk;
  const int offB = 16384 + ((wn * 64 + rsel) << 6) + kchunk;

  f32x4 acc[8][4] = {};
  bf16x8 bfr[4];

#pragma unroll
  for (int p = 0; p < 3; ++p) {
    char* db = lds + p * 32768;
    gload16(pA0 + p * 32, db + t16);
    gload16(pA1 + p * 32, db + 8192 + t16);
    gload16(pB0 + p * 32, db + 16384 + t16);
    gload16(pB1 + p * 32, db + 24576 + t16);
  }
  asm volatile("s_waitcnt vmcnt(8)" ::: "memory");
  __builtin_amdgcn_s_barrier();
  __builtin_amdgcn_sched_barrier(0);

#pragma unroll 1
  for (int tt = 0; tt < 32; ++tt) {
    const char* rb = lds + (tt & 3) * 32768;
    char* sb = lds + ((tt + 3) & 3) * 32768;
    const int ks = (tt + 3) * 32;
    bf16x8 af[4];
#pragma unroll
    for (int m = 0; m < 4; ++m) af[m] = *(const bf16x8*)(rb + offA + m * 1024);
#pragma unroll
    for (int n = 0; n < 4; ++n) bfr[n] = *(const bf16x8*)(rb + offB + n * 1024);
    if (tt < 29) {
      gload16(pA0 + ks, sb + t16);
      gload16(pA1 + ks, sb + 8192 + t16);
    }
    __builtin_amdgcn_s_setprio(1);
#pragma unroll
    for (int m = 0; m < 4; ++m)
#pragma unroll
      for (int n = 0; n < 4; ++n)
        acc[m][n] = __builtin_amdgcn_mfma_f32_16x16x32_bf16(af[m], bfr[n], acc[m][n], 0, 0, 0);
    __builtin_amdgcn_s_setprio(0);
    __builtin_amdgcn_s_barrier();
    __builtin_amdgcn_sched_barrier(0);
#pragma unroll
    for (int m = 0; m < 4; ++m) af[m] = *(const bf16x8*)(rb + offA + (m + 4) * 1024);
    if (tt < 29) {
      gload16(pB0 + ks, sb + 16384 + t16);
      gload16(pB1 + ks, sb + 24576 + t16);
    }
    __builtin_amdgcn_s_setprio(1);
#pragma unroll
    for (int m = 0; m < 4; ++m)
#pragma unroll
      for (int n = 0; n < 4; ++n)
        acc[m + 4][n] = __builtin_amdgcn_mfma_f32_16x16x32_bf16(af[m], bfr[n], acc[m + 4][n], 0, 0, 0);
    __builtin_amdgcn_s_setprio(0);
    if (tt < 29)       asm volatile("s_waitcnt vmcnt(8)" ::: "memory");
    else if (tt == 29) asm volatile("s_waitcnt vmcnt(4)" ::: "memory");
    else if (tt == 30) asm volatile("s_waitcnt vmcnt(0)" ::: "memory");
    __builtin_amdgcn_s_barrier();
    __builtin_amdgcn_sched_barrier(0);
  }

  const int row0 = mt * 256 + wm * 128 + hi * 4;
  const int col0 = nt * 256 + wn * 64 + rsel;
  float bv[4];
#pragma unroll
  for (int n = 0; n < 4; ++n) bv[n] = bias[col0 + n * 16];
#pragma unroll
  for (int m = 0; m < 8; ++m) {
#pragma unroll
    for (int q = 0; q < 4; ++q) {
      const size_t rr = (size_t)(row0 + m * 16 + q) * 1024;
#pragma unroll
      for (int n = 0; n < 4; ++n) {
        float v = acc[m][n][q] + bv[n];
        if (relu) v = fmaxf(v, 0.f);
        C[rr + col0 + n * 16] = (bf16_t)v;
      }
    }
  }
}

// ---------------- 128x128 split-K GEMM ----------------
__global__ __launch_bounds__(256)
void gemmK(const bf16_t* __restrict__ A, const bf16_t* __restrict__ W,
           float* __restrict__ P, int KS) {
  const int slice = (int)blockIdx.x >> 6;
  const int tl = (int)blockIdx.x & 63;
  const int mt = tl >> 3, nt = tl & 7;
  const int koff = slice * KS;

  const int f = threadIdx.x;
  const int lane = f & 63, w = f >> 6;
  const int sRow = f >> 2, sCol8 = (f & 3) * 8;

  const bf16_t* Ab = A + (size_t)mt * 128 * 1024 + (size_t)sRow * 1024 + sCol8;
  const bf16_t* Bb = W + (size_t)nt * 128 * 1024 + (size_t)sRow * 1024 + sCol8;

  __shared__ __align__(16) bf16_t sA[128 * 32];
  __shared__ __align__(16) bf16_t sB[128 * 32];
  bf16_t* sAp = sA + sRow * 32 + sCol8;
  bf16_t* sBp = sB + sRow * 32 + sCol8;

  const int wr = (w >> 1) * 64, wc = (w & 1) * 64;
  const int rsel = lane & 15, koff2 = (lane >> 4) * 8;
  const bf16_t* rA = sA + (wr + rsel) * 32 + koff2;
  const bf16_t* rB = sB + (wc + rsel) * 32 + koff2;

  f32x4 acc[4][4] = {};
  for (int kt = koff; kt < koff + KS; kt += 32) {
    __syncthreads();
    gload16(Ab + kt,             sAp);
    gload16(Ab + kt + 64 * 1024, sAp + 64 * 32);
    gload16(Bb + kt,             sBp);
    gload16(Bb + kt + 64 * 1024, sBp + 64 * 32);
    asm volatile("s_waitcnt vmcnt(0)" ::: "memory");
    __syncthreads();
    bf16x8 af[4], bfv[4];
#pragma unroll
    for (int m = 0; m < 4; ++m) af[m] = *(const bf16x8*)(rA + m * 16 * 32);
#pragma unroll
    for (int n = 0; n < 4; ++n) bfv[n] = *(const bf16x8*)(rB + n * 16 * 32);
#pragma unroll
    for (int m = 0; m < 4; ++m)
#pragma unroll
      for (int n = 0; n < 4; ++n)
        acc[m][n] = __builtin_amdgcn_mfma_f32_16x16x32_bf16(af[m], bfv[n], acc[m][n], 0, 0, 0);
  }

  float* Pb = P + (size_t)slice * 1048576;
  const int row0 = mt * 128 + wr + (lane >> 4) * 4;
  const int col0 = nt * 128 + wc + rsel;
#pragma unroll
  for (int n = 0; n < 4; ++n) {
    const int c = col0 + n * 16;
#pragma unroll
    for (int m = 0; m < 4; ++m) {
      const int r = row0 + m * 16;
#pragma unroll
      for (int q = 0; q < 4; ++q)
        Pb[(size_t)(r + q) * 1024 + c] = acc[m][n][q];
    }
  }
}

// reduce 4 G-partials -> bf16 G
__global__ __launch_bounds__(256)
void g_reduce(const float* __restrict__ Gp, bf16_t* __restrict__ GB) {
  const int i4 = blockIdx.x * 256 + threadIdx.x;
  float4 a = ((const float4*)Gp)[i4];
  float4 b = ((const float4*)(Gp + 1048576))[i4];
  float4 c = ((const float4*)(Gp + 2097152))[i4];
  float4 d = ((const float4*)(Gp + 3145728))[i4];
  bf16x4 o = { (bf16_t)(a.x + b.x + c.x + d.x), (bf16_t)(a.y + b.y + c.y + d.y),
               (bf16_t)(a.z + b.z + c.z + d.z), (bf16_t)(a.w + b.w + c.w + d.w) };
  ((bf16x4*)GB)[i4] = o;
}

// ---------------- pool split-K GEMM: U(256x1024) * W2^T, 8 K-slices ----------
__global__ __launch_bounds__(256)
void pool_gemmK(const bf16_t* __restrict__ A, const bf16_t* __restrict__ W,
                float* __restrict__ P) {
  const int slice = (int)blockIdx.x >> 4;
  const int tl = (int)blockIdx.x & 15;
  const int mt = tl >> 3, nt = tl & 7;
  const int koff = slice * 128;

  const int f = threadIdx.x;
  const int lane = f & 63, w = f >> 6;
  const int sRow = f >> 2, sCol8 = (f & 3) * 8;

  const bf16_t* Ab = A + (size_t)mt * 128 * 1024 + (size_t)sRow * 1024 + sCol8;
  const bf16_t* Bb = W + (size_t)nt * 128 * 1024 + (size_t)sRow * 1024 + sCol8;

  __shared__ __align__(16) bf16_t sA[128 * 32];
  __shared__ __align__(16) bf16_t sB[128 * 32];
  bf16_t* sAp = sA + sRow * 32 + sCol8;
  bf16_t* sBp = sB + sRow * 32 + sCol8;

  const int wr = (w >> 1) * 64, wc = (w & 1) * 64;
  const int rsel = lane & 15, koff2 = (lane >> 4) * 8;
  const bf16_t* rA = sA + (wr + rsel) * 32 + koff2;
  const bf16_t* rB = sB + (wc + rsel) * 32 + koff2;

  f32x4 acc[4][4] = {};
  for (int kt = koff; kt < koff + 128; kt += 32) {
    __syncthreads();
    gload16(Ab + kt,             sAp);
    gload16(Ab + kt + 64 * 1024, sAp + 64 * 32);
    gload16(Bb + kt,             sBp);
    gload16(Bb + kt + 64 * 1024, sBp + 64 * 32);
    asm volatile("s_waitcnt vmcnt(0)" ::: "memory");
    __syncthreads();
    bf16x8 af[4], bfv[4];
#pragma unroll
    for (int m = 0; m < 4; ++m) af[m] = *(const bf16x8*)(rA + m * 16 * 32);
#pragma unroll
    for (int n = 0; n < 4; ++n) bfv[n] = *(const bf16x8*)(rB + n * 16 * 32);
#pragma unroll
    for (int m = 0; m < 4; ++m)
#pragma unroll
      for (int n = 0; n < 4; ++n)
        acc[m][n] = __builtin_amdgcn_mfma_f32_16x16x32_bf16(af[m], bfv[n], acc[m][n], 0, 0, 0);
  }

  float* Pb = P + (size_t)slice * 262144;
  const int row0 = mt * 128 + wr + (lane >> 4) * 4;
  const int col0 = nt * 128 + wc + rsel;
#pragma unroll
  for (int n = 0; n < 4; ++n) {
    const int c = col0 + n * 16;
#pragma unroll
    for (int m = 0; m < 4; ++m) {
      const int r = row0 + m * 16;
#pragma unroll
      for (int q = 0; q < 4; ++q)
        Pb[(size_t)(r + q) * 1024 + c] = acc[m][n][q];
    }
  }
}

// reduce 8 pool partials + bias, remap rows -> d_out
__global__ __launch_bounds__(256)
void pool_reduce(const float* __restrict__ Pp, const float* __restrict__ b2,
                 float* __restrict__ out) {
  const int idx = blockIdx.x * 256 + threadIdx.x;
  const int r = idx >> 10, c = idx & 1023;
  float s = b2[c];
#pragma unroll
  for (int sl = 0; sl < 8; ++sl) s += Pp[(size_t)sl * 262144 + idx];
  const int g = r >> 6, b = r & 63;
  out[(size_t)(g >> 1) * 131072 + (size_t)b * 2048 + (g & 1) * 1024 + c] = s;
}

// ---------------- logits: oz[b,i,j] = z1[b,i,:].h2[b,j,:] ----------------
// Ring-4 counted-vmcnt K-loop + proven XOR swizzle (conflict-free ds_read).
__global__ __launch_bounds__(256)
void logits_gemm(const bf16_t* __restrict__ Y1, const bf16_t* __restrict__ Y2,
                 float* __restrict__ O) {
  const int wg = ((int)blockIdx.x & 7) * 48 + ((int)blockIdx.x >> 3);
  const int b = wg / 6, t6 = wg % 6;
  const int mt = t6 / 3, nt = t6 % 3;

  __shared__ __align__(16) char lds[65536];    // 4 bufs x (A 8KB + B 8KB)

  const int t = threadIdx.x;
  const int lane = t & 63, w = t >> 6;
  const int sRow = t >> 2;
  const int sCol8 = (((t & 3) ^ ((t >> 3) & 3))) * 8;   // pre-swizzled source chunk
  const int t16 = t * 16;

  const int i0 = mt * 128 + sRow;
  const int i1 = i0 + 64;
  int j0 = nt * 128 + sRow;      if (j0 > L2C - 1) j0 = L2C - 1;
  int j1 = nt * 128 + sRow + 64; if (j1 > L2C - 1) j1 = L2C - 1;
  const bf16_t* A0 = Y1 + ((size_t)i0 * BC + b) * DC + sCol8;
  const bf16_t* A1 = Y1 + ((size_t)i1 * BC + b) * DC + sCol8;
  const bf16_t* B0 = Y2 + ((size_t)j0 * BC + b) * DC + sCol8;
  const bf16_t* B1 = Y2 + ((size_t)j1 * BC + b) * DC + sCol8;

  const int wr = (w >> 1) * 64, wc = (w & 1) * 64;
  const int rsel = lane & 15, hi = lane >> 4;
  const int kchunk = (hi ^ ((rsel >> 1) & 3)) << 4;
  const int offA = ((wr + rsel) << 6) + kchunk;
  const int offB = 8192 + ((wc + rsel) << 6) + kchunk;

  f32x4 acc[4][4] = {};

  // prologue: stage tiles 0..2
#pragma unroll
  for (int p = 0; p < 3; ++p) {
    char* db = lds + p * 16384;
    gload16(A0 + p * 32, db + t16);
    gload16(A1 + p * 32, db + 4096 + t16);
    gload16(B0 + p * 32, db + 8192 + t16);
    gload16(B1 + p * 32, db + 12288 + t16);
  }
  asm volatile("s_waitcnt vmcnt(8)" ::: "memory");
  __builtin_amdgcn_s_barrier();
  __builtin_amdgcn_sched_barrier(0);

#pragma unroll 1
  for (int tt = 0; tt < 32; ++tt) {
    const char* rb = lds + (tt & 3) * 16384;
    char* sb = lds + ((tt + 3) & 3) * 16384;
    const int ks = (tt + 3) * 32;
    bf16x8 af[4], bfv[4];
#pragma unroll
    for (int m = 0; m < 4; ++m) af[m] = *(const bf16x8*)(rb + offA + m * 1024);
#pragma unroll
    for (int n = 0; n < 4; ++n) bfv[n] = *(const bf16x8*)(rb + offB + n * 1024);
    if (tt < 29) {
      gload16(A0 + ks, sb + t16);
      gload16(A1 + ks, sb + 4096 + t16);
      gload16(B0 + ks, sb + 8192 + t16);
      gload16(B1 + ks, sb + 12288 + t16);
    }
    __builtin_amdgcn_s_setprio(1);
#pragma unroll
    for (int m = 0; m < 4; ++m)
#pragma unroll
      for (int n = 0; n < 4; ++n)
        acc[m][n] = __builtin_amdgcn_mfma_f32_16x16x32_bf16(af[m], bfv[n], acc[m][n], 0, 0, 0);
    __builtin_amdgcn_s_setprio(0);
    if (tt < 29)       asm volatile("s_waitcnt vmcnt(8)" ::: "memory");
    else if (tt == 29) asm volatile("s_waitcnt vmcnt(4)" ::: "memory");
    else if (tt == 30) asm volatile("s_waitcnt vmcnt(0)" ::: "memory");
    __builtin_amdgcn_s_barrier();
    __builtin_amdgcn_sched_barrier(0);
  }

  float* Ob = O + (size_t)b * L1C * L2C;
  const int row0 = mt * 128 + wr + hi * 4;
  const int col0 = nt * 128 + wc + rsel;
#pragma unroll
  for (int n = 0; n < 4; ++n) {
    const int c = col0 + n * 16;
    if (c < L2C) {
#pragma unroll
      for (int m = 0; m < 4; ++m) {
        const int r = row0 + m * 16;
#pragma unroll
        for (int q = 0; q < 4; ++q)
          Ob[(size_t)(r + q) * L2C + c] = acc[m][n][q];
      }
    }
  }
}

// ---------------- softmax stats (with rank-1 terms t1,t2) ----------------
__global__ __launch_bounds__(256)
void row_stats(const float* __restrict__ O, const float* __restrict__ tT2,
               float* __restrict__ rowM, float* __restrict__ rowInv) {
  const int gw = blockIdx.x * 4 + (threadIdx.x >> 6);
  const int lane = threadIdx.x & 63;
  const int b = gw >> 8;
  const float* row = O + (size_t)gw * L2C;
  const float* t2 = tT2 + b * L2C;
  float v[5];
  float m = -1e30f;
#pragma unroll
  for (int t = 0; t < 5; ++t) { v[t] = row[t * 64 + lane] + t2[t * 64 + lane]; m = fmaxf(m, v[t]); }
#pragma unroll
  for (int off = 32; off; off >>= 1) m = fmaxf(m, __shfl_xor(m, off));
  float s = 0.f;
#pragma unroll
  for (int t = 0; t < 5; ++t) s += __expf(v[t] - m);
#pragma unroll
  for (int off = 32; off; off >>= 1) s += __shfl_xor(s, off);
  if (lane == 0) { rowM[gw] = m; rowInv[gw] = 1.f / s; }
}

__global__ __launch_bounds__(256)
void col_stats_c1(const float* __restrict__ O, const float* __restrict__ tT1,
                  const float* __restrict__ tT2,
                  const float* __restrict__ rowM, const float* __restrict__ rowInv,
                  float* __restrict__ colM, float* __restrict__ colInv,
                  float* __restrict__ c1) {
  const int b = blockIdx.x / 5, jb = blockIdx.x % 5;
  const int jl = threadIdx.x & 63, ig = threadIdx.x >> 6;
  const int j = jb * 64 + jl;
  const float* Ob = O + (size_t)b * L1C * L2C + j;
  const float* rM = rowM + b * L1C;
  const float* rI = rowInv + b * L1C;
  const float* t1 = tT1 + b * L1C;
  const float t2j = tT2[b * L2C + j];
  float m = -1e30f, s = 0.f, cp = 0.f;
  for (int i = ig; i < L1C; i += 4) {
    float ov = Ob[(size_t)i * L2C];
    float v = ov + t1[i];
    float mn = fmaxf(m, v);
    s = s * __expf(m - mn) + __expf(v - mn);
    m = mn;
    cp += __expf(ov + t2j - rM[i]) * rI[i];
  }
  __shared__ float sm[4][64], ss[4][64], sc[4][64];
  sm[ig][jl] = m; ss[ig][jl] = s; sc[ig][jl] = cp;
  __syncthreads();
  if (ig == 0) {
    for (int g = 1; g < 4; ++g) {
      float mg = sm[g][jl], sg = ss[g][jl];
      float mn = fmaxf(m, mg);
      s = s * __expf(m - mn) + sg * __expf(mg - mn);
      m = mn;
      cp += sc[g][jl];
    }
    colM[b * L2C + j] = m;
    colInv[b * L2C + j] = 1.f / s;
    c1[b * L2C + j] = cp;
  }
}

__global__ __launch_bounds__(256)
void c2_kernel(const float* __restrict__ O, const float* __restrict__ tT1,
               const float* __restrict__ colM, const float* __restrict__ colInv,
               float* __restrict__ c2) {
  const int gw = blockIdx.x * 4 + (threadIdx.x >> 6);
  const int lane = threadIdx.x & 63;
  const int b = gw >> 8;
  const float* row = O + (size_t)gw * L2C;
  const float* cM = colM + b * L2C;
  const float* cI = colInv + b * L2C;
  const float t1i = tT1[b * L1C + (gw & 255)];
  float s = 0.f;
#pragma unroll
  for (int t = 0; t < 5; ++t) {
    const int j = t * 64 + lane;
    s += __expf(row[j] + t1i - cM[j]) * cI[j];
  }
#pragma unroll
  for (int off = 32; off; off >>= 1) s += __shfl_xor(s, off);
  if (lane == 0) c2[gw] = s;
}

// ---------------- weighted h-sums -> U (256x1024 bf16) ----------------
__global__ __launch_bounds__(256)
void u_kernel(const bf16_t* __restrict__ H, const float* __restrict__ c1,
              const float* __restrict__ c2, bf16_t* __restrict__ Ub) {
  const int b = blockIdx.x >> 2;
  const int d = (blockIdx.x & 3) * 256 + threadIdx.x;
  const bf16_t* H2 = H + (size_t)L1C * BC * DC;
  float s1 = 0.f, s1c = 0.f, s2 = 0.f, s2c = 0.f;
  const float* c2b = c2 + b * L1C;
  for (int i = 0; i < L1C; ++i) {
    float v = (float)H[((size_t)i * BC + b) * DC + d];
    s1 += v; s1c += c2b[i] * v;
  }
  const float* c1b = c1 + b * L2C;
  for (int j = 0; j < L2C; ++j) {
    float v = (float)H2[((size_t)j * BC + b) * DC + d];
    s2 += v; s2c += c1b[j] * v;
  }
  Ub[(size_t)(0 * 64 + b) * 1024 + d] = (bf16_t)(s1  * (1.f / L1C));
  Ub[(size_t)(1 * 64 + b) * 1024 + d] = (bf16_t)(s2c * (1.f / L1C));
  Ub[(size_t)(2 * 64 + b) * 1024 + d] = (bf16_t)(s2  * (1.f / L2C));
  Ub[(size_t)(3 * 64 + b) * 1024 + d] = (bf16_t)(s1c * (1.f / L2C));
}

// ---------------- host ----------------
extern "C" void kernel_launch(void* const* d_in, const int* in_sizes, int n_in,
                              void* d_out, int out_size, void* d_ws, size_t ws_size,
                              hipStream_t stream) {
  const float* r1 = (const float*)d_in[0];
  const float* r2 = (const float*)d_in[1];
  const float* W1 = (const float*)d_in[2];
  const float* b1 = (const float*)d_in[3];
  const float* W2 = (const float*)d_in[4];
  const float* b2 = (const float*)d_in[5];
  float* out = (float*)d_out;
  char* ws = (char*)d_ws;

  const size_t M1 = (size_t)L1C * BC;   // 16384
  const size_t M2 = (size_t)L2C * BC;   // 20480
  const size_t Mt = M1 + M2;            // 36864

  size_t off = 0;
  bf16_t* XB  = (bf16_t*)(ws + off); off += Mt * DC * 2;        // 72MB: Z + O + Gpart
  bf16_t* HB  = (bf16_t*)(ws + off); off += Mt * DC * 2;        // 72MB, h; head reused as Ppart
  bf16_t* WB1 = (bf16_t*)(ws + off); off += (size_t)DC * DC * 2;
  bf16_t* WB2 = (bf16_t*)(ws + off); off += (size_t)DC * DC * 2;
  bf16_t* W2T = (bf16_t*)(ws + off); off += (size_t)DC * DC * 2;
  bf16_t* GB  = (bf16_t*)(ws + off); off += (size_t)DC * DC * 2;
  float* w2b   = (float*)(ws + off); off += 4096;
  float* zb    = (float*)(ws + off); off += 4096;
  float* tT1   = (float*)(ws + off); off += BC * L1C * 4;
  float* tT2   = (float*)(ws + off); off += BC * L2C * 4;
  float* rowM  = (float*)(ws + off); off += BC * L1C * 4;
  float* rowIv = (float*)(ws + off); off += BC * L1C * 4;
  float* colM  = (float*)(ws + off); off += BC * L2C * 4;
  float* colIv = (float*)(ws + off); off += BC * L2C * 4;
  float* c1v   = (float*)(ws + off); off += BC * L2C * 4;
  float* c2v   = (float*)(ws + off); off += BC * L1C * 4;
  bf16_t* Ub   = (bf16_t*)(ws + off); off += 256 * DC * 2;
  float* tpart = (float*)(ws + off); off += (size_t)16 * Mt * 4;  // 2.4MB

  bf16_t* Z = XB;                                   // 16384x1024 bf16 (32MB)
  float*  O = (float*)((char*)XB + 35651584);       // 21MB logits
  float*  Gpart = (float*)((char*)XB + 58720256);   // 16MB (4 slices)
  float*  Ppart = (float*)HB;                       // 8MB (8 slices), HB dead then
  bf16_t* H2 = HB + M1 * DC;

  // 1. weight prep only (r1/r2 consumed fp32-direct by GEMM1)
  conv_kernel<<<512, 256, 0, stream>>>(W1, WB1, (int)((size_t)DC * DC / 4));
  conv_kernel<<<512, 256, 0, stream>>>(W2, WB2, (int)((size_t)DC * DC / 4));
  w2t_kernel<<<dim3(32, 32), 256, 0, stream>>>(W2, W2T);
  wb_kernel<<<64, 256, 0, stream>>>(W2, b2, w2b);
  (void)hipMemsetAsync(zb, 0, 4096, stream);

  // 2. h = relu(x W1^T + b1), fp32-direct A (R6 variant) + fused t-partials
  mlp_gemm_f32a<<<576, 512, 0, stream>>>(r1, r2, WB1, b1, HB, 144, w2b, tpart);
  t_red<<<144, 256, 0, stream>>>(tpart, tT1, tT2);

  // 3. G = W2^T W2 split-K
  gemmK<<<256, 256, 0, stream>>>(W2T, W2T, Gpart, 256);
  g_reduce<<<1024, 256, 0, stream>>>(Gpart, GB);

  // 4. z1 = h1 G
  mlp_gemm8<<<256, 512, 0, stream>>>(HB, GB, zb, Z, 64, 0);

  // 5. oz[b,i,j] = z1 . h2
  logits_gemm<<<384, 256, 0, stream>>>(Z, H2, O);

  // 6. softmax stats with rank-1 corrections
  row_stats<<<4096, 256, 0, stream>>>(O, tT2, rowM, rowIv);
  col_stats_c1<<<320, 256, 0, stream>>>(O, tT1, tT2, rowM, rowIv, colM, colIv, c1v);
  c2_kernel<<<4096, 256, 0, stream>>>(O, tT1, colM, colIv, c2v);

  // 7. weighted h pools -> U;  out = U W2^T + b2, split-K + reduce
  u_kernel<<<256, 256, 0, stream>>>(HB, c1v, c2v, Ub);
  pool_gemmK<<<128, 256, 0, stream>>>(Ub, WB2, Ppart);
  pool_reduce<<<1024, 256, 0, stream>>>(Ppart, b2, out);
}

// Round 11
// 299.852 us; speedup vs baseline: 1.1625x; 1.0137x over previous
//
#include <hip/hip_runtime.h>
#include <stdint.h>

#define L1C 256
#define L2C 320
#define BC  64
#define DC  1024

typedef __bf16 bf16_t;
typedef __bf16 bf16x8 __attribute__((ext_vector_type(8)));
typedef __bf16 bf16x4 __attribute__((ext_vector_type(4)));
typedef float  f32x4  __attribute__((ext_vector_type(4)));

__device__ __forceinline__ void gload16(const void* g, void* l) {
  __builtin_amdgcn_global_load_lds(
      (__attribute__((address_space(1))) void*)g,
      (__attribute__((address_space(3))) void*)l, 16, 0, 0);
}

// ---------------- fp32 -> bf16 convert ----------------
__global__ __launch_bounds__(256)
void conv_kernel(const float* __restrict__ src, bf16_t* __restrict__ dst, int n4) {
  int i = blockIdx.x * 256 + threadIdx.x;
  const int stride = gridDim.x * 256;
  for (; i < n4; i += stride) {
    float4 v = ((const float4*)src)[i];
    bf16x4 o = { (__bf16)v.x, (__bf16)v.y, (__bf16)v.z, (__bf16)v.w };
    ((bf16x4*)dst)[i] = o;
  }
}

// ---------------- transpose W2 (fp32 1024x1024) -> bf16 W2T ----------------
__global__ __launch_bounds__(256)
void w2t_kernel(const float* __restrict__ W2, bf16_t* __restrict__ W2T) {
  __shared__ float tile[32][33];
  const int tx = threadIdx.x & 31, ty = threadIdx.x >> 5;  // 32 x 8
  const int x0 = blockIdx.x * 32, y0 = blockIdx.y * 32;
#pragma unroll
  for (int k = 0; k < 32; k += 8)
    tile[ty + k][tx] = W2[(size_t)(y0 + ty + k) * 1024 + x0 + tx];
  __syncthreads();
#pragma unroll
  for (int k = 0; k < 32; k += 8)
    W2T[(size_t)(x0 + ty + k) * 1024 + y0 + tx] = (bf16_t)tile[tx][ty + k];
}

// ---------------- w2b[d] = sum_k W2[k,d] * b2[k] ----------------
__global__ __launch_bounds__(256)
void wb_kernel(const float* __restrict__ W2, const float* __restrict__ b2,
               float* __restrict__ w2b) {
  const int dt = threadIdx.x & 15, kg = threadIdx.x >> 4;   // 16 d x 16 kgroups
  const int d = blockIdx.x * 16 + dt;
  float s = 0.f;
  for (int k = kg * 64; k < kg * 64 + 64; ++k)
    s += W2[(size_t)k * 1024 + d] * b2[k];
  __shared__ float red[16][17];
  red[kg][dt] = s;
  __syncthreads();
  if (kg == 0) {
    float t = 0.f;
#pragma unroll
    for (int g = 0; g < 16; ++g) t += red[g][dt];
    w2b[d] = t;
  }
}

// ---------------- GEMM1: 128x128 tile, 4-wave, ring-4, XOR swizzle ----------
// Clone of the proven logits_gemm structure; C = relu(A W^T + bias), bf16.
// A: 36864x1024 bf16, W: 1024x1024 bf16, grid 2304 (288 mt x 8 nt).
__global__ __launch_bounds__(256)
void gemm1_128(const bf16_t* __restrict__ A, const bf16_t* __restrict__ W,
               const float* __restrict__ bias, bf16_t* __restrict__ C) {
  const int wg = ((int)blockIdx.x & 7) * 288 + ((int)blockIdx.x >> 3);
  const int mt = wg >> 3, nt = wg & 7;

  __shared__ __align__(16) char lds[65536];    // 4 bufs x (A 8KB + B 8KB)

  const int t = threadIdx.x;
  const int lane = t & 63, w = t >> 6;
  const int sRow = t >> 2;
  const int sCol8 = (((t & 3) ^ ((t >> 3) & 3))) * 8;   // pre-swizzled source chunk
  const int t16 = t * 16;

  const bf16_t* A0 = A + (size_t)(mt * 128 + sRow) * 1024 + sCol8;
  const bf16_t* A1 = A0 + (size_t)64 * 1024;
  const bf16_t* B0 = W + (size_t)(nt * 128 + sRow) * 1024 + sCol8;
  const bf16_t* B1 = B0 + (size_t)64 * 1024;

  const int wr = (w >> 1) * 64, wc = (w & 1) * 64;
  const int rsel = lane & 15, hi = lane >> 4;
  const int kchunk = (hi ^ ((rsel >> 1) & 3)) << 4;
  const int offA = ((wr + rsel) << 6) + kchunk;
  const int offB = 8192 + ((wc + rsel) << 6) + kchunk;

  f32x4 acc[4][4] = {};

  // prologue: stage tiles 0..2
#pragma unroll
  for (int p = 0; p < 3; ++p) {
    char* db = lds + p * 16384;
    gload16(A0 + p * 32, db + t16);
    gload16(A1 + p * 32, db + 4096 + t16);
    gload16(B0 + p * 32, db + 8192 + t16);
    gload16(B1 + p * 32, db + 12288 + t16);
  }
  asm volatile("s_waitcnt vmcnt(8)" ::: "memory");
  __builtin_amdgcn_s_barrier();
  __builtin_amdgcn_sched_barrier(0);

#pragma unroll 1
  for (int tt = 0; tt < 32; ++tt) {
    const char* rb = lds + (tt & 3) * 16384;
    char* sb = lds + ((tt + 3) & 3) * 16384;
    const int ks = (tt + 3) * 32;
    bf16x8 af[4], bfv[4];
#pragma unroll
    for (int m = 0; m < 4; ++m) af[m] = *(const bf16x8*)(rb + offA + m * 1024);
#pragma unroll
    for (int n = 0; n < 4; ++n) bfv[n] = *(const bf16x8*)(rb + offB + n * 1024);
    if (tt < 29) {
      gload16(A0 + ks, sb + t16);
      gload16(A1 + ks, sb + 4096 + t16);
      gload16(B0 + ks, sb + 8192 + t16);
      gload16(B1 + ks, sb + 12288 + t16);
    }
    __builtin_amdgcn_s_setprio(1);
#pragma unroll
    for (int m = 0; m < 4; ++m)
#pragma unroll
      for (int n = 0; n < 4; ++n)
        acc[m][n] = __builtin_amdgcn_mfma_f32_16x16x32_bf16(af[m], bfv[n], acc[m][n], 0, 0, 0);
    __builtin_amdgcn_s_setprio(0);
    if (tt < 29)       asm volatile("s_waitcnt vmcnt(8)" ::: "memory");
    else if (tt == 29) asm volatile("s_waitcnt vmcnt(4)" ::: "memory");
    else if (tt == 30) asm volatile("s_waitcnt vmcnt(0)" ::: "memory");
    __builtin_amdgcn_s_barrier();
    __builtin_amdgcn_sched_barrier(0);
  }

  const int row0 = mt * 128 + wr + hi * 4;
  const int col0 = nt * 128 + wc + rsel;
  float bv[4];
#pragma unroll
  for (int n = 0; n < 4; ++n) bv[n] = bias[col0 + n * 16];
#pragma unroll
  for (int m = 0; m < 4; ++m) {
#pragma unroll
    for (int q = 0; q < 4; ++q) {
      const size_t rr = (size_t)(row0 + m * 16 + q) * 1024;
#pragma unroll
      for (int n = 0; n < 4; ++n) {
        float v = fmaxf(acc[m][n][q] + bv[n], 0.f);
        C[rr + col0 + n * 16] = (bf16_t)v;
      }
    }
  }
}

// ---------------- t[r] = h[r,:] . w2b ----------------
__global__ __launch_bounds__(256)
void t_kernel(const bf16_t* __restrict__ H, const float* __restrict__ w2b,
              float* __restrict__ tT1, float* __restrict__ tT2) {
  const int wv = threadIdx.x >> 6, lane = threadIdx.x & 63;
  const int r = blockIdx.x * 4 + wv;
  const bf16_t* hrow = H + (size_t)r * 1024;
  float s = 0.f;
#pragma unroll
  for (int h = 0; h < 2; ++h) {
    bf16x8 v = *(const bf16x8*)(hrow + h * 512 + lane * 8);
#pragma unroll
    for (int e = 0; e < 8; ++e) s += (float)v[e] * w2b[h * 512 + lane * 8 + e];
  }
#pragma unroll
  for (int off = 32; off; off >>= 1) s += __shfl_xor(s, off);
  if (lane == 0) {
    const int b = r & 63;
    if (r < 16384) tT1[b * L1C + (r >> 6)] = s;
    else           tT2[b * L2C + ((r - 16384) >> 6)] = s;
  }
}

// ---------------- bf16 MLP GEMM, 256x256 tile, 8-wave (r2/r3 proven) ----------
__global__ __launch_bounds__(512, 2)
void mlp_gemm8(const bf16_t* __restrict__ A, const bf16_t* __restrict__ W,
               const float* __restrict__ bias, bf16_t* __restrict__ C,
               int Mtiles, int relu) {
  const int nwg = Mtiles * 4;
  const int cpx = nwg >> 3;
  const int wg  = ((int)blockIdx.x & 7) * cpx + ((int)blockIdx.x >> 3);
  const int mt = wg >> 2, nt = wg & 3;

  __shared__ __align__(16) char lds[131072];

  const int t    = threadIdx.x;
  const int lane = t & 63, wid = t >> 6;
  const int wm = wid >> 2, wn = wid & 3;
  const int rsel = lane & 15, hi = lane >> 4;
  const int t16 = t * 16;

  const int P0 = t16, P1 = 8192 + t16;
  const int Lg0 = P0 ^ ((P0 >> 3) & 0x30);
  const int Lg1 = P1 ^ ((P1 >> 3) & 0x30);
  const int rS0 = Lg0 >> 6, cS0 = (Lg0 & 63) >> 1;
  const int rS1 = Lg1 >> 6, cS1 = (Lg1 & 63) >> 1;
  const bf16_t* pA0 = A + (size_t)(mt * 256 + rS0) * 1024 + cS0;
  const bf16_t* pA1 = A + (size_t)(mt * 256 + rS1) * 1024 + cS1;
  const bf16_t* pB0 = W + (size_t)(nt * 256 + rS0) * 1024 + cS0;
  const bf16_t* pB1 = W + (size_t)(nt * 256 + rS1) * 1024 + cS1;

  const int kchunk = (hi ^ ((rsel >> 1) & 3)) << 4;
  const int offA = ((wm * 128 + rsel) << 6) + kchunk;
  const int offB = 16384 + ((wn * 64 + rsel) << 6) + kchunk;

  f32x4 acc[8][4] = {};
  bf16x8 bfr[4];

#pragma unroll
  for (int p = 0; p < 3; ++p) {
    char* db = lds + p * 32768;
    gload16(pA0 + p * 32, db + t16);
    gload16(pA1 + p * 32, db + 8192 + t16);
    gload16(pB0 + p * 32, db + 16384 + t16);
    gload16(pB1 + p * 32, db + 24576 + t16);
  }
  asm volatile("s_waitcnt vmcnt(8)" ::: "memory");
  __builtin_amdgcn_s_barrier();
  __builtin_amdgcn_sched_barrier(0);

#pragma unroll 1
  for (int tt = 0; tt < 32; ++tt) {
    const char* rb = lds + (tt & 3) * 32768;
    char* sb = lds + ((tt + 3) & 3) * 32768;
    const int ks = (tt + 3) * 32;
    bf16x8 af[4];
#pragma unroll
    for (int m = 0; m < 4; ++m) af[m] = *(const bf16x8*)(rb + offA + m * 1024);
#pragma unroll
    for (int n = 0; n < 4; ++n) bfr[n] = *(const bf16x8*)(rb + offB + n * 1024);
    if (tt < 29) {
      gload16(pA0 + ks, sb + t16);
      gload16(pA1 + ks, sb + 8192 + t16);
    }
    __builtin_amdgcn_s_setprio(1);
#pragma unroll
    for (int m = 0; m < 4; ++m)
#pragma unroll
      for (int n = 0; n < 4; ++n)
        acc[m][n] = __builtin_amdgcn_mfma_f32_16x16x32_bf16(af[m], bfr[n], acc[m][n], 0, 0, 0);
    __builtin_amdgcn_s_setprio(0);
    __builtin_amdgcn_s_barrier();
    __builtin_amdgcn_sched_barrier(0);
#pragma unroll
    for (int m = 0; m < 4; ++m) af[m] = *(const bf16x8*)(rb + offA + (m + 4) * 1024);
    if (tt < 29) {
      gload16(pB0 + ks, sb + 16384 + t16);
      gload16(pB1 + ks, sb + 24576 + t16);
    }
    __builtin_amdgcn_s_setprio(1);
#pragma unroll
    for (int m = 0; m < 4; ++m)
#pragma unroll
      for (int n = 0; n < 4; ++n)
        acc[m + 4][n] = __builtin_amdgcn_mfma_f32_16x16x32_bf16(af[m], bfr[n], acc[m + 4][n], 0, 0, 0);
    __builtin_amdgcn_s_setprio(0);
    if (tt < 29)       asm volatile("s_waitcnt vmcnt(8)" ::: "memory");
    else if (tt == 29) asm volatile("s_waitcnt vmcnt(4)" ::: "memory");
    else if (tt == 30) asm volatile("s_waitcnt vmcnt(0)" ::: "memory");
    __builtin_amdgcn_s_barrier();
    __builtin_amdgcn_sched_barrier(0);
  }

  const int row0 = mt * 256 + wm * 128 + hi * 4;
  const int col0 = nt * 256 + wn * 64 + rsel;
  float bv[4];
#pragma unroll
  for (int n = 0; n < 4; ++n) bv[n] = bias[col0 + n * 16];
#pragma unroll
  for (int m = 0; m < 8; ++m) {
#pragma unroll
    for (int q = 0; q < 4; ++q) {
      const size_t rr = (size_t)(row0 + m * 16 + q) * 1024;
#pragma unroll
      for (int n = 0; n < 4; ++n) {
        float v = acc[m][n][q] + bv[n];
        if (relu) v = fmaxf(v, 0.f);
        C[rr + col0 + n * 16] = (bf16_t)v;
      }
    }
  }
}

// ---------------- 128x128 split-K GEMM ----------------
__global__ __launch_bounds__(256)
void gemmK(const bf16_t* __restrict__ A, const bf16_t* __restrict__ W,
           float* __restrict__ P, int KS) {
  const int slice = (int)blockIdx.x >> 6;
  const int tl = (int)blockIdx.x & 63;
  const int mt = tl >> 3, nt = tl & 7;
  const int koff = slice * KS;

  const int f = threadIdx.x;
  const int lane = f & 63, w = f >> 6;
  const int sRow = f >> 2, sCol8 = (f & 3) * 8;

  const bf16_t* Ab = A + (size_t)mt * 128 * 1024 + (size_t)sRow * 1024 + sCol8;
  const bf16_t* Bb = W + (size_t)nt * 128 * 1024 + (size_t)sRow * 1024 + sCol8;

  __shared__ __align__(16) bf16_t sA[128 * 32];
  __shared__ __align__(16) bf16_t sB[128 * 32];
  bf16_t* sAp = sA + sRow * 32 + sCol8;
  bf16_t* sBp = sB + sRow * 32 + sCol8;

  const int wr = (w >> 1) * 64, wc = (w & 1) * 64;
  const int rsel = lane & 15, koff2 = (lane >> 4) * 8;
  const bf16_t* rA = sA + (wr + rsel) * 32 + koff2;
  const bf16_t* rB = sB + (wc + rsel) * 32 + koff2;

  f32x4 acc[4][4] = {};
  for (int kt = koff; kt < koff + KS; kt += 32) {
    __syncthreads();
    gload16(Ab + kt,             sAp);
    gload16(Ab + kt + 64 * 1024, sAp + 64 * 32);
    gload16(Bb + kt,             sBp);
    gload16(Bb + kt + 64 * 1024, sBp + 64 * 32);
    asm volatile("s_waitcnt vmcnt(0)" ::: "memory");
    __syncthreads();
    bf16x8 af[4], bfv[4];
#pragma unroll
    for (int m = 0; m < 4; ++m) af[m] = *(const bf16x8*)(rA + m * 16 * 32);
#pragma unroll
    for (int n = 0; n < 4; ++n) bfv[n] = *(const bf16x8*)(rB + n * 16 * 32);
#pragma unroll
    for (int m = 0; m < 4; ++m)
#pragma unroll
      for (int n = 0; n < 4; ++n)
        acc[m][n] = __builtin_amdgcn_mfma_f32_16x16x32_bf16(af[m], bfv[n], acc[m][n], 0, 0, 0);
  }

  float* Pb = P + (size_t)slice * 1048576;
  const int row0 = mt * 128 + wr + (lane >> 4) * 4;
  const int col0 = nt * 128 + wc + rsel;
#pragma unroll
  for (int n = 0; n < 4; ++n) {
    const int c = col0 + n * 16;
#pragma unroll
    for (int m = 0; m < 4; ++m) {
      const int r = row0 + m * 16;
#pragma unroll
      for (int q = 0; q < 4; ++q)
        Pb[(size_t)(r + q) * 1024 + c] = acc[m][n][q];
    }
  }
}

// reduce 4 G-partials -> bf16 G
__global__ __launch_bounds__(256)
void g_reduce(const float* __restrict__ Gp, bf16_t* __restrict__ GB) {
  const int i4 = blockIdx.x * 256 + threadIdx.x;
  float4 a = ((const float4*)Gp)[i4];
  float4 b = ((const float4*)(Gp + 1048576))[i4];
  float4 c = ((const float4*)(Gp + 2097152))[i4];
  float4 d = ((const float4*)(Gp + 3145728))[i4];
  bf16x4 o = { (bf16_t)(a.x + b.x + c.x + d.x), (bf16_t)(a.y + b.y + c.y + d.y),
               (bf16_t)(a.z + b.z + c.z + d.z), (bf16_t)(a.w + b.w + c.w + d.w) };
  ((bf16x4*)GB)[i4] = o;
}

// ---------------- pool split-K GEMM: U(256x1024) * W2^T, 8 K-slices ----------
__global__ __launch_bounds__(256)
void pool_gemmK(const bf16_t* __restrict__ A, const bf16_t* __restrict__ W,
                float* __restrict__ P) {
  const int slice = (int)blockIdx.x >> 4;
  const int tl = (int)blockIdx.x & 15;
  const int mt = tl >> 3, nt = tl & 7;
  const int koff = slice * 128;

  const int f = threadIdx.x;
  const int lane = f & 63, w = f >> 6;
  const int sRow = f >> 2, sCol8 = (f & 3) * 8;

  const bf16_t* Ab = A + (size_t)mt * 128 * 1024 + (size_t)sRow * 1024 + sCol8;
  const bf16_t* Bb = W + (size_t)nt * 128 * 1024 + (size_t)sRow * 1024 + sCol8;

  __shared__ __align__(16) bf16_t sA[128 * 32];
  __shared__ __align__(16) bf16_t sB[128 * 32];
  bf16_t* sAp = sA + sRow * 32 + sCol8;
  bf16_t* sBp = sB + sRow * 32 + sCol8;

  const int wr = (w >> 1) * 64, wc = (w & 1) * 64;
  const int rsel = lane & 15, koff2 = (lane >> 4) * 8;
  const bf16_t* rA = sA + (wr + rsel) * 32 + koff2;
  const bf16_t* rB = sB + (wc + rsel) * 32 + koff2;

  f32x4 acc[4][4] = {};
  for (int kt = koff; kt < koff + 128; kt += 32) {
    __syncthreads();
    gload16(Ab + kt,             sAp);
    gload16(Ab + kt + 64 * 1024, sAp + 64 * 32);
    gload16(Bb + kt,             sBp);
    gload16(Bb + kt + 64 * 1024, sBp + 64 * 32);
    asm volatile("s_waitcnt vmcnt(0)" ::: "memory");
    __syncthreads();
    bf16x8 af[4], bfv[4];
#pragma unroll
    for (int m = 0; m < 4; ++m) af[m] = *(const bf16x8*)(rA + m * 16 * 32);
#pragma unroll
    for (int n = 0; n < 4; ++n) bfv[n] = *(const bf16x8*)(rB + n * 16 * 32);
#pragma unroll
    for (int m = 0; m < 4; ++m)
#pragma unroll
      for (int n = 0; n < 4; ++n)
        acc[m][n] = __builtin_amdgcn_mfma_f32_16x16x32_bf16(af[m], bfv[n], acc[m][n], 0, 0, 0);
  }

  float* Pb = P + (size_t)slice * 262144;
  const int row0 = mt * 128 + wr + (lane >> 4) * 4;
  const int col0 = nt * 128 + wc + rsel;
#pragma unroll
  for (int n = 0; n < 4; ++n) {
    const int c = col0 + n * 16;
#pragma unroll
    for (int m = 0; m < 4; ++m) {
      const int r = row0 + m * 16;
#pragma unroll
      for (int q = 0; q < 4; ++q)
        Pb[(size_t)(r + q) * 1024 + c] = acc[m][n][q];
    }
  }
}

// reduce 8 pool partials + bias, remap rows -> d_out
__global__ __launch_bounds__(256)
void pool_reduce(const float* __restrict__ Pp, const float* __restrict__ b2,
                 float* __restrict__ out) {
  const int idx = blockIdx.x * 256 + threadIdx.x;
  const int r = idx >> 10, c = idx & 1023;
  float s = b2[c];
#pragma unroll
  for (int sl = 0; sl < 8; ++sl) s += Pp[(size_t)sl * 262144 + idx];
  const int g = r >> 6, b = r & 63;
  out[(size_t)(g >> 1) * 131072 + (size_t)b * 2048 + (g & 1) * 1024 + c] = s;
}

// ---------------- logits: oz[b,i,j] = z1[b,i,:].h2[b,j,:] ----------------
__global__ __launch_bounds__(256)
void logits_gemm(const bf16_t* __restrict__ Y1, const bf16_t* __restrict__ Y2,
                 float* __restrict__ O) {
  const int wg = ((int)blockIdx.x & 7) * 48 + ((int)blockIdx.x >> 3);
  const int b = wg / 6, t6 = wg % 6;
  const int mt = t6 / 3, nt = t6 % 3;

  __shared__ __align__(16) char lds[65536];    // 4 bufs x (A 8KB + B 8KB)

  const int t = threadIdx.x;
  const int lane = t & 63, w = t >> 6;
  const int sRow = t >> 2;
  const int sCol8 = (((t & 3) ^ ((t >> 3) & 3))) * 8;   // pre-swizzled source chunk
  const int t16 = t * 16;

  const int i0 = mt * 128 + sRow;
  const int i1 = i0 + 64;
  int j0 = nt * 128 + sRow;      if (j0 > L2C - 1) j0 = L2C - 1;
  int j1 = nt * 128 + sRow + 64; if (j1 > L2C - 1) j1 = L2C - 1;
  const bf16_t* A0 = Y1 + ((size_t)i0 * BC + b) * DC + sCol8;
  const bf16_t* A1 = Y1 + ((size_t)i1 * BC + b) * DC + sCol8;
  const bf16_t* B0 = Y2 + ((size_t)j0 * BC + b) * DC + sCol8;
  const bf16_t* B1 = Y2 + ((size_t)j1 * BC + b) * DC + sCol8;

  const int wr = (w >> 1) * 64, wc = (w & 1) * 64;
  const int rsel = lane & 15, hi = lane >> 4;
  const int kchunk = (hi ^ ((rsel >> 1) & 3)) << 4;
  const int offA = ((wr + rsel) << 6) + kchunk;
  const int offB = 8192 + ((wc + rsel) << 6) + kchunk;

  f32x4 acc[4][4] = {};

  // prologue: stage tiles 0..2
#pragma unroll
  for (int p = 0; p < 3; ++p) {
    char* db = lds + p * 16384;
    gload16(A0 + p * 32, db + t16);
    gload16(A1 + p * 32, db + 4096 + t16);
    gload16(B0 + p * 32, db + 8192 + t16);
    gload16(B1 + p * 32, db + 12288 + t16);
  }
  asm volatile("s_waitcnt vmcnt(8)" ::: "memory");
  __builtin_amdgcn_s_barrier();
  __builtin_amdgcn_sched_barrier(0);

#pragma unroll 1
  for (int tt = 0; tt < 32; ++tt) {
    const char* rb = lds + (tt & 3) * 16384;
    char* sb = lds + ((tt + 3) & 3) * 16384;
    const int ks = (tt + 3) * 32;
    bf16x8 af[4], bfv[4];
#pragma unroll
    for (int m = 0; m < 4; ++m) af[m] = *(const bf16x8*)(rb + offA + m * 1024);
#pragma unroll
    for (int n = 0; n < 4; ++n) bfv[n] = *(const bf16x8*)(rb + offB + n * 1024);
    if (tt < 29) {
      gload16(A0 + ks, sb + t16);
      gload16(A1 + ks, sb + 4096 + t16);
      gload16(B0 + ks, sb + 8192 + t16);
      gload16(B1 + ks, sb + 12288 + t16);
    }
    __builtin_amdgcn_s_setprio(1);
#pragma unroll
    for (int m = 0; m < 4; ++m)
#pragma unroll
      for (int n = 0; n < 4; ++n)
        acc[m][n] = __builtin_amdgcn_mfma_f32_16x16x32_bf16(af[m], bfv[n], acc[m][n], 0, 0, 0);
    __builtin_amdgcn_s_setprio(0);
    if (tt < 29)       asm volatile("s_waitcnt vmcnt(8)" ::: "memory");
    else if (tt == 29) asm volatile("s_waitcnt vmcnt(4)" ::: "memory");
    else if (tt == 30) asm volatile("s_waitcnt vmcnt(0)" ::: "memory");
    __builtin_amdgcn_s_barrier();
    __builtin_amdgcn_sched_barrier(0);
  }

  float* Ob = O + (size_t)b * L1C * L2C;
  const int row0 = mt * 128 + wr + hi * 4;
  const int col0 = nt * 128 + wc + rsel;
#pragma unroll
  for (int n = 0; n < 4; ++n) {
    const int c = col0 + n * 16;
    if (c < L2C) {
#pragma unroll
      for (int m = 0; m < 4; ++m) {
        const int r = row0 + m * 16;
#pragma unroll
        for (int q = 0; q < 4; ++q)
          Ob[(size_t)(r + q) * L2C + c] = acc[m][n][q];
      }
    }
  }
}

// ---------------- softmax stats (with rank-1 terms t1,t2) ----------------
__global__ __launch_bounds__(256)
void row_stats(const float* __restrict__ O, const float* __restrict__ tT2,
               float* __restrict__ rowM, float* __restrict__ rowInv) {
  const int gw = blockIdx.x * 4 + (threadIdx.x >> 6);
  const int lane = threadIdx.x & 63;
  const int b = gw >> 8;
  const float* row = O + (size_t)gw * L2C;
  const float* t2 = tT2 + b * L2C;
  float v[5];
  float m = -1e30f;
#pragma unroll
  for (int t = 0; t < 5; ++t) { v[t] = row[t * 64 + lane] + t2[t * 64 + lane]; m = fmaxf(m, v[t]); }
#pragma unroll
  for (int off = 32; off; off >>= 1) m = fmaxf(m, __shfl_xor(m, off));
  float s = 0.f;
#pragma unroll
  for (int t = 0; t < 5; ++t) s += __expf(v[t] - m);
#pragma unroll
  for (int off = 32; off; off >>= 1) s += __shfl_xor(s, off);
  if (lane == 0) { rowM[gw] = m; rowInv[gw] = 1.f / s; }
}

__global__ __launch_bounds__(256)
void col_stats_c1(const float* __restrict__ O, const float* __restrict__ tT1,
                  const float* __restrict__ tT2,
                  const float* __restrict__ rowM, const float* __restrict__ rowInv,
                  float* __restrict__ colM, float* __restrict__ colInv,
                  float* __restrict__ c1) {
  const int b = blockIdx.x / 5, jb = blockIdx.x % 5;
  const int jl = threadIdx.x & 63, ig = threadIdx.x >> 6;
  const int j = jb * 64 + jl;
  const float* Ob = O + (size_t)b * L1C * L2C + j;
  const float* rM = rowM + b * L1C;
  const float* rI = rowInv + b * L1C;
  const float* t1 = tT1 + b * L1C;
  const float t2j = tT2[b * L2C + j];
  float m = -1e30f, s = 0.f, cp = 0.f;
  for (int i = ig; i < L1C; i += 4) {
    float ov = Ob[(size_t)i * L2C];
    float v = ov + t1[i];
    float mn = fmaxf(m, v);
    s = s * __expf(m - mn) + __expf(v - mn);
    m = mn;
    cp += __expf(ov + t2j - rM[i]) * rI[i];
  }
  __shared__ float sm[4][64], ss[4][64], sc[4][64];
  sm[ig][jl] = m; ss[ig][jl] = s; sc[ig][jl] = cp;
  __syncthreads();
  if (ig == 0) {
    for (int g = 1; g < 4; ++g) {
      float mg = sm[g][jl], sg = ss[g][jl];
      float mn = fmaxf(m, mg);
      s = s * __expf(m - mn) + sg * __expf(mg - mn);
      m = mn;
      cp += sc[g][jl];
    }
    colM[b * L2C + j] = m;
    colInv[b * L2C + j] = 1.f / s;
    c1[b * L2C + j] = cp;
  }
}

__global__ __launch_bounds__(256)
void c2_kernel(const float* __restrict__ O, const float* __restrict__ tT1,
               const float* __restrict__ colM, const float* __restrict__ colInv,
               float* __restrict__ c2) {
  const int gw = blockIdx.x * 4 + (threadIdx.x >> 6);
  const int lane = threadIdx.x & 63;
  const int b = gw >> 8;
  const float* row = O + (size_t)gw * L2C;
  const float* cM = colM + b * L2C;
  const float* cI = colInv + b * L2C;
  const float t1i = tT1[b * L1C + (gw & 255)];
  float s = 0.f;
#pragma unroll
  for (int t = 0; t < 5; ++t) {
    const int j = t * 64 + lane;
    s += __expf(row[j] + t1i - cM[j]) * cI[j];
  }
#pragma unroll
  for (int off = 32; off; off >>= 1) s += __shfl_xor(s, off);
  if (lane == 0) c2[gw] = s;
}

// ---------------- weighted h-sums -> U (256x1024 bf16) ----------------
__global__ __launch_bounds__(256)
void u_kernel(const bf16_t* __restrict__ H, const float* __restrict__ c1,
              const float* __restrict__ c2, bf16_t* __restrict__ Ub) {
  const int b = blockIdx.x >> 2;
  const int d = (blockIdx.x & 3) * 256 + threadIdx.x;
  const bf16_t* H2 = H + (size_t)L1C * BC * DC;
  float s1 = 0.f, s1c = 0.f, s2 = 0.f, s2c = 0.f;
  const float* c2b = c2 + b * L1C;
  for (int i = 0; i < L1C; ++i) {
    float v = (float)H[((size_t)i * BC + b) * DC + d];
    s1 += v; s1c += c2b[i] * v;
  }
  const float* c1b = c1 + b * L2C;
  for (int j = 0; j < L2C; ++j) {
    float v = (float)H2[((size_t)j * BC + b) * DC + d];
    s2 += v; s2c += c1b[j] * v;
  }
  Ub[(size_t)(0 * 64 + b) * 1024 + d] = (bf16_t)(s1  * (1.f / L1C));
  Ub[(size_t)(1 * 64 + b) * 1024 + d] = (bf16_t)(s2c * (1.f / L1C));
  Ub[(size_t)(2 * 64 + b) * 1024 + d] = (bf16_t)(s2  * (1.f / L2C));
  Ub[(size_t)(3 * 64 + b) * 1024 + d] = (bf16_t)(s1c * (1.f / L2C));
}

// ---------------- host ----------------
extern "C" void kernel_launch(void* const* d_in, const int* in_sizes, int n_in,
                              void* d_out, int out_size, void* d_ws, size_t ws_size,
                              hipStream_t stream) {
  const float* r1 = (const float*)d_in[0];
  const float* r2 = (const float*)d_in[1];
  const float* W1 = (const float*)d_in[2];
  const float* b1 = (const float*)d_in[3];
  const float* W2 = (const float*)d_in[4];
  const float* b2 = (const float*)d_in[5];
  float* out = (float*)d_out;
  char* ws = (char*)d_ws;

  const size_t M1 = (size_t)L1C * BC;   // 16384
  const size_t M2 = (size_t)L2C * BC;   // 20480
  const size_t Mt = M1 + M2;            // 36864

  size_t off = 0;
  bf16_t* XB  = (bf16_t*)(ws + off); off += Mt * DC * 2;        // 72MB: A-bf16, then Z + O + Gpart
  bf16_t* HB  = (bf16_t*)(ws + off); off += Mt * DC * 2;        // 72MB, h; head reused as Ppart
  bf16_t* WB1 = (bf16_t*)(ws + off); off += (size_t)DC * DC * 2;
  bf16_t* WB2 = (bf16_t*)(ws + off); off += (size_t)DC * DC * 2;
  bf16_t* W2T = (bf16_t*)(ws + off); off += (size_t)DC * DC * 2;
  bf16_t* GB  = (bf16_t*)(ws + off); off += (size_t)DC * DC * 2;
  float* w2b   = (float*)(ws + off); off += 4096;
  float* zb    = (float*)(ws + off); off += 4096;
  float* tT1   = (float*)(ws + off); off += BC * L1C * 4;
  float* tT2   = (float*)(ws + off); off += BC * L2C * 4;
  float* rowM  = (float*)(ws + off); off += BC * L1C * 4;
  float* rowIv = (float*)(ws + off); off += BC * L1C * 4;
  float* colM  = (float*)(ws + off); off += BC * L2C * 4;
  float* colIv = (float*)(ws + off); off += BC * L2C * 4;
  float* c1v   = (float*)(ws + off); off += BC * L2C * 4;
  float* c2v   = (float*)(ws + off); off += BC * L1C * 4;
  bf16_t* Ub   = (bf16_t*)(ws + off); off += 256 * DC * 2;

  bf16_t* Z = XB;                                   // 16384x1024 bf16 (32MB)
  float*  O = (float*)((char*)XB + 35651584);       // 21MB logits
  float*  Gpart = (float*)((char*)XB + 58720256);   // 16MB (4 slices)
  float*  Ppart = (float*)HB;                       // 8MB (8 slices), HB dead then
  bf16_t* H2 = HB + M1 * DC;

  // 1. converts + weight prep
  conv_kernel<<<2048, 256, 0, stream>>>(r1, XB,           (int)(M1 * DC / 4));
  conv_kernel<<<2048, 256, 0, stream>>>(r2, XB + M1 * DC, (int)(M2 * DC / 4));
  conv_kernel<<<512,  256, 0, stream>>>(W1, WB1, (int)((size_t)DC * DC / 4));
  conv_kernel<<<512,  256, 0, stream>>>(W2, WB2, (int)((size_t)DC * DC / 4));
  w2t_kernel<<<dim3(32, 32), 256, 0, stream>>>(W2, W2T);
  wb_kernel<<<64, 256, 0, stream>>>(W2, b2, w2b);
  (void)hipMemsetAsync(zb, 0, 4096, stream);

  // 2. h = relu(x W1^T + b1): swizzled 128^2 ring-4 (logits-clone structure)
  gemm1_128<<<2304, 256, 0, stream>>>(XB, WB1, b1, HB);
  t_kernel<<<9216, 256, 0, stream>>>(HB, w2b, tT1, tT2);

  // 3. G = W2^T W2 split-K
  gemmK<<<256, 256, 0, stream>>>(W2T, W2T, Gpart, 256);
  g_reduce<<<1024, 256, 0, stream>>>(Gpart, GB);

  // 4. z1 = h1 G
  mlp_gemm8<<<256, 512, 0, stream>>>(HB, GB, zb, Z, 64, 0);

  // 5. oz[b,i,j] = z1 . h2
  logits_gemm<<<384, 256, 0, stream>>>(Z, H2, O);

  // 6. softmax stats with rank-1 corrections
  row_stats<<<4096, 256, 0, stream>>>(O, tT2, rowM, rowIv);
  col_stats_c1<<<320, 256, 0, stream>>>(O, tT1, tT2, rowM, rowIv, colM, colIv, c1v);
  c2_kernel<<<4096, 256, 0, stream>>>(O, tT1, colM, colIv, c2v);

  // 7. weighted h pools -> U;  out = U W2^T + b2, split-K + reduce
  u_kernel<<<256, 256, 0, stream>>>(HB, c1v, c2v, Ub);
  pool_gemmK<<<128, 256, 0, stream>>>(Ub, WB2, Ppart);
  pool_reduce<<<1024, 256, 0, stream>>>(Ppart, b2, out);
}

// Round 12
// 297.143 us; speedup vs baseline: 1.1731x; 1.0091x over previous
//
#include <hip/hip_runtime.h>
#include <stdint.h>

#define L1C 256
#define L2C 320
#define BC  64
#define DC  1024

typedef __bf16 bf16_t;
typedef __bf16 bf16x8 __attribute__((ext_vector_type(8)));
typedef __bf16 bf16x4 __attribute__((ext_vector_type(4)));
typedef float  f32x4  __attribute__((ext_vector_type(4)));

__device__ __forceinline__ void gload16(const void* g, void* l) {
  __builtin_amdgcn_global_load_lds(
      (__attribute__((address_space(1))) void*)g,
      (__attribute__((address_space(3))) void*)l, 16, 0, 0);
}

// ---------------- fp32 -> bf16 convert ----------------
__global__ __launch_bounds__(256)
void conv_kernel(const float* __restrict__ src, bf16_t* __restrict__ dst, int n4) {
  int i = blockIdx.x * 256 + threadIdx.x;
  const int stride = gridDim.x * 256;
  for (; i < n4; i += stride) {
    float4 v = ((const float4*)src)[i];
    bf16x4 o = { (__bf16)v.x, (__bf16)v.y, (__bf16)v.z, (__bf16)v.w };
    ((bf16x4*)dst)[i] = o;
  }
}

// fused convert of W1 and W2 (one launch)
__global__ __launch_bounds__(256)
void convw_kernel(const float* __restrict__ W1, bf16_t* __restrict__ D1,
                  const float* __restrict__ W2, bf16_t* __restrict__ D2) {
  const int i = blockIdx.x * 256 + threadIdx.x;   // 1024 blocks, n4 = 262144 each
  {
    float4 v = ((const float4*)W1)[i];
    bf16x4 o = { (__bf16)v.x, (__bf16)v.y, (__bf16)v.z, (__bf16)v.w };
    ((bf16x4*)D1)[i] = o;
  }
  {
    float4 v = ((const float4*)W2)[i];
    bf16x4 o = { (__bf16)v.x, (__bf16)v.y, (__bf16)v.z, (__bf16)v.w };
    ((bf16x4*)D2)[i] = o;
  }
}

// ---------------- transpose W2 (fp32 1024x1024) -> bf16 W2T ----------------
__global__ __launch_bounds__(256)
void w2t_kernel(const float* __restrict__ W2, bf16_t* __restrict__ W2T) {
  __shared__ float tile[32][33];
  const int tx = threadIdx.x & 31, ty = threadIdx.x >> 5;  // 32 x 8
  const int x0 = blockIdx.x * 32, y0 = blockIdx.y * 32;
#pragma unroll
  for (int k = 0; k < 32; k += 8)
    tile[ty + k][tx] = W2[(size_t)(y0 + ty + k) * 1024 + x0 + tx];
  __syncthreads();
#pragma unroll
  for (int k = 0; k < 32; k += 8)
    W2T[(size_t)(x0 + ty + k) * 1024 + y0 + tx] = (bf16_t)tile[tx][ty + k];
}

// ---------------- w2b[d] = sum_k W2[k,d] * b2[k] ----------------
__global__ __launch_bounds__(256)
void wb_kernel(const float* __restrict__ W2, const float* __restrict__ b2,
               float* __restrict__ w2b) {
  const int dt = threadIdx.x & 15, kg = threadIdx.x >> 4;   // 16 d x 16 kgroups
  const int d = blockIdx.x * 16 + dt;
  float s = 0.f;
  for (int k = kg * 64; k < kg * 64 + 64; ++k)
    s += W2[(size_t)k * 1024 + d] * b2[k];
  __shared__ float red[16][17];
  red[kg][dt] = s;
  __syncthreads();
  if (kg == 0) {
    float t = 0.f;
#pragma unroll
    for (int g = 0; g < 16; ++g) t += red[g][dt];
    w2b[d] = t;
  }
}

// ---------------- GEMM1: 128x128 tile, 4-wave, ring-3, XOR swizzle ----------
// C = relu(A W^T + bias), bf16. Ring-3 (48KB LDS) -> 3 blocks/CU; grid 2304 =
// exactly 3 rounds of 768 co-resident blocks (no tail quantization).
__global__ __launch_bounds__(256, 3)
void gemm1_128(const bf16_t* __restrict__ A, const bf16_t* __restrict__ W,
               const float* __restrict__ bias, bf16_t* __restrict__ C) {
  const int wg = ((int)blockIdx.x & 7) * 288 + ((int)blockIdx.x >> 3);
  const int mt = wg >> 3, nt = wg & 7;

  __shared__ __align__(16) char lds[49152];    // 3 bufs x (A 8KB + B 8KB)

  const int t = threadIdx.x;
  const int lane = t & 63, w = t >> 6;
  const int sRow = t >> 2;
  const int sCol8 = (((t & 3) ^ ((t >> 3) & 3))) * 8;   // pre-swizzled source chunk
  const int t16 = t * 16;

  const bf16_t* A0 = A + (size_t)(mt * 128 + sRow) * 1024 + sCol8;
  const bf16_t* A1 = A0 + (size_t)64 * 1024;
  const bf16_t* B0 = W + (size_t)(nt * 128 + sRow) * 1024 + sCol8;
  const bf16_t* B1 = B0 + (size_t)64 * 1024;

  const int wr = (w >> 1) * 64, wc = (w & 1) * 64;
  const int rsel = lane & 15, hi = lane >> 4;
  const int kchunk = (hi ^ ((rsel >> 1) & 3)) << 4;
  const int offA = ((wr + rsel) << 6) + kchunk;
  const int offB = 8192 + ((wc + rsel) << 6) + kchunk;

  f32x4 acc[4][4] = {};

  // prologue: stage tiles 0,1
#pragma unroll
  for (int p = 0; p < 2; ++p) {
    char* db = lds + p * 16384;
    gload16(A0 + p * 32, db + t16);
    gload16(A1 + p * 32, db + 4096 + t16);
    gload16(B0 + p * 32, db + 8192 + t16);
    gload16(B1 + p * 32, db + 12288 + t16);
  }
  asm volatile("s_waitcnt vmcnt(4)" ::: "memory");   // tile 0 resident
  __builtin_amdgcn_s_barrier();
  __builtin_amdgcn_sched_barrier(0);

  int cur = 0;
#pragma unroll 1
  for (int tt = 0; tt < 32; ++tt) {
    const char* rb = lds + cur * 16384;
    int nx = cur + 2; if (nx >= 3) nx -= 3;
    char* sb = lds + nx * 16384;             // buffer of tile tt-1 (dead) -> tt+2
    const int ks = (tt + 2) * 32;
    bf16x8 af[4], bfv[4];
#pragma unroll
    for (int m = 0; m < 4; ++m) af[m] = *(const bf16x8*)(rb + offA + m * 1024);
#pragma unroll
    for (int n = 0; n < 4; ++n) bfv[n] = *(const bf16x8*)(rb + offB + n * 1024);
    if (tt < 30) {
      gload16(A0 + ks, sb + t16);
      gload16(A1 + ks, sb + 4096 + t16);
      gload16(B0 + ks, sb + 8192 + t16);
      gload16(B1 + ks, sb + 12288 + t16);
    }
    __builtin_amdgcn_s_setprio(1);
#pragma unroll
    for (int m = 0; m < 4; ++m)
#pragma unroll
      for (int n = 0; n < 4; ++n)
        acc[m][n] = __builtin_amdgcn_mfma_f32_16x16x32_bf16(af[m], bfv[n], acc[m][n], 0, 0, 0);
    __builtin_amdgcn_s_setprio(0);
    if (tt < 30)       asm volatile("s_waitcnt vmcnt(4)" ::: "memory");  // tt+1 resident
    else if (tt == 30) asm volatile("s_waitcnt vmcnt(0)" ::: "memory");  // tile 31 resident
    __builtin_amdgcn_s_barrier();
    __builtin_amdgcn_sched_barrier(0);
    cur = (cur + 1 == 3) ? 0 : cur + 1;
  }

  const int row0 = mt * 128 + wr + hi * 4;
  const int col0 = nt * 128 + wc + rsel;
  float bv[4];
#pragma unroll
  for (int n = 0; n < 4; ++n) bv[n] = bias[col0 + n * 16];
#pragma unroll
  for (int m = 0; m < 4; ++m) {
#pragma unroll
    for (int q = 0; q < 4; ++q) {
      const size_t rr = (size_t)(row0 + m * 16 + q) * 1024;
#pragma unroll
      for (int n = 0; n < 4; ++n) {
        float v = fmaxf(acc[m][n][q] + bv[n], 0.f);
        C[rr + col0 + n * 16] = (bf16_t)v;
      }
    }
  }
}

// ---------------- t[r] = h[r,:] . w2b ----------------
__global__ __launch_bounds__(256)
void t_kernel(const bf16_t* __restrict__ H, const float* __restrict__ w2b,
              float* __restrict__ tT1, float* __restrict__ tT2) {
  const int wv = threadIdx.x >> 6, lane = threadIdx.x & 63;
  const int r = blockIdx.x * 4 + wv;
  const bf16_t* hrow = H + (size_t)r * 1024;
  float s = 0.f;
#pragma unroll
  for (int h = 0; h < 2; ++h) {
    bf16x8 v = *(const bf16x8*)(hrow + h * 512 + lane * 8);
#pragma unroll
    for (int e = 0; e < 8; ++e) s += (float)v[e] * w2b[h * 512 + lane * 8 + e];
  }
#pragma unroll
  for (int off = 32; off; off >>= 1) s += __shfl_xor(s, off);
  if (lane == 0) {
    const int b = r & 63;
    if (r < 16384) tT1[b * L1C + (r >> 6)] = s;
    else           tT2[b * L2C + ((r - 16384) >> 6)] = s;
  }
}

// ---------------- bf16 MLP GEMM, 256x256 tile, 8-wave (r2/r3 proven) ----------
__global__ __launch_bounds__(512, 2)
void mlp_gemm8(const bf16_t* __restrict__ A, const bf16_t* __restrict__ W,
               const float* __restrict__ bias, bf16_t* __restrict__ C,
               int Mtiles, int relu) {
  const int nwg = Mtiles * 4;
  const int cpx = nwg >> 3;
  const int wg  = ((int)blockIdx.x & 7) * cpx + ((int)blockIdx.x >> 3);
  const int mt = wg >> 2, nt = wg & 3;

  __shared__ __align__(16) char lds[131072];

  const int t    = threadIdx.x;
  const int lane = t & 63, wid = t >> 6;
  const int wm = wid >> 2, wn = wid & 3;
  const int rsel = lane & 15, hi = lane >> 4;
  const int t16 = t * 16;

  const int P0 = t16, P1 = 8192 + t16;
  const int Lg0 = P0 ^ ((P0 >> 3) & 0x30);
  const int Lg1 = P1 ^ ((P1 >> 3) & 0x30);
  const int rS0 = Lg0 >> 6, cS0 = (Lg0 & 63) >> 1;
  const int rS1 = Lg1 >> 6, cS1 = (Lg1 & 63) >> 1;
  const bf16_t* pA0 = A + (size_t)(mt * 256 + rS0) * 1024 + cS0;
  const bf16_t* pA1 = A + (size_t)(mt * 256 + rS1) * 1024 + cS1;
  const bf16_t* pB0 = W + (size_t)(nt * 256 + rS0) * 1024 + cS0;
  const bf16_t* pB1 = W + (size_t)(nt * 256 + rS1) * 1024 + cS1;

  const int kchunk = (hi ^ ((rsel >> 1) & 3)) << 4;
  const int offA = ((wm * 128 + rsel) << 6) + kchunk;
  const int offB = 16384 + ((wn * 64 + rsel) << 6) + kchunk;

  f32x4 acc[8][4] = {};
  bf16x8 bfr[4];

#pragma unroll
  for (int p = 0; p < 3; ++p) {
    char* db = lds + p * 32768;
    gload16(pA0 + p * 32, db + t16);
    gload16(pA1 + p * 32, db + 8192 + t16);
    gload16(pB0 + p * 32, db + 16384 + t16);
    gload16(pB1 + p * 32, db + 24576 + t16);
  }
  asm volatile("s_waitcnt vmcnt(8)" ::: "memory");
  __builtin_amdgcn_s_barrier();
  __builtin_amdgcn_sched_barrier(0);

#pragma unroll 1
  for (int tt = 0; tt < 32; ++tt) {
    const char* rb = lds + (tt & 3) * 32768;
    char* sb = lds + ((tt + 3) & 3) * 32768;
    const int ks = (tt + 3) * 32;
    bf16x8 af[4];
#pragma unroll
    for (int m = 0; m < 4; ++m) af[m] = *(const bf16x8*)(rb + offA + m * 1024);
#pragma unroll
    for (int n = 0; n < 4; ++n) bfr[n] = *(const bf16x8*)(rb + offB + n * 1024);
    if (tt < 29) {
      gload16(pA0 + ks, sb + t16);
      gload16(pA1 + ks, sb + 8192 + t16);
    }
    __builtin_amdgcn_s_setprio(1);
#pragma unroll
    for (int m = 0; m < 4; ++m)
#pragma unroll
      for (int n = 0; n < 4; ++n)
        acc[m][n] = __builtin_amdgcn_mfma_f32_16x16x32_bf16(af[m], bfr[n], acc[m][n], 0, 0, 0);
    __builtin_amdgcn_s_setprio(0);
    __builtin_amdgcn_s_barrier();
    __builtin_amdgcn_sched_barrier(0);
#pragma unroll
    for (int m = 0; m < 4; ++m) af[m] = *(const bf16x8*)(rb + offA + (m + 4) * 1024);
    if (tt < 29) {
      gload16(pB0 + ks, sb + 16384 + t16);
      gload16(pB1 + ks, sb + 24576 + t16);
    }
    __builtin_amdgcn_s_setprio(1);
#pragma unroll
    for (int m = 0; m < 4; ++m)
#pragma unroll
      for (int n = 0; n < 4; ++n)
        acc[m + 4][n] = __builtin_amdgcn_mfma_f32_16x16x32_bf16(af[m], bfr[n], acc[m + 4][n], 0, 0, 0);
    __builtin_amdgcn_s_setprio(0);
    if (tt < 29)       asm volatile("s_waitcnt vmcnt(8)" ::: "memory");
    else if (tt == 29) asm volatile("s_waitcnt vmcnt(4)" ::: "memory");
    else if (tt == 30) asm volatile("s_waitcnt vmcnt(0)" ::: "memory");
    __builtin_amdgcn_s_barrier();
    __builtin_amdgcn_sched_barrier(0);
  }

  const int row0 = mt * 256 + wm * 128 + hi * 4;
  const int col0 = nt * 256 + wn * 64 + rsel;
  float bv[4];
#pragma unroll
  for (int n = 0; n < 4; ++n) bv[n] = bias[col0 + n * 16];
#pragma unroll
  for (int m = 0; m < 8; ++m) {
#pragma unroll
    for (int q = 0; q < 4; ++q) {
      const size_t rr = (size_t)(row0 + m * 16 + q) * 1024;
#pragma unroll
      for (int n = 0; n < 4; ++n) {
        float v = acc[m][n][q] + bv[n];
        if (relu) v = fmaxf(v, 0.f);
        C[rr + col0 + n * 16] = (bf16_t)v;
      }
    }
  }
}

// ---------------- 128x128 split-K GEMM ----------------
__global__ __launch_bounds__(256)
void gemmK(const bf16_t* __restrict__ A, const bf16_t* __restrict__ W,
           float* __restrict__ P, int KS) {
  const int slice = (int)blockIdx.x >> 6;
  const int tl = (int)blockIdx.x & 63;
  const int mt = tl >> 3, nt = tl & 7;
  const int koff = slice * KS;

  const int f = threadIdx.x;
  const int lane = f & 63, w = f >> 6;
  const int sRow = f >> 2, sCol8 = (f & 3) * 8;

  const bf16_t* Ab = A + (size_t)mt * 128 * 1024 + (size_t)sRow * 1024 + sCol8;
  const bf16_t* Bb = W + (size_t)nt * 128 * 1024 + (size_t)sRow * 1024 + sCol8;

  __shared__ __align__(16) bf16_t sA[128 * 32];
  __shared__ __align__(16) bf16_t sB[128 * 32];
  bf16_t* sAp = sA + sRow * 32 + sCol8;
  bf16_t* sBp = sB + sRow * 32 + sCol8;

  const int wr = (w >> 1) * 64, wc = (w & 1) * 64;
  const int rsel = lane & 15, koff2 = (lane >> 4) * 8;
  const bf16_t* rA = sA + (wr + rsel) * 32 + koff2;
  const bf16_t* rB = sB + (wc + rsel) * 32 + koff2;

  f32x4 acc[4][4] = {};
  for (int kt = koff; kt < koff + KS; kt += 32) {
    __syncthreads();
    gload16(Ab + kt,             sAp);
    gload16(Ab + kt + 64 * 1024, sAp + 64 * 32);
    gload16(Bb + kt,             sBp);
    gload16(Bb + kt + 64 * 1024, sBp + 64 * 32);
    asm volatile("s_waitcnt vmcnt(0)" ::: "memory");
    __syncthreads();
    bf16x8 af[4], bfv[4];
#pragma unroll
    for (int m = 0; m < 4; ++m) af[m] = *(const bf16x8*)(rA + m * 16 * 32);
#pragma unroll
    for (int n = 0; n < 4; ++n) bfv[n] = *(const bf16x8*)(rB + n * 16 * 32);
#pragma unroll
    for (int m = 0; m < 4; ++m)
#pragma unroll
      for (int n = 0; n < 4; ++n)
        acc[m][n] = __builtin_amdgcn_mfma_f32_16x16x32_bf16(af[m], bfv[n], acc[m][n], 0, 0, 0);
  }

  float* Pb = P + (size_t)slice * 1048576;
  const int row0 = mt * 128 + wr + (lane >> 4) * 4;
  const int col0 = nt * 128 + wc + rsel;
#pragma unroll
  for (int n = 0; n < 4; ++n) {
    const int c = col0 + n * 16;
#pragma unroll
    for (int m = 0; m < 4; ++m) {
      const int r = row0 + m * 16;
#pragma unroll
      for (int q = 0; q < 4; ++q)
        Pb[(size_t)(r + q) * 1024 + c] = acc[m][n][q];
    }
  }
}

// reduce 4 G-partials -> bf16 G
__global__ __launch_bounds__(256)
void g_reduce(const float* __restrict__ Gp, bf16_t* __restrict__ GB) {
  const int i4 = blockIdx.x * 256 + threadIdx.x;
  float4 a = ((const float4*)Gp)[i4];
  float4 b = ((const float4*)(Gp + 1048576))[i4];
  float4 c = ((const float4*)(Gp + 2097152))[i4];
  float4 d = ((const float4*)(Gp + 3145728))[i4];
  bf16x4 o = { (bf16_t)(a.x + b.x + c.x + d.x), (bf16_t)(a.y + b.y + c.y + d.y),
               (bf16_t)(a.z + b.z + c.z + d.z), (bf16_t)(a.w + b.w + c.w + d.w) };
  ((bf16x4*)GB)[i4] = o;
}

// ---------------- pool split-K GEMM: U(256x1024) * W2^T, 8 K-slices ----------
__global__ __launch_bounds__(256)
void pool_gemmK(const bf16_t* __restrict__ A, const bf16_t* __restrict__ W,
                float* __restrict__ P) {
  const int slice = (int)blockIdx.x >> 4;
  const int tl = (int)blockIdx.x & 15;
  const int mt = tl >> 3, nt = tl & 7;
  const int koff = slice * 128;

  const int f = threadIdx.x;
  const int lane = f & 63, w = f >> 6;
  const int sRow = f >> 2, sCol8 = (f & 3) * 8;

  const bf16_t* Ab = A + (size_t)mt * 128 * 1024 + (size_t)sRow * 1024 + sCol8;
  const bf16_t* Bb = W + (size_t)nt * 128 * 1024 + (size_t)sRow * 1024 + sCol8;

  __shared__ __align__(16) bf16_t sA[128 * 32];
  __shared__ __align__(16) bf16_t sB[128 * 32];
  bf16_t* sAp = sA + sRow * 32 + sCol8;
  bf16_t* sBp = sB + sRow * 32 + sCol8;

  const int wr = (w >> 1) * 64, wc = (w & 1) * 64;
  const int rsel = lane & 15, koff2 = (lane >> 4) * 8;
  const bf16_t* rA = sA + (wr + rsel) * 32 + koff2;
  const bf16_t* rB = sB + (wc + rsel) * 32 + koff2;

  f32x4 acc[4][4] = {};
  for (int kt = koff; kt < koff + 128; kt += 32) {
    __syncthreads();
    gload16(Ab + kt,             sAp);
    gload16(Ab + kt + 64 * 1024, sAp + 64 * 32);
    gload16(Bb + kt,             sBp);
    gload16(Bb + kt + 64 * 1024, sBp + 64 * 32);
    asm volatile("s_waitcnt vmcnt(0)" ::: "memory");
    __syncthreads();
    bf16x8 af[4], bfv[4];
#pragma unroll
    for (int m = 0; m < 4; ++m) af[m] = *(const bf16x8*)(rA + m * 16 * 32);
#pragma unroll
    for (int n = 0; n < 4; ++n) bfv[n] = *(const bf16x8*)(rB + n * 16 * 32);
#pragma unroll
    for (int m = 0; m < 4; ++m)
#pragma unroll
      for (int n = 0; n < 4; ++n)
        acc[m][n] = __builtin_amdgcn_mfma_f32_16x16x32_bf16(af[m], bfv[n], acc[m][n], 0, 0, 0);
  }

  float* Pb = P + (size_t)slice * 262144;
  const int row0 = mt * 128 + wr + (lane >> 4) * 4;
  const int col0 = nt * 128 + wc + rsel;
#pragma unroll
  for (int n = 0; n < 4; ++n) {
    const int c = col0 + n * 16;
#pragma unroll
    for (int m = 0; m < 4; ++m) {
      const int r = row0 + m * 16;
#pragma unroll
      for (int q = 0; q < 4; ++q)
        Pb[(size_t)(r + q) * 1024 + c] = acc[m][n][q];
    }
  }
}

// reduce 8 pool partials + bias, remap rows -> d_out
__global__ __launch_bounds__(256)
void pool_reduce(const float* __restrict__ Pp, const float* __restrict__ b2,
                 float* __restrict__ out) {
  const int idx = blockIdx.x * 256 + threadIdx.x;
  const int r = idx >> 10, c = idx & 1023;
  float s = b2[c];
#pragma unroll
  for (int sl = 0; sl < 8; ++sl) s += Pp[(size_t)sl * 262144 + idx];
  const int g = r >> 6, b = r & 63;
  out[(size_t)(g >> 1) * 131072 + (size_t)b * 2048 + (g & 1) * 1024 + c] = s;
}

// ---------------- logits: oz[b,i,j] = z1[b,i,:].h2[b,j,:] ----------------
__global__ __launch_bounds__(256)
void logits_gemm(const bf16_t* __restrict__ Y1, const bf16_t* __restrict__ Y2,
                 float* __restrict__ O) {
  const int wg = ((int)blockIdx.x & 7) * 48 + ((int)blockIdx.x >> 3);
  const int b = wg / 6, t6 = wg % 6;
  const int mt = t6 / 3, nt = t6 % 3;

  __shared__ __align__(16) char lds[65536];    // 4 bufs x (A 8KB + B 8KB)

  const int t = threadIdx.x;
  const int lane = t & 63, w = t >> 6;
  const int sRow = t >> 2;
  const int sCol8 = (((t & 3) ^ ((t >> 3) & 3))) * 8;   // pre-swizzled source chunk
  const int t16 = t * 16;

  const int i0 = mt * 128 + sRow;
  const int i1 = i0 + 64;
  int j0 = nt * 128 + sRow;      if (j0 > L2C - 1) j0 = L2C - 1;
  int j1 = nt * 128 + sRow + 64; if (j1 > L2C - 1) j1 = L2C - 1;
  const bf16_t* A0 = Y1 + ((size_t)i0 * BC + b) * DC + sCol8;
  const bf16_t* A1 = Y1 + ((size_t)i1 * BC + b) * DC + sCol8;
  const bf16_t* B0 = Y2 + ((size_t)j0 * BC + b) * DC + sCol8;
  const bf16_t* B1 = Y2 + ((size_t)j1 * BC + b) * DC + sCol8;

  const int wr = (w >> 1) * 64, wc = (w & 1) * 64;
  const int rsel = lane & 15, hi = lane >> 4;
  const int kchunk = (hi ^ ((rsel >> 1) & 3)) << 4;
  const int offA = ((wr + rsel) << 6) + kchunk;
  const int offB = 8192 + ((wc + rsel) << 6) + kchunk;

  f32x4 acc[4][4] = {};

  // prologue: stage tiles 0..2
#pragma unroll
  for (int p = 0; p < 3; ++p) {
    char* db = lds + p * 16384;
    gload16(A0 + p * 32, db + t16);
    gload16(A1 + p * 32, db + 4096 + t16);
    gload16(B0 + p * 32, db + 8192 + t16);
    gload16(B1 + p * 32, db + 12288 + t16);
  }
  asm volatile("s_waitcnt vmcnt(8)" ::: "memory");
  __builtin_amdgcn_s_barrier();
  __builtin_amdgcn_sched_barrier(0);

#pragma unroll 1
  for (int tt = 0; tt < 32; ++tt) {
    const char* rb = lds + (tt & 3) * 16384;
    char* sb = lds + ((tt + 3) & 3) * 16384;
    const int ks = (tt + 3) * 32;
    bf16x8 af[4], bfv[4];
#pragma unroll
    for (int m = 0; m < 4; ++m) af[m] = *(const bf16x8*)(rb + offA + m * 1024);
#pragma unroll
    for (int n = 0; n < 4; ++n) bfv[n] = *(const bf16x8*)(rb + offB + n * 1024);
    if (tt < 29) {
      gload16(A0 + ks, sb + t16);
      gload16(A1 + ks, sb + 4096 + t16);
      gload16(B0 + ks, sb + 8192 + t16);
      gload16(B1 + ks, sb + 12288 + t16);
    }
    __builtin_amdgcn_s_setprio(1);
#pragma unroll
    for (int m = 0; m < 4; ++m)
#pragma unroll
      for (int n = 0; n < 4; ++n)
        acc[m][n] = __builtin_amdgcn_mfma_f32_16x16x32_bf16(af[m], bfv[n], acc[m][n], 0, 0, 0);
    __builtin_amdgcn_s_setprio(0);
    if (tt < 29)       asm volatile("s_waitcnt vmcnt(8)" ::: "memory");
    else if (tt == 29) asm volatile("s_waitcnt vmcnt(4)" ::: "memory");
    else if (tt == 30) asm volatile("s_waitcnt vmcnt(0)" ::: "memory");
    __builtin_amdgcn_s_barrier();
    __builtin_amdgcn_sched_barrier(0);
  }

  float* Ob = O + (size_t)b * L1C * L2C;
  const int row0 = mt * 128 + wr + hi * 4;
  const int col0 = nt * 128 + wc + rsel;
#pragma unroll
  for (int n = 0; n < 4; ++n) {
    const int c = col0 + n * 16;
    if (c < L2C) {
#pragma unroll
      for (int m = 0; m < 4; ++m) {
        const int r = row0 + m * 16;
#pragma unroll
        for (int q = 0; q < 4; ++q)
          Ob[(size_t)(r + q) * L2C + c] = acc[m][n][q];
      }
    }
  }
}

// ---------------- softmax stats (with rank-1 terms t1,t2) ----------------
__global__ __launch_bounds__(256)
void row_stats(const float* __restrict__ O, const float* __restrict__ tT2,
               float* __restrict__ rowM, float* __restrict__ rowInv) {
  const int gw = blockIdx.x * 4 + (threadIdx.x >> 6);
  const int lane = threadIdx.x & 63;
  const int b = gw >> 8;
  const float* row = O + (size_t)gw * L2C;
  const float* t2 = tT2 + b * L2C;
  float v[5];
  float m = -1e30f;
#pragma unroll
  for (int t = 0; t < 5; ++t) { v[t] = row[t * 64 + lane] + t2[t * 64 + lane]; m = fmaxf(m, v[t]); }
#pragma unroll
  for (int off = 32; off; off >>= 1) m = fmaxf(m, __shfl_xor(m, off));
  float s = 0.f;
#pragma unroll
  for (int t = 0; t < 5; ++t) s += __expf(v[t] - m);
#pragma unroll
  for (int off = 32; off; off >>= 1) s += __shfl_xor(s, off);
  if (lane == 0) { rowM[gw] = m; rowInv[gw] = 1.f / s; }
}

__global__ __launch_bounds__(256)
void col_stats_c1(const float* __restrict__ O, const float* __restrict__ tT1,
                  const float* __restrict__ tT2,
                  const float* __restrict__ rowM, const float* __restrict__ rowInv,
                  float* __restrict__ colM, float* __restrict__ colInv,
                  float* __restrict__ c1) {
  const int b = blockIdx.x / 5, jb = blockIdx.x % 5;
  const int jl = threadIdx.x & 63, ig = threadIdx.x >> 6;
  const int j = jb * 64 + jl;
  const float* Ob = O + (size_t)b * L1C * L2C + j;
  const float* rM = rowM + b * L1C;
  const float* rI = rowInv + b * L1C;
  const float* t1 = tT1 + b * L1C;
  const float t2j = tT2[b * L2C + j];
  float m = -1e30f, s = 0.f, cp = 0.f;
  for (int i = ig; i < L1C; i += 4) {
    float ov = Ob[(size_t)i * L2C];
    float v = ov + t1[i];
    float mn = fmaxf(m, v);
    s = s * __expf(m - mn) + __expf(v - mn);
    m = mn;
    cp += __expf(ov + t2j - rM[i]) * rI[i];
  }
  __shared__ float sm[4][64], ss[4][64], sc[4][64];
  sm[ig][jl] = m; ss[ig][jl] = s; sc[ig][jl] = cp;
  __syncthreads();
  if (ig == 0) {
    for (int g = 1; g < 4; ++g) {
      float mg = sm[g][jl], sg = ss[g][jl];
      float mn = fmaxf(m, mg);
      s = s * __expf(m - mn) + sg * __expf(mg - mn);
      m = mn;
      cp += sc[g][jl];
    }
    colM[b * L2C + j] = m;
    colInv[b * L2C + j] = 1.f / s;
    c1[b * L2C + j] = cp;
  }
}

__global__ __launch_bounds__(256)
void c2_kernel(const float* __restrict__ O, const float* __restrict__ tT1,
               const float* __restrict__ colM, const float* __restrict__ colInv,
               float* __restrict__ c2) {
  const int gw = blockIdx.x * 4 + (threadIdx.x >> 6);
  const int lane = threadIdx.x & 63;
  const int b = gw >> 8;
  const float* row = O + (size_t)gw * L2C;
  const float* cM = colM + b * L2C;
  const float* cI = colInv + b * L2C;
  const float t1i = tT1[b * L1C + (gw & 255)];
  float s = 0.f;
#pragma unroll
  for (int t = 0; t < 5; ++t) {
    const int j = t * 64 + lane;
    s += __expf(row[j] + t1i - cM[j]) * cI[j];
  }
#pragma unroll
  for (int off = 32; off; off >>= 1) s += __shfl_xor(s, off);
  if (lane == 0) c2[gw] = s;
}

// ---------------- weighted h-sums -> U (256x1024 bf16) ----------------
__global__ __launch_bounds__(256)
void u_kernel(const bf16_t* __restrict__ H, const float* __restrict__ c1,
              const float* __restrict__ c2, bf16_t* __restrict__ Ub) {
  const int b = blockIdx.x >> 2;
  const int d = (blockIdx.x & 3) * 256 + threadIdx.x;
  const bf16_t* H2 = H + (size_t)L1C * BC * DC;
  float s1 = 0.f, s1c = 0.f, s2 = 0.f, s2c = 0.f;
  const float* c2b = c2 + b * L1C;
  for (int i = 0; i < L1C; ++i) {
    float v = (float)H[((size_t)i * BC + b) * DC + d];
    s1 += v; s1c += c2b[i] * v;
  }
  const float* c1b = c1 + b * L2C;
  for (int j = 0; j < L2C; ++j) {
    float v = (float)H2[((size_t)j * BC + b) * DC + d];
    s2 += v; s2c += c1b[j] * v;
  }
  Ub[(size_t)(0 * 64 + b) * 1024 + d] = (bf16_t)(s1  * (1.f / L1C));
  Ub[(size_t)(1 * 64 + b) * 1024 + d] = (bf16_t)(s2c * (1.f / L1C));
  Ub[(size_t)(2 * 64 + b) * 1024 + d] = (bf16_t)(s2  * (1.f / L2C));
  Ub[(size_t)(3 * 64 + b) * 1024 + d] = (bf16_t)(s1c * (1.f / L2C));
}

// ---------------- host ----------------
extern "C" void kernel_launch(void* const* d_in, const int* in_sizes, int n_in,
                              void* d_out, int out_size, void* d_ws, size_t ws_size,
                              hipStream_t stream) {
  const float* r1 = (const float*)d_in[0];
  const float* r2 = (const float*)d_in[1];
  const float* W1 = (const float*)d_in[2];
  const float* b1 = (const float*)d_in[3];
  const float* W2 = (const float*)d_in[4];
  const float* b2 = (const float*)d_in[5];
  float* out = (float*)d_out;
  char* ws = (char*)d_ws;

  const size_t M1 = (size_t)L1C * BC;   // 16384
  const size_t M2 = (size_t)L2C * BC;   // 20480
  const size_t Mt = M1 + M2;            // 36864

  size_t off = 0;
  bf16_t* XB  = (bf16_t*)(ws + off); off += Mt * DC * 2;        // 72MB: A-bf16, then Z + O + Gpart
  bf16_t* HB  = (bf16_t*)(ws + off); off += Mt * DC * 2;        // 72MB, h; head reused as Ppart
  bf16_t* WB1 = (bf16_t*)(ws + off); off += (size_t)DC * DC * 2;
  bf16_t* WB2 = (bf16_t*)(ws + off); off += (size_t)DC * DC * 2;
  bf16_t* W2T = (bf16_t*)(ws + off); off += (size_t)DC * DC * 2;
  bf16_t* GB  = (bf16_t*)(ws + off); off += (size_t)DC * DC * 2;
  float* w2b   = (float*)(ws + off); off += 4096;
  float* zb    = (float*)(ws + off); off += 4096;
  float* tT1   = (float*)(ws + off); off += BC * L1C * 4;
  float* tT2   = (float*)(ws + off); off += BC * L2C * 4;
  float* rowM  = (float*)(ws + off); off += BC * L1C * 4;
  float* rowIv = (float*)(ws + off); off += BC * L1C * 4;
  float* colM  = (float*)(ws + off); off += BC * L2C * 4;
  float* colIv = (float*)(ws + off); off += BC * L2C * 4;
  float* c1v   = (float*)(ws + off); off += BC * L2C * 4;
  float* c2v   = (float*)(ws + off); off += BC * L1C * 4;
  bf16_t* Ub   = (bf16_t*)(ws + off); off += 256 * DC * 2;

  bf16_t* Z = XB;                                   // 16384x1024 bf16 (32MB)
  float*  O = (float*)((char*)XB + 35651584);       // 21MB logits
  float*  Gpart = (float*)((char*)XB + 58720256);   // 16MB (4 slices)
  float*  Ppart = (float*)HB;                       // 8MB (8 slices), HB dead then
  bf16_t* H2 = HB + M1 * DC;

  // 1. converts + weight prep
  conv_kernel<<<2048, 256, 0, stream>>>(r1, XB,           (int)(M1 * DC / 4));
  conv_kernel<<<2048, 256, 0, stream>>>(r2, XB + M1 * DC, (int)(M2 * DC / 4));
  convw_kernel<<<1024, 256, 0, stream>>>(W1, WB1, W2, WB2);
  w2t_kernel<<<dim3(32, 32), 256, 0, stream>>>(W2, W2T);
  wb_kernel<<<64, 256, 0, stream>>>(W2, b2, w2b);
  (void)hipMemsetAsync(zb, 0, 4096, stream);

  // 2. h = relu(x W1^T + b1): swizzled 128^2 ring-3, 3 blocks/CU, exact 3 rounds
  gemm1_128<<<2304, 256, 0, stream>>>(XB, WB1, b1, HB);
  t_kernel<<<9216, 256, 0, stream>>>(HB, w2b, tT1, tT2);

  // 3. G = W2^T W2 split-K
  gemmK<<<256, 256, 0, stream>>>(W2T, W2T, Gpart, 256);
  g_reduce<<<1024, 256, 0, stream>>>(Gpart, GB);

  // 4. z1 = h1 G
  mlp_gemm8<<<256, 512, 0, stream>>>(HB, GB, zb, Z, 64, 0);

  // 5. oz[b,i,j] = z1 . h2
  logits_gemm<<<384, 256, 0, stream>>>(Z, H2, O);

  // 6. softmax stats with rank-1 corrections
  row_stats<<<4096, 256, 0, stream>>>(O, tT2, rowM, rowIv);
  col_stats_c1<<<320, 256, 0, stream>>>(O, tT1, tT2, rowM, rowIv, colM, colIv, c1v);
  c2_kernel<<<4096, 256, 0, stream>>>(O, tT1, colM, colIv, c2v);

  // 7. weighted h pools -> U;  out = U W2^T + b2, split-K + reduce
  u_kernel<<<256, 256, 0, stream>>>(HB, c1v, c2v, Ub);
  pool_gemmK<<<128, 256, 0, stream>>>(Ub, WB2, Ppart);
  pool_reduce<<<1024, 256, 0, stream>>>(Ppart, b2, out);
}

// Round 13
// 282.643 us; speedup vs baseline: 1.2333x; 1.0513x over previous
//
#include <hip/hip_runtime.h>
#include <stdint.h>

#define L1C 256
#define L2C 320
#define BC  64
#define DC  1024

typedef __bf16 bf16_t;
typedef __bf16 bf16x8 __attribute__((ext_vector_type(8)));
typedef __bf16 bf16x4 __attribute__((ext_vector_type(4)));
typedef float  f32x4  __attribute__((ext_vector_type(4)));

__device__ __forceinline__ void gload16(const void* g, void* l) {
  __builtin_amdgcn_global_load_lds(
      (__attribute__((address_space(1))) void*)g,
      (__attribute__((address_space(3))) void*)l, 16, 0, 0);
}

// ---------------- fused prep: converts + W2T + w2b + zb-zero ----------------
// blocks [0,9216):    r1/r2 fp32 -> bf16 XB (1024 float4 per block)
// blocks [9216,9728): W1/W2 fp32 -> bf16 (256 blocks each)
// blocks [9728,10752): W2 transpose -> bf16 W2T (32x32 tiles)
// blocks [10752,10816): w2b[d] = sum_k W2[k,d]*b2[k]
// block 10816:        zero zb
__global__ __launch_bounds__(256)
void prep_kernel(const float* __restrict__ r1, const float* __restrict__ r2,
                 bf16_t* __restrict__ XB,
                 const float* __restrict__ W1, bf16_t* __restrict__ WB1,
                 const float* __restrict__ W2, bf16_t* __restrict__ WB2,
                 bf16_t* __restrict__ W2T,
                 const float* __restrict__ b2, float* __restrict__ w2b,
                 float* __restrict__ zb) {
  __shared__ float buf[32 * 33];
  const int b = (int)blockIdx.x;
  if (b < 9216) {
    const float* src;
    size_t soff;
    if (b < 4096) { src = r1; soff = (size_t)b * 1024; }
    else          { src = r2; soff = (size_t)(b - 4096) * 1024; }
    const size_t doff = (size_t)b * 1024;
#pragma unroll
    for (int k = 0; k < 4; ++k) {
      const int i = threadIdx.x + k * 256;
      float4 v = ((const float4*)src)[soff + i];
      bf16x4 o = { (__bf16)v.x, (__bf16)v.y, (__bf16)v.z, (__bf16)v.w };
      ((bf16x4*)XB)[doff + i] = o;
    }
  } else if (b < 9728) {
    const int bb = b - 9216;
    const float* src = (bb < 256) ? W1 : W2;
    bf16_t* dst = (bb < 256) ? WB1 : WB2;
    const size_t base = (size_t)(bb & 255) * 1024;
#pragma unroll
    for (int k = 0; k < 4; ++k) {
      const int i = threadIdx.x + k * 256;
      float4 v = ((const float4*)src)[base + i];
      bf16x4 o = { (__bf16)v.x, (__bf16)v.y, (__bf16)v.z, (__bf16)v.w };
      ((bf16x4*)dst)[base + i] = o;
    }
  } else if (b < 10752) {
    const int bb = b - 9728;
    float (*tile)[33] = (float(*)[33])buf;
    const int tx = threadIdx.x & 31, ty = threadIdx.x >> 5;
    const int x0 = (bb & 31) * 32, y0 = (bb >> 5) * 32;
#pragma unroll
    for (int k = 0; k < 32; k += 8)
      tile[ty + k][tx] = W2[(size_t)(y0 + ty + k) * 1024 + x0 + tx];
    __syncthreads();
#pragma unroll
    for (int k = 0; k < 32; k += 8)
      W2T[(size_t)(x0 + ty + k) * 1024 + y0 + tx] = (bf16_t)tile[tx][ty + k];
  } else if (b < 10816) {
    const int bb = b - 10752;
    float (*red)[17] = (float(*)[17])buf;
    const int dt = threadIdx.x & 15, kg = threadIdx.x >> 4;
    const int d = bb * 16 + dt;
    float s = 0.f;
    for (int k = kg * 64; k < kg * 64 + 64; ++k)
      s += W2[(size_t)k * 1024 + d] * b2[k];
    red[kg][dt] = s;
    __syncthreads();
    if (kg == 0) {
      float t = 0.f;
#pragma unroll
      for (int g = 0; g < 16; ++g) t += red[g][dt];
      w2b[d] = t;
    }
  } else {
#pragma unroll
    for (int k = 0; k < 4; ++k) zb[threadIdx.x + k * 256] = 0.f;
  }
}

// ---------------- GEMM1: 128x128 tile, 4-wave, ring-3, XOR swizzle ----------
// C = relu(A W^T + bias), bf16. Ring-3 (48KB LDS) -> 3 blocks/CU; grid 2304 =
// exactly 3 rounds of 768 co-resident blocks (no tail quantization).
__global__ __launch_bounds__(256, 3)
void gemm1_128(const bf16_t* __restrict__ A, const bf16_t* __restrict__ W,
               const float* __restrict__ bias, bf16_t* __restrict__ C) {
  const int wg = ((int)blockIdx.x & 7) * 288 + ((int)blockIdx.x >> 3);
  const int mt = wg >> 3, nt = wg & 7;

  __shared__ __align__(16) char lds[49152];    // 3 bufs x (A 8KB + B 8KB)

  const int t = threadIdx.x;
  const int lane = t & 63, w = t >> 6;
  const int sRow = t >> 2;
  const int sCol8 = (((t & 3) ^ ((t >> 3) & 3))) * 8;   // pre-swizzled source chunk
  const int t16 = t * 16;

  const bf16_t* A0 = A + (size_t)(mt * 128 + sRow) * 1024 + sCol8;
  const bf16_t* A1 = A0 + (size_t)64 * 1024;
  const bf16_t* B0 = W + (size_t)(nt * 128 + sRow) * 1024 + sCol8;
  const bf16_t* B1 = B0 + (size_t)64 * 1024;

  const int wr = (w >> 1) * 64, wc = (w & 1) * 64;
  const int rsel = lane & 15, hi = lane >> 4;
  const int kchunk = (hi ^ ((rsel >> 1) & 3)) << 4;
  const int offA = ((wr + rsel) << 6) + kchunk;
  const int offB = 8192 + ((wc + rsel) << 6) + kchunk;

  f32x4 acc[4][4] = {};

  // prologue: stage tiles 0,1
#pragma unroll
  for (int p = 0; p < 2; ++p) {
    char* db = lds + p * 16384;
    gload16(A0 + p * 32, db + t16);
    gload16(A1 + p * 32, db + 4096 + t16);
    gload16(B0 + p * 32, db + 8192 + t16);
    gload16(B1 + p * 32, db + 12288 + t16);
  }
  asm volatile("s_waitcnt vmcnt(4)" ::: "memory");   // tile 0 resident
  __builtin_amdgcn_s_barrier();
  __builtin_amdgcn_sched_barrier(0);

  int cur = 0;
#pragma unroll 1
  for (int tt = 0; tt < 32; ++tt) {
    const char* rb = lds + cur * 16384;
    int nx = cur + 2; if (nx >= 3) nx -= 3;
    char* sb = lds + nx * 16384;             // buffer of tile tt-1 (dead) -> tt+2
    const int ks = (tt + 2) * 32;
    bf16x8 af[4], bfv[4];
#pragma unroll
    for (int m = 0; m < 4; ++m) af[m] = *(const bf16x8*)(rb + offA + m * 1024);
#pragma unroll
    for (int n = 0; n < 4; ++n) bfv[n] = *(const bf16x8*)(rb + offB + n * 1024);
    if (tt < 30) {
      gload16(A0 + ks, sb + t16);
      gload16(A1 + ks, sb + 4096 + t16);
      gload16(B0 + ks, sb + 8192 + t16);
      gload16(B1 + ks, sb + 12288 + t16);
    }
    __builtin_amdgcn_s_setprio(1);
#pragma unroll
    for (int m = 0; m < 4; ++m)
#pragma unroll
      for (int n = 0; n < 4; ++n)
        acc[m][n] = __builtin_amdgcn_mfma_f32_16x16x32_bf16(af[m], bfv[n], acc[m][n], 0, 0, 0);
    __builtin_amdgcn_s_setprio(0);
    if (tt < 30)       asm volatile("s_waitcnt vmcnt(4)" ::: "memory");  // tt+1 resident
    else if (tt == 30) asm volatile("s_waitcnt vmcnt(0)" ::: "memory");  // tile 31 resident
    __builtin_amdgcn_s_barrier();
    __builtin_amdgcn_sched_barrier(0);
    cur = (cur + 1 == 3) ? 0 : cur + 1;
  }

  const int row0 = mt * 128 + wr + hi * 4;
  const int col0 = nt * 128 + wc + rsel;
  float bv[4];
#pragma unroll
  for (int n = 0; n < 4; ++n) bv[n] = bias[col0 + n * 16];
#pragma unroll
  for (int m = 0; m < 4; ++m) {
#pragma unroll
    for (int q = 0; q < 4; ++q) {
      const size_t rr = (size_t)(row0 + m * 16 + q) * 1024;
#pragma unroll
      for (int n = 0; n < 4; ++n) {
        float v = fmaxf(acc[m][n][q] + bv[n], 0.f);
        C[rr + col0 + n * 16] = (bf16_t)v;
      }
    }
  }
}

// ---------------- fused: G split-K GEMM (blocks 0..255) + t GEMV (rest) -----
// gemmK part: Gpart[slice] += W2T tile products (KS=256).
// t part: t[r] = H[r,:].w2b  -> tT1/tT2 (transposed), r = (blk-256)*4+wave.
__global__ __launch_bounds__(256)
void tg_kernel(const bf16_t* __restrict__ H, const float* __restrict__ w2b,
               float* __restrict__ tT1, float* __restrict__ tT2,
               const bf16_t* __restrict__ W2T, float* __restrict__ Gpart) {
  __shared__ __align__(16) bf16_t sA[128 * 32];
  __shared__ __align__(16) bf16_t sB[128 * 32];
  const int blk = (int)blockIdx.x;
  if (blk >= 256) {
    // ---- t GEMV ----
    const int wv = threadIdx.x >> 6, lane = threadIdx.x & 63;
    const int r = (blk - 256) * 4 + wv;
    const bf16_t* hrow = H + (size_t)r * 1024;
    float s = 0.f;
#pragma unroll
    for (int h = 0; h < 2; ++h) {
      bf16x8 v = *(const bf16x8*)(hrow + h * 512 + lane * 8);
#pragma unroll
      for (int e = 0; e < 8; ++e) s += (float)v[e] * w2b[h * 512 + lane * 8 + e];
    }
#pragma unroll
    for (int off = 32; off; off >>= 1) s += __shfl_xor(s, off);
    if (lane == 0) {
      const int b = r & 63;
      if (r < 16384) tT1[b * L1C + (r >> 6)] = s;
      else           tT2[b * L2C + ((r - 16384) >> 6)] = s;
    }
    return;
  }
  // ---- G split-K GEMM ----
  const int slice = blk >> 6;
  const int tl = blk & 63;
  const int mt = tl >> 3, nt = tl & 7;
  const int koff = slice * 256;

  const int f = threadIdx.x;
  const int lane = f & 63, w = f >> 6;
  const int sRow = f >> 2, sCol8 = (f & 3) * 8;

  const bf16_t* Ab = W2T + (size_t)mt * 128 * 1024 + (size_t)sRow * 1024 + sCol8;
  const bf16_t* Bb = W2T + (size_t)nt * 128 * 1024 + (size_t)sRow * 1024 + sCol8;

  bf16_t* sAp = sA + sRow * 32 + sCol8;
  bf16_t* sBp = sB + sRow * 32 + sCol8;

  const int wr = (w >> 1) * 64, wc = (w & 1) * 64;
  const int rsel = lane & 15, koff2 = (lane >> 4) * 8;
  const bf16_t* rA = sA + (wr + rsel) * 32 + koff2;
  const bf16_t* rB = sB + (wc + rsel) * 32 + koff2;

  f32x4 acc[4][4] = {};
  for (int kt = koff; kt < koff + 256; kt += 32) {
    __syncthreads();
    gload16(Ab + kt,             sAp);
    gload16(Ab + kt + 64 * 1024, sAp + 64 * 32);
    gload16(Bb + kt,             sBp);
    gload16(Bb + kt + 64 * 1024, sBp + 64 * 32);
    asm volatile("s_waitcnt vmcnt(0)" ::: "memory");
    __syncthreads();
    bf16x8 af[4], bfv[4];
#pragma unroll
    for (int m = 0; m < 4; ++m) af[m] = *(const bf16x8*)(rA + m * 16 * 32);
#pragma unroll
    for (int n = 0; n < 4; ++n) bfv[n] = *(const bf16x8*)(rB + n * 16 * 32);
#pragma unroll
    for (int m = 0; m < 4; ++m)
#pragma unroll
      for (int n = 0; n < 4; ++n)
        acc[m][n] = __builtin_amdgcn_mfma_f32_16x16x32_bf16(af[m], bfv[n], acc[m][n], 0, 0, 0);
  }

  float* Pb = Gpart + (size_t)slice * 1048576;
  const int row0 = mt * 128 + wr + (lane >> 4) * 4;
  const int col0 = nt * 128 + wc + rsel;
#pragma unroll
  for (int n = 0; n < 4; ++n) {
    const int c = col0 + n * 16;
#pragma unroll
    for (int m = 0; m < 4; ++m) {
      const int r = row0 + m * 16;
#pragma unroll
      for (int q = 0; q < 4; ++q)
        Pb[(size_t)(r + q) * 1024 + c] = acc[m][n][q];
    }
  }
}

// reduce 4 G-partials -> bf16 G
__global__ __launch_bounds__(256)
void g_reduce(const float* __restrict__ Gp, bf16_t* __restrict__ GB) {
  const int i4 = blockIdx.x * 256 + threadIdx.x;
  float4 a = ((const float4*)Gp)[i4];
  float4 b = ((const float4*)(Gp + 1048576))[i4];
  float4 c = ((const float4*)(Gp + 2097152))[i4];
  float4 d = ((const float4*)(Gp + 3145728))[i4];
  bf16x4 o = { (bf16_t)(a.x + b.x + c.x + d.x), (bf16_t)(a.y + b.y + c.y + d.y),
               (bf16_t)(a.z + b.z + c.z + d.z), (bf16_t)(a.w + b.w + c.w + d.w) };
  ((bf16x4*)GB)[i4] = o;
}

// ---------------- bf16 MLP GEMM, 256x256 tile, 8-wave (r2/r3 proven) ----------
__global__ __launch_bounds__(512, 2)
void mlp_gemm8(const bf16_t* __restrict__ A, const bf16_t* __restrict__ W,
               const float* __restrict__ bias, bf16_t* __restrict__ C,
               int Mtiles, int relu) {
  const int nwg = Mtiles * 4;
  const int cpx = nwg >> 3;
  const int wg  = ((int)blockIdx.x & 7) * cpx + ((int)blockIdx.x >> 3);
  const int mt = wg >> 2, nt = wg & 3;

  __shared__ __align__(16) char lds[131072];

  const int t    = threadIdx.x;
  const int lane = t & 63, wid = t >> 6;
  const int wm = wid >> 2, wn = wid & 3;
  const int rsel = lane & 15, hi = lane >> 4;
  const int t16 = t * 16;

  const int P0 = t16, P1 = 8192 + t16;
  const int Lg0 = P0 ^ ((P0 >> 3) & 0x30);
  const int Lg1 = P1 ^ ((P1 >> 3) & 0x30);
  const int rS0 = Lg0 >> 6, cS0 = (Lg0 & 63) >> 1;
  const int rS1 = Lg1 >> 6, cS1 = (Lg1 & 63) >> 1;
  const bf16_t* pA0 = A + (size_t)(mt * 256 + rS0) * 1024 + cS0;
  const bf16_t* pA1 = A + (size_t)(mt * 256 + rS1) * 1024 + cS1;
  const bf16_t* pB0 = W + (size_t)(nt * 256 + rS0) * 1024 + cS0;
  const bf16_t* pB1 = W + (size_t)(nt * 256 + rS1) * 1024 + cS1;

  const int kchunk = (hi ^ ((rsel >> 1) & 3)) << 4;
  const int offA = ((wm * 128 + rsel) << 6) + kchunk;
  const int offB = 16384 + ((wn * 64 + rsel) << 6) + kchunk;

  f32x4 acc[8][4] = {};
  bf16x8 bfr[4];

#pragma unroll
  for (int p = 0; p < 3; ++p) {
    char* db = lds + p * 32768;
    gload16(pA0 + p * 32, db + t16);
    gload16(pA1 + p * 32, db + 8192 + t16);
    gload16(pB0 + p * 32, db + 16384 + t16);
    gload16(pB1 + p * 32, db + 24576 + t16);
  }
  asm volatile("s_waitcnt vmcnt(8)" ::: "memory");
  __builtin_amdgcn_s_barrier();
  __builtin_amdgcn_sched_barrier(0);

#pragma unroll 1
  for (int tt = 0; tt < 32; ++tt) {
    const char* rb = lds + (tt & 3) * 32768;
    char* sb = lds + ((tt + 3) & 3) * 32768;
    const int ks = (tt + 3) * 32;
    bf16x8 af[4];
#pragma unroll
    for (int m = 0; m < 4; ++m) af[m] = *(const bf16x8*)(rb + offA + m * 1024);
#pragma unroll
    for (int n = 0; n < 4; ++n) bfr[n] = *(const bf16x8*)(rb + offB + n * 1024);
    if (tt < 29) {
      gload16(pA0 + ks, sb + t16);
      gload16(pA1 + ks, sb + 8192 + t16);
    }
    __builtin_amdgcn_s_setprio(1);
#pragma unroll
    for (int m = 0; m < 4; ++m)
#pragma unroll
      for (int n = 0; n < 4; ++n)
        acc[m][n] = __builtin_amdgcn_mfma_f32_16x16x32_bf16(af[m], bfr[n], acc[m][n], 0, 0, 0);
    __builtin_amdgcn_s_setprio(0);
    __builtin_amdgcn_s_barrier();
    __builtin_amdgcn_sched_barrier(0);
#pragma unroll
    for (int m = 0; m < 4; ++m) af[m] = *(const bf16x8*)(rb + offA + (m + 4) * 1024);
    if (tt < 29) {
      gload16(pB0 + ks, sb + 16384 + t16);
      gload16(pB1 + ks, sb + 24576 + t16);
    }
    __builtin_amdgcn_s_setprio(1);
#pragma unroll
    for (int m = 0; m < 4; ++m)
#pragma unroll
      for (int n = 0; n < 4; ++n)
        acc[m + 4][n] = __builtin_amdgcn_mfma_f32_16x16x32_bf16(af[m], bfr[n], acc[m + 4][n], 0, 0, 0);
    __builtin_amdgcn_s_setprio(0);
    if (tt < 29)       asm volatile("s_waitcnt vmcnt(8)" ::: "memory");
    else if (tt == 29) asm volatile("s_waitcnt vmcnt(4)" ::: "memory");
    else if (tt == 30) asm volatile("s_waitcnt vmcnt(0)" ::: "memory");
    __builtin_amdgcn_s_barrier();
    __builtin_amdgcn_sched_barrier(0);
  }

  const int row0 = mt * 256 + wm * 128 + hi * 4;
  const int col0 = nt * 256 + wn * 64 + rsel;
  float bv[4];
#pragma unroll
  for (int n = 0; n < 4; ++n) bv[n] = bias[col0 + n * 16];
#pragma unroll
  for (int m = 0; m < 8; ++m) {
#pragma unroll
    for (int q = 0; q < 4; ++q) {
      const size_t rr = (size_t)(row0 + m * 16 + q) * 1024;
#pragma unroll
      for (int n = 0; n < 4; ++n) {
        float v = acc[m][n][q] + bv[n];
        if (relu) v = fmaxf(v, 0.f);
        C[rr + col0 + n * 16] = (bf16_t)v;
      }
    }
  }
}

// ---------------- pool split-K GEMM: U(256x1024) * W2^T, 8 K-slices ----------
__global__ __launch_bounds__(256)
void pool_gemmK(const bf16_t* __restrict__ A, const bf16_t* __restrict__ W,
                float* __restrict__ P) {
  const int slice = (int)blockIdx.x >> 4;
  const int tl = (int)blockIdx.x & 15;
  const int mt = tl >> 3, nt = tl & 7;
  const int koff = slice * 128;

  const int f = threadIdx.x;
  const int lane = f & 63, w = f >> 6;
  const int sRow = f >> 2, sCol8 = (f & 3) * 8;

  const bf16_t* Ab = A + (size_t)mt * 128 * 1024 + (size_t)sRow * 1024 + sCol8;
  const bf16_t* Bb = W + (size_t)nt * 128 * 1024 + (size_t)sRow * 1024 + sCol8;

  __shared__ __align__(16) bf16_t sA[128 * 32];
  __shared__ __align__(16) bf16_t sB[128 * 32];
  bf16_t* sAp = sA + sRow * 32 + sCol8;
  bf16_t* sBp = sB + sRow * 32 + sCol8;

  const int wr = (w >> 1) * 64, wc = (w & 1) * 64;
  const int rsel = lane & 15, koff2 = (lane >> 4) * 8;
  const bf16_t* rA = sA + (wr + rsel) * 32 + koff2;
  const bf16_t* rB = sB + (wc + rsel) * 32 + koff2;

  f32x4 acc[4][4] = {};
  for (int kt = koff; kt < koff + 128; kt += 32) {
    __syncthreads();
    gload16(Ab + kt,             sAp);
    gload16(Ab + kt + 64 * 1024, sAp + 64 * 32);
    gload16(Bb + kt,             sBp);
    gload16(Bb + kt + 64 * 1024, sBp + 64 * 32);
    asm volatile("s_waitcnt vmcnt(0)" ::: "memory");
    __syncthreads();
    bf16x8 af[4], bfv[4];
#pragma unroll
    for (int m = 0; m < 4; ++m) af[m] = *(const bf16x8*)(rA + m * 16 * 32);
#pragma unroll
    for (int n = 0; n < 4; ++n) bfv[n] = *(const bf16x8*)(rB + n * 16 * 32);
#pragma unroll
    for (int m = 0; m < 4; ++m)
#pragma unroll
      for (int n = 0; n < 4; ++n)
        acc[m][n] = __builtin_amdgcn_mfma_f32_16x16x32_bf16(af[m], bfv[n], acc[m][n], 0, 0, 0);
  }

  float* Pb = P + (size_t)slice * 262144;
  const int row0 = mt * 128 + wr + (lane >> 4) * 4;
  const int col0 = nt * 128 + wc + rsel;
#pragma unroll
  for (int n = 0; n < 4; ++n) {
    const int c = col0 + n * 16;
#pragma unroll
    for (int m = 0; m < 4; ++m) {
      const int r = row0 + m * 16;
#pragma unroll
      for (int q = 0; q < 4; ++q)
        Pb[(size_t)(r + q) * 1024 + c] = acc[m][n][q];
    }
  }
}

// reduce 8 pool partials + bias, remap rows -> d_out
__global__ __launch_bounds__(256)
void pool_reduce(const float* __restrict__ Pp, const float* __restrict__ b2,
                 float* __restrict__ out) {
  const int idx = blockIdx.x * 256 + threadIdx.x;
  const int r = idx >> 10, c = idx & 1023;
  float s = b2[c];
#pragma unroll
  for (int sl = 0; sl < 8; ++sl) s += Pp[(size_t)sl * 262144 + idx];
  const int g = r >> 6, b = r & 63;
  out[(size_t)(g >> 1) * 131072 + (size_t)b * 2048 + (g & 1) * 1024 + c] = s;
}

// ---------------- logits: oz[b,i,j] = z1[b,i,:].h2[b,j,:] ----------------
__global__ __launch_bounds__(256)
void logits_gemm(const bf16_t* __restrict__ Y1, const bf16_t* __restrict__ Y2,
                 float* __restrict__ O) {
  const int wg = ((int)blockIdx.x & 7) * 48 + ((int)blockIdx.x >> 3);
  const int b = wg / 6, t6 = wg % 6;
  const int mt = t6 / 3, nt = t6 % 3;

  __shared__ __align__(16) char lds[65536];    // 4 bufs x (A 8KB + B 8KB)

  const int t = threadIdx.x;
  const int lane = t & 63, w = t >> 6;
  const int sRow = t >> 2;
  const int sCol8 = (((t & 3) ^ ((t >> 3) & 3))) * 8;   // pre-swizzled source chunk
  const int t16 = t * 16;

  const int i0 = mt * 128 + sRow;
  const int i1 = i0 + 64;
  int j0 = nt * 128 + sRow;      if (j0 > L2C - 1) j0 = L2C - 1;
  int j1 = nt * 128 + sRow + 64; if (j1 > L2C - 1) j1 = L2C - 1;
  const bf16_t* A0 = Y1 + ((size_t)i0 * BC + b) * DC + sCol8;
  const bf16_t* A1 = Y1 + ((size_t)i1 * BC + b) * DC + sCol8;
  const bf16_t* B0 = Y2 + ((size_t)j0 * BC + b) * DC + sCol8;
  const bf16_t* B1 = Y2 + ((size_t)j1 * BC + b) * DC + sCol8;

  const int wr = (w >> 1) * 64, wc = (w & 1) * 64;
  const int rsel = lane & 15, hi = lane >> 4;
  const int kchunk = (hi ^ ((rsel >> 1) & 3)) << 4;
  const int offA = ((wr + rsel) << 6) + kchunk;
  const int offB = 8192 + ((wc + rsel) << 6) + kchunk;

  f32x4 acc[4][4] = {};

  // prologue: stage tiles 0..2
#pragma unroll
  for (int p = 0; p < 3; ++p) {
    char* db = lds + p * 16384;
    gload16(A0 + p * 32, db + t16);
    gload16(A1 + p * 32, db + 4096 + t16);
    gload16(B0 + p * 32, db + 8192 + t16);
    gload16(B1 + p * 32, db + 12288 + t16);
  }
  asm volatile("s_waitcnt vmcnt(8)" ::: "memory");
  __builtin_amdgcn_s_barrier();
  __builtin_amdgcn_sched_barrier(0);

#pragma unroll 1
  for (int tt = 0; tt < 32; ++tt) {
    const char* rb = lds + (tt & 3) * 16384;
    char* sb = lds + ((tt + 3) & 3) * 16384;
    const int ks = (tt + 3) * 32;
    bf16x8 af[4], bfv[4];
#pragma unroll
    for (int m = 0; m < 4; ++m) af[m] = *(const bf16x8*)(rb + offA + m * 1024);
#pragma unroll
    for (int n = 0; n < 4; ++n) bfv[n] = *(const bf16x8*)(rb + offB + n * 1024);
    if (tt < 29) {
      gload16(A0 + ks, sb + t16);
      gload16(A1 + ks, sb + 4096 + t16);
      gload16(B0 + ks, sb + 8192 + t16);
      gload16(B1 + ks, sb + 12288 + t16);
    }
    __builtin_amdgcn_s_setprio(1);
#pragma unroll
    for (int m = 0; m < 4; ++m)
#pragma unroll
      for (int n = 0; n < 4; ++n)
        acc[m][n] = __builtin_amdgcn_mfma_f32_16x16x32_bf16(af[m], bfv[n], acc[m][n], 0, 0, 0);
    __builtin_amdgcn_s_setprio(0);
    if (tt < 29)       asm volatile("s_waitcnt vmcnt(8)" ::: "memory");
    else if (tt == 29) asm volatile("s_waitcnt vmcnt(4)" ::: "memory");
    else if (tt == 30) asm volatile("s_waitcnt vmcnt(0)" ::: "memory");
    __builtin_amdgcn_s_barrier();
    __builtin_amdgcn_sched_barrier(0);
  }

  float* Ob = O + (size_t)b * L1C * L2C;
  const int row0 = mt * 128 + wr + hi * 4;
  const int col0 = nt * 128 + wc + rsel;
#pragma unroll
  for (int n = 0; n < 4; ++n) {
    const int c = col0 + n * 16;
    if (c < L2C) {
#pragma unroll
      for (int m = 0; m < 4; ++m) {
        const int r = row0 + m * 16;
#pragma unroll
        for (int q = 0; q < 4; ++q)
          Ob[(size_t)(r + q) * L2C + c] = acc[m][n][q];
      }
    }
  }
}

// ---------------- softmax stats (with rank-1 terms t1,t2) ----------------
__global__ __launch_bounds__(256)
void row_stats(const float* __restrict__ O, const float* __restrict__ tT2,
               float* __restrict__ rowM, float* __restrict__ rowInv) {
  const int gw = blockIdx.x * 4 + (threadIdx.x >> 6);
  const int lane = threadIdx.x & 63;
  const int b = gw >> 8;
  const float* row = O + (size_t)gw * L2C;
  const float* t2 = tT2 + b * L2C;
  float v[5];
  float m = -1e30f;
#pragma unroll
  for (int t = 0; t < 5; ++t) { v[t] = row[t * 64 + lane] + t2[t * 64 + lane]; m = fmaxf(m, v[t]); }
#pragma unroll
  for (int off = 32; off; off >>= 1) m = fmaxf(m, __shfl_xor(m, off));
  float s = 0.f;
#pragma unroll
  for (int t = 0; t < 5; ++t) s += __expf(v[t] - m);
#pragma unroll
  for (int off = 32; off; off >>= 1) s += __shfl_xor(s, off);
  if (lane == 0) { rowM[gw] = m; rowInv[gw] = 1.f / s; }
}

__global__ __launch_bounds__(256)
void col_stats_c1(const float* __restrict__ O, const float* __restrict__ tT1,
                  const float* __restrict__ tT2,
                  const float* __restrict__ rowM, const float* __restrict__ rowInv,
                  float* __restrict__ colM, float* __restrict__ colInv,
                  float* __restrict__ c1) {
  const int b = blockIdx.x / 5, jb = blockIdx.x % 5;
  const int jl = threadIdx.x & 63, ig = threadIdx.x >> 6;
  const int j = jb * 64 + jl;
  const float* Ob = O + (size_t)b * L1C * L2C + j;
  const float* rM = rowM + b * L1C;
  const float* rI = rowInv + b * L1C;
  const float* t1 = tT1 + b * L1C;
  const float t2j = tT2[b * L2C + j];
  float m = -1e30f, s = 0.f, cp = 0.f;
  for (int i = ig; i < L1C; i += 4) {
    float ov = Ob[(size_t)i * L2C];
    float v = ov + t1[i];
    float mn = fmaxf(m, v);
    s = s * __expf(m - mn) + __expf(v - mn);
    m = mn;
    cp += __expf(ov + t2j - rM[i]) * rI[i];
  }
  __shared__ float sm[4][64], ss[4][64], sc[4][64];
  sm[ig][jl] = m; ss[ig][jl] = s; sc[ig][jl] = cp;
  __syncthreads();
  if (ig == 0) {
    for (int g = 1; g < 4; ++g) {
      float mg = sm[g][jl], sg = ss[g][jl];
      float mn = fmaxf(m, mg);
      s = s * __expf(m - mn) + sg * __expf(mg - mn);
      m = mn;
      cp += sc[g][jl];
    }
    colM[b * L2C + j] = m;
    colInv[b * L2C + j] = 1.f / s;
    c1[b * L2C + j] = cp;
  }
}

__global__ __launch_bounds__(256)
void c2_kernel(const float* __restrict__ O, const float* __restrict__ tT1,
               const float* __restrict__ colM, const float* __restrict__ colInv,
               float* __restrict__ c2) {
  const int gw = blockIdx.x * 4 + (threadIdx.x >> 6);
  const int lane = threadIdx.x & 63;
  const int b = gw >> 8;
  const float* row = O + (size_t)gw * L2C;
  const float* cM = colM + b * L2C;
  const float* cI = colInv + b * L2C;
  const float t1i = tT1[b * L1C + (gw & 255)];
  float s = 0.f;
#pragma unroll
  for (int t = 0; t < 5; ++t) {
    const int j = t * 64 + lane;
    s += __expf(row[j] + t1i - cM[j]) * cI[j];
  }
#pragma unroll
  for (int off = 32; off; off >>= 1) s += __shfl_xor(s, off);
  if (lane == 0) c2[gw] = s;
}

// ---------------- weighted h-sums -> U (256x1024 bf16) ----------------
__global__ __launch_bounds__(256)
void u_kernel(const bf16_t* __restrict__ H, const float* __restrict__ c1,
              const float* __restrict__ c2, bf16_t* __restrict__ Ub) {
  const int b = blockIdx.x >> 2;
  const int d = (blockIdx.x & 3) * 256 + threadIdx.x;
  const bf16_t* H2 = H + (size_t)L1C * BC * DC;
  float s1 = 0.f, s1c = 0.f, s2 = 0.f, s2c = 0.f;
  const float* c2b = c2 + b * L1C;
  for (int i = 0; i < L1C; ++i) {
    float v = (float)H[((size_t)i * BC + b) * DC + d];
    s1 += v; s1c += c2b[i] * v;
  }
  const float* c1b = c1 + b * L2C;
  for (int j = 0; j < L2C; ++j) {
    float v = (float)H2[((size_t)j * BC + b) * DC + d];
    s2 += v; s2c += c1b[j] * v;
  }
  Ub[(size_t)(0 * 64 + b) * 1024 + d] = (bf16_t)(s1  * (1.f / L1C));
  Ub[(size_t)(1 * 64 + b) * 1024 + d] = (bf16_t)(s2c * (1.f / L1C));
  Ub[(size_t)(2 * 64 + b) * 1024 + d] = (bf16_t)(s2  * (1.f / L2C));
  Ub[(size_t)(3 * 64 + b) * 1024 + d] = (bf16_t)(s1c * (1.f / L2C));
}

// ---------------- host ----------------
extern "C" void kernel_launch(void* const* d_in, const int* in_sizes, int n_in,
                              void* d_out, int out_size, void* d_ws, size_t ws_size,
                              hipStream_t stream) {
  const float* r1 = (const float*)d_in[0];
  const float* r2 = (const float*)d_in[1];
  const float* W1 = (const float*)d_in[2];
  const float* b1 = (const float*)d_in[3];
  const float* W2 = (const float*)d_in[4];
  const float* b2 = (const float*)d_in[5];
  float* out = (float*)d_out;
  char* ws = (char*)d_ws;

  const size_t M1 = (size_t)L1C * BC;   // 16384
  const size_t M2 = (size_t)L2C * BC;   // 20480
  const size_t Mt = M1 + M2;            // 36864

  size_t off = 0;
  bf16_t* XB  = (bf16_t*)(ws + off); off += Mt * DC * 2;        // 72MB: A-bf16, then Z + O + Gpart
  bf16_t* HB  = (bf16_t*)(ws + off); off += Mt * DC * 2;        // 72MB, h; head reused as Ppart
  bf16_t* WB1 = (bf16_t*)(ws + off); off += (size_t)DC * DC * 2;
  bf16_t* WB2 = (bf16_t*)(ws + off); off += (size_t)DC * DC * 2;
  bf16_t* W2T = (bf16_t*)(ws + off); off += (size_t)DC * DC * 2;
  bf16_t* GB  = (bf16_t*)(ws + off); off += (size_t)DC * DC * 2;
  float* w2b   = (float*)(ws + off); off += 4096;
  float* zb    = (float*)(ws + off); off += 4096;
  float* tT1   = (float*)(ws + off); off += BC * L1C * 4;
  float* tT2   = (float*)(ws + off); off += BC * L2C * 4;
  float* rowM  = (float*)(ws + off); off += BC * L1C * 4;
  float* rowIv = (float*)(ws + off); off += BC * L1C * 4;
  float* colM  = (float*)(ws + off); off += BC * L2C * 4;
  float* colIv = (float*)(ws + off); off += BC * L2C * 4;
  float* c1v   = (float*)(ws + off); off += BC * L2C * 4;
  float* c2v   = (float*)(ws + off); off += BC * L1C * 4;
  bf16_t* Ub   = (bf16_t*)(ws + off); off += 256 * DC * 2;

  bf16_t* Z = XB;                                   // 16384x1024 bf16 (32MB)
  float*  O = (float*)((char*)XB + 35651584);       // 21MB logits
  float*  Gpart = (float*)((char*)XB + 58720256);   // 16MB (4 slices)
  float*  Ppart = (float*)HB;                       // 8MB (8 slices), HB dead then
  bf16_t* H2 = HB + M1 * DC;

  // 1. fused prep (converts + W2T + w2b + zb)
  prep_kernel<<<10817, 256, 0, stream>>>(r1, r2, XB, W1, WB1, W2, WB2, W2T,
                                         b2, w2b, zb);

  // 2. h = relu(x W1^T + b1): swizzled 128^2 ring-3, 3 blocks/CU
  gemm1_128<<<2304, 256, 0, stream>>>(XB, WB1, b1, HB);

  // 3. fused: G split-K (blocks 0..255, overlaps) + t GEMV (blocks 256..9471)
  tg_kernel<<<9472, 256, 0, stream>>>(HB, w2b, tT1, tT2, W2T, Gpart);
  g_reduce<<<1024, 256, 0, stream>>>(Gpart, GB);

  // 4. z1 = h1 G
  mlp_gemm8<<<256, 512, 0, stream>>>(HB, GB, zb, Z, 64, 0);

  // 5. oz[b,i,j] = z1 . h2
  logits_gemm<<<384, 256, 0, stream>>>(Z, H2, O);

  // 6. softmax stats with rank-1 corrections
  row_stats<<<4096, 256, 0, stream>>>(O, tT2, rowM, rowIv);
  col_stats_c1<<<320, 256, 0, stream>>>(O, tT1, tT2, rowM, rowIv, colM, colIv, c1v);
  c2_kernel<<<4096, 256, 0, stream>>>(O, tT1, colM, colIv, c2v);

  // 7. weighted h pools -> U;  out = U W2^T + b2, split-K + reduce
  u_kernel<<<256, 256, 0, stream>>>(HB, c1v, c2v, Ub);
  pool_gemmK<<<128, 256, 0, stream>>>(Ub, WB2, Ppart);
  pool_reduce<<<1024, 256, 0, stream>>>(Ppart, b2, out);
}

// Round 14
// 277.521 us; speedup vs baseline: 1.2560x; 1.0185x over previous
//
#include <hip/hip_runtime.h>
#include <stdint.h>

#define L1C 256
#define L2C 320
#define BC  64
#define DC  1024

typedef __bf16 bf16_t;
typedef __bf16 bf16x8 __attribute__((ext_vector_type(8)));
typedef __bf16 bf16x4 __attribute__((ext_vector_type(4)));
typedef float  f32x4  __attribute__((ext_vector_type(4)));

__device__ __forceinline__ void gload16(const void* g, void* l) {
  __builtin_amdgcn_global_load_lds(
      (__attribute__((address_space(1))) void*)g,
      (__attribute__((address_space(3))) void*)l, 16, 0, 0);
}

// ---------------- fused prep: converts + W2T + w2b + zb-zero ----------------
__global__ __launch_bounds__(256)
void prep_kernel(const float* __restrict__ r1, const float* __restrict__ r2,
                 bf16_t* __restrict__ XB,
                 const float* __restrict__ W1, bf16_t* __restrict__ WB1,
                 const float* __restrict__ W2, bf16_t* __restrict__ WB2,
                 bf16_t* __restrict__ W2T,
                 const float* __restrict__ b2, float* __restrict__ w2b,
                 float* __restrict__ zb) {
  __shared__ float buf[32 * 33];
  const int b = (int)blockIdx.x;
  if (b < 9216) {
    const float* src;
    size_t soff;
    if (b < 4096) { src = r1; soff = (size_t)b * 1024; }
    else          { src = r2; soff = (size_t)(b - 4096) * 1024; }
    const size_t doff = (size_t)b * 1024;
#pragma unroll
    for (int k = 0; k < 4; ++k) {
      const int i = threadIdx.x + k * 256;
      float4 v = ((const float4*)src)[soff + i];
      bf16x4 o = { (__bf16)v.x, (__bf16)v.y, (__bf16)v.z, (__bf16)v.w };
      ((bf16x4*)XB)[doff + i] = o;
    }
  } else if (b < 9728) {
    const int bb = b - 9216;
    const float* src = (bb < 256) ? W1 : W2;
    bf16_t* dst = (bb < 256) ? WB1 : WB2;
    const size_t base = (size_t)(bb & 255) * 1024;
#pragma unroll
    for (int k = 0; k < 4; ++k) {
      const int i = threadIdx.x + k * 256;
      float4 v = ((const float4*)src)[base + i];
      bf16x4 o = { (__bf16)v.x, (__bf16)v.y, (__bf16)v.z, (__bf16)v.w };
      ((bf16x4*)dst)[base + i] = o;
    }
  } else if (b < 10752) {
    const int bb = b - 9728;
    float (*tile)[33] = (float(*)[33])buf;
    const int tx = threadIdx.x & 31, ty = threadIdx.x >> 5;
    const int x0 = (bb & 31) * 32, y0 = (bb >> 5) * 32;
#pragma unroll
    for (int k = 0; k < 32; k += 8)
      tile[ty + k][tx] = W2[(size_t)(y0 + ty + k) * 1024 + x0 + tx];
    __syncthreads();
#pragma unroll
    for (int k = 0; k < 32; k += 8)
      W2T[(size_t)(x0 + ty + k) * 1024 + y0 + tx] = (bf16_t)tile[tx][ty + k];
  } else if (b < 10816) {
    const int bb = b - 10752;
    float (*red)[17] = (float(*)[17])buf;
    const int dt = threadIdx.x & 15, kg = threadIdx.x >> 4;
    const int d = bb * 16 + dt;
    float s = 0.f;
    for (int k = kg * 64; k < kg * 64 + 64; ++k)
      s += W2[(size_t)k * 1024 + d] * b2[k];
    red[kg][dt] = s;
    __syncthreads();
    if (kg == 0) {
      float t = 0.f;
#pragma unroll
      for (int g = 0; g < 16; ++g) t += red[g][dt];
      w2b[d] = t;
    }
  } else {
#pragma unroll
    for (int k = 0; k < 4; ++k) zb[threadIdx.x + k * 256] = 0.f;
  }
}

// ---------------- fused GEMM1 + G ------------------------------------------
// blocks [0,64):   G = W2T . W2T^T (full K=1024), 128x128 tile -> bf16 GB
// blocks [64,2368): h = relu(A W1^T + b1), 128^2 ring-3 XOR-swizzled (proven)
__global__ __launch_bounds__(256, 3)
void g1g_kernel(const bf16_t* __restrict__ A, const bf16_t* __restrict__ W,
                const float* __restrict__ bias, bf16_t* __restrict__ C,
                const bf16_t* __restrict__ W2T, bf16_t* __restrict__ GB) {
  __shared__ __align__(16) char lds[49152];
  const int blk = (int)blockIdx.x;

  if (blk < 64) {
    // ---- G block: 2-barrier 128^2 full-K GEMM (proven gemmK structure) ----
    bf16_t* sA = (bf16_t*)lds;
    bf16_t* sB = (bf16_t*)(lds + 8192);
    const int f = threadIdx.x;
    const int lane = f & 63, w4 = f >> 6;
    const int sRowG = f >> 2, sCol8G = (f & 3) * 8;
    const bf16_t* Ab = W2T + (size_t)(blk >> 3) * 128 * 1024 + (size_t)sRowG * 1024 + sCol8G;
    const bf16_t* Bb = W2T + (size_t)(blk & 7) * 128 * 1024 + (size_t)sRowG * 1024 + sCol8G;
    bf16_t* sAp = sA + sRowG * 32 + sCol8G;
    bf16_t* sBp = sB + sRowG * 32 + sCol8G;
    const int wrG = (w4 >> 1) * 64, wcG = (w4 & 1) * 64;
    const int rselG = lane & 15, koff2 = (lane >> 4) * 8;
    const bf16_t* rA = sA + (wrG + rselG) * 32 + koff2;
    const bf16_t* rB = sB + (wcG + rselG) * 32 + koff2;
    f32x4 acc[4][4] = {};
    for (int kt = 0; kt < 1024; kt += 32) {
      __syncthreads();
      gload16(Ab + kt,             sAp);
      gload16(Ab + kt + 64 * 1024, sAp + 64 * 32);
      gload16(Bb + kt,             sBp);
      gload16(Bb + kt + 64 * 1024, sBp + 64 * 32);
      asm volatile("s_waitcnt vmcnt(0)" ::: "memory");
      __syncthreads();
      bf16x8 af[4], bfv[4];
#pragma unroll
      for (int m = 0; m < 4; ++m) af[m] = *(const bf16x8*)(rA + m * 16 * 32);
#pragma unroll
      for (int n = 0; n < 4; ++n) bfv[n] = *(const bf16x8*)(rB + n * 16 * 32);
#pragma unroll
      for (int m = 0; m < 4; ++m)
#pragma unroll
        for (int n = 0; n < 4; ++n)
          acc[m][n] = __builtin_amdgcn_mfma_f32_16x16x32_bf16(af[m], bfv[n], acc[m][n], 0, 0, 0);
    }
    const int row0 = (blk >> 3) * 128 + wrG + (lane >> 4) * 4;
    const int col0 = (blk & 7) * 128 + wcG + rselG;
#pragma unroll
    for (int n = 0; n < 4; ++n) {
      const int c = col0 + n * 16;
#pragma unroll
      for (int m = 0; m < 4; ++m) {
        const int r = row0 + m * 16;
#pragma unroll
        for (int q = 0; q < 4; ++q)
          GB[(size_t)(r + q) * 1024 + c] = (bf16_t)acc[m][n][q];
      }
    }
    return;
  }

  // ---- gemm1 block ----
  const int bid = blk - 64;
  const int wg = (bid & 7) * 288 + (bid >> 3);
  const int mt = wg >> 3, nt = wg & 7;

  const int t = threadIdx.x;
  const int lane = t & 63, w = t >> 6;
  const int sRow = t >> 2;
  const int sCol8 = (((t & 3) ^ ((t >> 3) & 3))) * 8;   // pre-swizzled source chunk
  const int t16 = t * 16;

  const bf16_t* A0 = A + (size_t)(mt * 128 + sRow) * 1024 + sCol8;
  const bf16_t* A1 = A0 + (size_t)64 * 1024;
  const bf16_t* B0 = W + (size_t)(nt * 128 + sRow) * 1024 + sCol8;
  const bf16_t* B1 = B0 + (size_t)64 * 1024;

  const int wr = (w >> 1) * 64, wc = (w & 1) * 64;
  const int rsel = lane & 15, hi = lane >> 4;
  const int kchunk = (hi ^ ((rsel >> 1) & 3)) << 4;
  const int offA = ((wr + rsel) << 6) + kchunk;
  const int offB = 8192 + ((wc + rsel) << 6) + kchunk;

  f32x4 acc[4][4] = {};

  // prologue: stage tiles 0,1
#pragma unroll
  for (int p = 0; p < 2; ++p) {
    char* db = lds + p * 16384;
    gload16(A0 + p * 32, db + t16);
    gload16(A1 + p * 32, db + 4096 + t16);
    gload16(B0 + p * 32, db + 8192 + t16);
    gload16(B1 + p * 32, db + 12288 + t16);
  }
  asm volatile("s_waitcnt vmcnt(4)" ::: "memory");   // tile 0 resident
  __builtin_amdgcn_s_barrier();
  __builtin_amdgcn_sched_barrier(0);

  int cur = 0;
#pragma unroll 1
  for (int tt = 0; tt < 32; ++tt) {
    const char* rb = lds + cur * 16384;
    int nx = cur + 2; if (nx >= 3) nx -= 3;
    char* sb = lds + nx * 16384;             // buffer of tile tt-1 (dead) -> tt+2
    const int ks = (tt + 2) * 32;
    bf16x8 af[4], bfv[4];
#pragma unroll
    for (int m = 0; m < 4; ++m) af[m] = *(const bf16x8*)(rb + offA + m * 1024);
#pragma unroll
    for (int n = 0; n < 4; ++n) bfv[n] = *(const bf16x8*)(rb + offB + n * 1024);
    if (tt < 30) {
      gload16(A0 + ks, sb + t16);
      gload16(A1 + ks, sb + 4096 + t16);
      gload16(B0 + ks, sb + 8192 + t16);
      gload16(B1 + ks, sb + 12288 + t16);
    }
    __builtin_amdgcn_s_setprio(1);
#pragma unroll
    for (int m = 0; m < 4; ++m)
#pragma unroll
      for (int n = 0; n < 4; ++n)
        acc[m][n] = __builtin_amdgcn_mfma_f32_16x16x32_bf16(af[m], bfv[n], acc[m][n], 0, 0, 0);
    __builtin_amdgcn_s_setprio(0);
    if (tt < 30)       asm volatile("s_waitcnt vmcnt(4)" ::: "memory");
    else if (tt == 30) asm volatile("s_waitcnt vmcnt(0)" ::: "memory");
    __builtin_amdgcn_s_barrier();
    __builtin_amdgcn_sched_barrier(0);
    cur = (cur + 1 == 3) ? 0 : cur + 1;
  }

  const int row0 = mt * 128 + wr + hi * 4;
  const int col0 = nt * 128 + wc + rsel;
  float bv[4];
#pragma unroll
  for (int n = 0; n < 4; ++n) bv[n] = bias[col0 + n * 16];
#pragma unroll
  for (int m = 0; m < 4; ++m) {
#pragma unroll
    for (int q = 0; q < 4; ++q) {
      const size_t rr = (size_t)(row0 + m * 16 + q) * 1024;
#pragma unroll
      for (int n = 0; n < 4; ++n) {
        float v = fmaxf(acc[m][n][q] + bv[n], 0.f);
        C[rr + col0 + n * 16] = (bf16_t)v;
      }
    }
  }
}

// ---------------- t[r] = h[r,:] . w2b ----------------
__global__ __launch_bounds__(256)
void t_kernel(const bf16_t* __restrict__ H, const float* __restrict__ w2b,
              float* __restrict__ tT1, float* __restrict__ tT2) {
  const int wv = threadIdx.x >> 6, lane = threadIdx.x & 63;
  const int r = blockIdx.x * 4 + wv;
  const bf16_t* hrow = H + (size_t)r * 1024;
  float s = 0.f;
#pragma unroll
  for (int h = 0; h < 2; ++h) {
    bf16x8 v = *(const bf16x8*)(hrow + h * 512 + lane * 8);
#pragma unroll
    for (int e = 0; e < 8; ++e) s += (float)v[e] * w2b[h * 512 + lane * 8 + e];
  }
#pragma unroll
  for (int off = 32; off; off >>= 1) s += __shfl_xor(s, off);
  if (lane == 0) {
    const int b = r & 63;
    if (r < 16384) tT1[b * L1C + (r >> 6)] = s;
    else           tT2[b * L2C + ((r - 16384) >> 6)] = s;
  }
}

// ---------------- bf16 MLP GEMM, 256x256 tile, 8-wave (r2/r3 proven) ----------
__global__ __launch_bounds__(512, 2)
void mlp_gemm8(const bf16_t* __restrict__ A, const bf16_t* __restrict__ W,
               const float* __restrict__ bias, bf16_t* __restrict__ C,
               int Mtiles, int relu) {
  const int nwg = Mtiles * 4;
  const int cpx = nwg >> 3;
  const int wg  = ((int)blockIdx.x & 7) * cpx + ((int)blockIdx.x >> 3);
  const int mt = wg >> 2, nt = wg & 3;

  __shared__ __align__(16) char lds[131072];

  const int t    = threadIdx.x;
  const int lane = t & 63, wid = t >> 6;
  const int wm = wid >> 2, wn = wid & 3;
  const int rsel = lane & 15, hi = lane >> 4;
  const int t16 = t * 16;

  const int P0 = t16, P1 = 8192 + t16;
  const int Lg0 = P0 ^ ((P0 >> 3) & 0x30);
  const int Lg1 = P1 ^ ((P1 >> 3) & 0x30);
  const int rS0 = Lg0 >> 6, cS0 = (Lg0 & 63) >> 1;
  const int rS1 = Lg1 >> 6, cS1 = (Lg1 & 63) >> 1;
  const bf16_t* pA0 = A + (size_t)(mt * 256 + rS0) * 1024 + cS0;
  const bf16_t* pA1 = A + (size_t)(mt * 256 + rS1) * 1024 + cS1;
  const bf16_t* pB0 = W + (size_t)(nt * 256 + rS0) * 1024 + cS0;
  const bf16_t* pB1 = W + (size_t)(nt * 256 + rS1) * 1024 + cS1;

  const int kchunk = (hi ^ ((rsel >> 1) & 3)) << 4;
  const int offA = ((wm * 128 + rsel) << 6) + kchunk;
  const int offB = 16384 + ((wn * 64 + rsel) << 6) + kchunk;

  f32x4 acc[8][4] = {};
  bf16x8 bfr[4];

#pragma unroll
  for (int p = 0; p < 3; ++p) {
    char* db = lds + p * 32768;
    gload16(pA0 + p * 32, db + t16);
    gload16(pA1 + p * 32, db + 8192 + t16);
    gload16(pB0 + p * 32, db + 16384 + t16);
    gload16(pB1 + p * 32, db + 24576 + t16);
  }
  asm volatile("s_waitcnt vmcnt(8)" ::: "memory");
  __builtin_amdgcn_s_barrier();
  __builtin_amdgcn_sched_barrier(0);

#pragma unroll 1
  for (int tt = 0; tt < 32; ++tt) {
    const char* rb = lds + (tt & 3) * 32768;
    char* sb = lds + ((tt + 3) & 3) * 32768;
    const int ks = (tt + 3) * 32;
    bf16x8 af[4];
#pragma unroll
    for (int m = 0; m < 4; ++m) af[m] = *(const bf16x8*)(rb + offA + m * 1024);
#pragma unroll
    for (int n = 0; n < 4; ++n) bfr[n] = *(const bf16x8*)(rb + offB + n * 1024);
    if (tt < 29) {
      gload16(pA0 + ks, sb + t16);
      gload16(pA1 + ks, sb + 8192 + t16);
    }
    __builtin_amdgcn_s_setprio(1);
#pragma unroll
    for (int m = 0; m < 4; ++m)
#pragma unroll
      for (int n = 0; n < 4; ++n)
        acc[m][n] = __builtin_amdgcn_mfma_f32_16x16x32_bf16(af[m], bfr[n], acc[m][n], 0, 0, 0);
    __builtin_amdgcn_s_setprio(0);
    __builtin_amdgcn_s_barrier();
    __builtin_amdgcn_sched_barrier(0);
#pragma unroll
    for (int m = 0; m < 4; ++m) af[m] = *(const bf16x8*)(rb + offA + (m + 4) * 1024);
    if (tt < 29) {
      gload16(pB0 + ks, sb + 16384 + t16);
      gload16(pB1 + ks, sb + 24576 + t16);
    }
    __builtin_amdgcn_s_setprio(1);
#pragma unroll
    for (int m = 0; m < 4; ++m)
#pragma unroll
      for (int n = 0; n < 4; ++n)
        acc[m + 4][n] = __builtin_amdgcn_mfma_f32_16x16x32_bf16(af[m], bfr[n], acc[m + 4][n], 0, 0, 0);
    __builtin_amdgcn_s_setprio(0);
    if (tt < 29)       asm volatile("s_waitcnt vmcnt(8)" ::: "memory");
    else if (tt == 29) asm volatile("s_waitcnt vmcnt(4)" ::: "memory");
    else if (tt == 30) asm volatile("s_waitcnt vmcnt(0)" ::: "memory");
    __builtin_amdgcn_s_barrier();
    __builtin_amdgcn_sched_barrier(0);
  }

  const int row0 = mt * 256 + wm * 128 + hi * 4;
  const int col0 = nt * 256 + wn * 64 + rsel;
  float bv[4];
#pragma unroll
  for (int n = 0; n < 4; ++n) bv[n] = bias[col0 + n * 16];
#pragma unroll
  for (int m = 0; m < 8; ++m) {
#pragma unroll
    for (int q = 0; q < 4; ++q) {
      const size_t rr = (size_t)(row0 + m * 16 + q) * 1024;
#pragma unroll
      for (int n = 0; n < 4; ++n) {
        float v = acc[m][n][q] + bv[n];
        if (relu) v = fmaxf(v, 0.f);
        C[rr + col0 + n * 16] = (bf16_t)v;
      }
    }
  }
}

// ---------------- pool split-K GEMM: U(256x1024) * W2^T, 8 K-slices ----------
__global__ __launch_bounds__(256)
void pool_gemmK(const bf16_t* __restrict__ A, const bf16_t* __restrict__ W,
                float* __restrict__ P) {
  const int slice = (int)blockIdx.x >> 4;
  const int tl = (int)blockIdx.x & 15;
  const int mt = tl >> 3, nt = tl & 7;
  const int koff = slice * 128;

  const int f = threadIdx.x;
  const int lane = f & 63, w = f >> 6;
  const int sRow = f >> 2, sCol8 = (f & 3) * 8;

  const bf16_t* Ab = A + (size_t)mt * 128 * 1024 + (size_t)sRow * 1024 + sCol8;
  const bf16_t* Bb = W + (size_t)nt * 128 * 1024 + (size_t)sRow * 1024 + sCol8;

  __shared__ __align__(16) bf16_t sA[128 * 32];
  __shared__ __align__(16) bf16_t sB[128 * 32];
  bf16_t* sAp = sA + sRow * 32 + sCol8;
  bf16_t* sBp = sB + sRow * 32 + sCol8;

  const int wr = (w >> 1) * 64, wc = (w & 1) * 64;
  const int rsel = lane & 15, koff2 = (lane >> 4) * 8;
  const bf16_t* rA = sA + (wr + rsel) * 32 + koff2;
  const bf16_t* rB = sB + (wc + rsel) * 32 + koff2;

  f32x4 acc[4][4] = {};
  for (int kt = koff; kt < koff + 128; kt += 32) {
    __syncthreads();
    gload16(Ab + kt,             sAp);
    gload16(Ab + kt + 64 * 1024, sAp + 64 * 32);
    gload16(Bb + kt,             sBp);
    gload16(Bb + kt + 64 * 1024, sBp + 64 * 32);
    asm volatile("s_waitcnt vmcnt(0)" ::: "memory");
    __syncthreads();
    bf16x8 af[4], bfv[4];
#pragma unroll
    for (int m = 0; m < 4; ++m) af[m] = *(const bf16x8*)(rA + m * 16 * 32);
#pragma unroll
    for (int n = 0; n < 4; ++n) bfv[n] = *(const bf16x8*)(rB + n * 16 * 32);
#pragma unroll
    for (int m = 0; m < 4; ++m)
#pragma unroll
      for (int n = 0; n < 4; ++n)
        acc[m][n] = __builtin_amdgcn_mfma_f32_16x16x32_bf16(af[m], bfv[n], acc[m][n], 0, 0, 0);
  }

  float* Pb = P + (size_t)slice * 262144;
  const int row0 = mt * 128 + wr + (lane >> 4) * 4;
  const int col0 = nt * 128 + wc + rsel;
#pragma unroll
  for (int n = 0; n < 4; ++n) {
    const int c = col0 + n * 16;
#pragma unroll
    for (int m = 0; m < 4; ++m) {
      const int r = row0 + m * 16;
#pragma unroll
      for (int q = 0; q < 4; ++q)
        Pb[(size_t)(r + q) * 1024 + c] = acc[m][n][q];
    }
  }
}

// reduce 8 pool partials + bias, remap rows -> d_out
__global__ __launch_bounds__(256)
void pool_reduce(const float* __restrict__ Pp, const float* __restrict__ b2,
                 float* __restrict__ out) {
  const int idx = blockIdx.x * 256 + threadIdx.x;
  const int r = idx >> 10, c = idx & 1023;
  float s = b2[c];
#pragma unroll
  for (int sl = 0; sl < 8; ++sl) s += Pp[(size_t)sl * 262144 + idx];
  const int g = r >> 6, b = r & 63;
  out[(size_t)(g >> 1) * 131072 + (size_t)b * 2048 + (g & 1) * 1024 + c] = s;
}

// ---------------- logits: oz[b,i,j] = z1[b,i,:].h2[b,j,:] ----------------
__global__ __launch_bounds__(256)
void logits_gemm(const bf16_t* __restrict__ Y1, const bf16_t* __restrict__ Y2,
                 float* __restrict__ O) {
  const int wg = ((int)blockIdx.x & 7) * 48 + ((int)blockIdx.x >> 3);
  const int b = wg / 6, t6 = wg % 6;
  const int mt = t6 / 3, nt = t6 % 3;

  __shared__ __align__(16) char lds[65536];    // 4 bufs x (A 8KB + B 8KB)

  const int t = threadIdx.x;
  const int lane = t & 63, w = t >> 6;
  const int sRow = t >> 2;
  const int sCol8 = (((t & 3) ^ ((t >> 3) & 3))) * 8;   // pre-swizzled source chunk
  const int t16 = t * 16;

  const int i0 = mt * 128 + sRow;
  const int i1 = i0 + 64;
  int j0 = nt * 128 + sRow;      if (j0 > L2C - 1) j0 = L2C - 1;
  int j1 = nt * 128 + sRow + 64; if (j1 > L2C - 1) j1 = L2C - 1;
  const bf16_t* A0 = Y1 + ((size_t)i0 * BC + b) * DC + sCol8;
  const bf16_t* A1 = Y1 + ((size_t)i1 * BC + b) * DC + sCol8;
  const bf16_t* B0 = Y2 + ((size_t)j0 * BC + b) * DC + sCol8;
  const bf16_t* B1 = Y2 + ((size_t)j1 * BC + b) * DC + sCol8;

  const int wr = (w >> 1) * 64, wc = (w & 1) * 64;
  const int rsel = lane & 15, hi = lane >> 4;
  const int kchunk = (hi ^ ((rsel >> 1) & 3)) << 4;
  const int offA = ((wr + rsel) << 6) + kchunk;
  const int offB = 8192 + ((wc + rsel) << 6) + kchunk;

  f32x4 acc[4][4] = {};

  // prologue: stage tiles 0..2
#pragma unroll
  for (int p = 0; p < 3; ++p) {
    char* db = lds + p * 16384;
    gload16(A0 + p * 32, db + t16);
    gload16(A1 + p * 32, db + 4096 + t16);
    gload16(B0 + p * 32, db + 8192 + t16);
    gload16(B1 + p * 32, db + 12288 + t16);
  }
  asm volatile("s_waitcnt vmcnt(8)" ::: "memory");
  __builtin_amdgcn_s_barrier();
  __builtin_amdgcn_sched_barrier(0);

#pragma unroll 1
  for (int tt = 0; tt < 32; ++tt) {
    const char* rb = lds + (tt & 3) * 16384;
    char* sb = lds + ((tt + 3) & 3) * 16384;
    const int ks = (tt + 3) * 32;
    bf16x8 af[4], bfv[4];
#pragma unroll
    for (int m = 0; m < 4; ++m) af[m] = *(const bf16x8*)(rb + offA + m * 1024);
#pragma unroll
    for (int n = 0; n < 4; ++n) bfv[n] = *(const bf16x8*)(rb + offB + n * 1024);
    if (tt < 29) {
      gload16(A0 + ks, sb + t16);
      gload16(A1 + ks, sb + 4096 + t16);
      gload16(B0 + ks, sb + 8192 + t16);
      gload16(B1 + ks, sb + 12288 + t16);
    }
    __builtin_amdgcn_s_setprio(1);
#pragma unroll
    for (int m = 0; m < 4; ++m)
#pragma unroll
      for (int n = 0; n < 4; ++n)
        acc[m][n] = __builtin_amdgcn_mfma_f32_16x16x32_bf16(af[m], bfv[n], acc[m][n], 0, 0, 0);
    __builtin_amdgcn_s_setprio(0);
    if (tt < 29)       asm volatile("s_waitcnt vmcnt(8)" ::: "memory");
    else if (tt == 29) asm volatile("s_waitcnt vmcnt(4)" ::: "memory");
    else if (tt == 30) asm volatile("s_waitcnt vmcnt(0)" ::: "memory");
    __builtin_amdgcn_s_barrier();
    __builtin_amdgcn_sched_barrier(0);
  }

  float* Ob = O + (size_t)b * L1C * L2C;
  const int row0 = mt * 128 + wr + hi * 4;
  const int col0 = nt * 128 + wc + rsel;
#pragma unroll
  for (int n = 0; n < 4; ++n) {
    const int c = col0 + n * 16;
    if (c < L2C) {
#pragma unroll
      for (int m = 0; m < 4; ++m) {
        const int r = row0 + m * 16;
#pragma unroll
        for (int q = 0; q < 4; ++q)
          Ob[(size_t)(r + q) * L2C + c] = acc[m][n][q];
      }
    }
  }
}

// ---------------- softmax stats (with rank-1 terms t1,t2) ----------------
__global__ __launch_bounds__(256)
void row_stats(const float* __restrict__ O, const float* __restrict__ tT2,
               float* __restrict__ rowM, float* __restrict__ rowInv) {
  const int gw = blockIdx.x * 4 + (threadIdx.x >> 6);
  const int lane = threadIdx.x & 63;
  const int b = gw >> 8;
  const float* row = O + (size_t)gw * L2C;
  const float* t2 = tT2 + b * L2C;
  float v[5];
  float m = -1e30f;
#pragma unroll
  for (int t = 0; t < 5; ++t) { v[t] = row[t * 64 + lane] + t2[t * 64 + lane]; m = fmaxf(m, v[t]); }
#pragma unroll
  for (int off = 32; off; off >>= 1) m = fmaxf(m, __shfl_xor(m, off));
  float s = 0.f;
#pragma unroll
  for (int t = 0; t < 5; ++t) s += __expf(v[t] - m);
#pragma unroll
  for (int off = 32; off; off >>= 1) s += __shfl_xor(s, off);
  if (lane == 0) { rowM[gw] = m; rowInv[gw] = 1.f / s; }
}

__global__ __launch_bounds__(256)
void col_stats_c1(const float* __restrict__ O, const float* __restrict__ tT1,
                  const float* __restrict__ tT2,
                  const float* __restrict__ rowM, const float* __restrict__ rowInv,
                  float* __restrict__ colM, float* __restrict__ colInv,
                  float* __restrict__ c1) {
  const int b = blockIdx.x / 5, jb = blockIdx.x % 5;
  const int jl = threadIdx.x & 63, ig = threadIdx.x >> 6;
  const int j = jb * 64 + jl;
  const float* Ob = O + (size_t)b * L1C * L2C + j;
  const float* rM = rowM + b * L1C;
  const float* rI = rowInv + b * L1C;
  const float* t1 = tT1 + b * L1C;
  const float t2j = tT2[b * L2C + j];
  float m = -1e30f, s = 0.f, cp = 0.f;
  for (int i = ig; i < L1C; i += 4) {
    float ov = Ob[(size_t)i * L2C];
    float v = ov + t1[i];
    float mn = fmaxf(m, v);
    s = s * __expf(m - mn) + __expf(v - mn);
    m = mn;
    cp += __expf(ov + t2j - rM[i]) * rI[i];
  }
  __shared__ float sm[4][64], ss[4][64], sc[4][64];
  sm[ig][jl] = m; ss[ig][jl] = s; sc[ig][jl] = cp;
  __syncthreads();
  if (ig == 0) {
    for (int g = 1; g < 4; ++g) {
      float mg = sm[g][jl], sg = ss[g][jl];
      float mn = fmaxf(m, mg);
      s = s * __expf(m - mn) + sg * __expf(mg - mn);
      m = mn;
      cp += sc[g][jl];
    }
    colM[b * L2C + j] = m;
    colInv[b * L2C + j] = 1.f / s;
    c1[b * L2C + j] = cp;
  }
}

__global__ __launch_bounds__(256)
void c2_kernel(const float* __restrict__ O, const float* __restrict__ tT1,
               const float* __restrict__ colM, const float* __restrict__ colInv,
               float* __restrict__ c2) {
  const int gw = blockIdx.x * 4 + (threadIdx.x >> 6);
  const int lane = threadIdx.x & 63;
  const int b = gw >> 8;
  const float* row = O + (size_t)gw * L2C;
  const float* cM = colM + b * L2C;
  const float* cI = colInv + b * L2C;
  const float t1i = tT1[b * L1C + (gw & 255)];
  float s = 0.f;
#pragma unroll
  for (int t = 0; t < 5; ++t) {
    const int j = t * 64 + lane;
    s += __expf(row[j] + t1i - cM[j]) * cI[j];
  }
#pragma unroll
  for (int off = 32; off; off >>= 1) s += __shfl_xor(s, off);
  if (lane == 0) c2[gw] = s;
}

// ---------------- weighted h-sums -> U (256x1024 bf16) ----------------
__global__ __launch_bounds__(256)
void u_kernel(const bf16_t* __restrict__ H, const float* __restrict__ c1,
              const float* __restrict__ c2, bf16_t* __restrict__ Ub) {
  const int b = blockIdx.x >> 2;
  const int d = (blockIdx.x & 3) * 256 + threadIdx.x;
  const bf16_t* H2 = H + (size_t)L1C * BC * DC;
  float s1 = 0.f, s1c = 0.f, s2 = 0.f, s2c = 0.f;
  const float* c2b = c2 + b * L1C;
  for (int i = 0; i < L1C; ++i) {
    float v = (float)H[((size_t)i * BC + b) * DC + d];
    s1 += v; s1c += c2b[i] * v;
  }
  const float* c1b = c1 + b * L2C;
  for (int j = 0; j < L2C; ++j) {
    float v = (float)H2[((size_t)j * BC + b) * DC + d];
    s2 += v; s2c += c1b[j] * v;
  }
  Ub[(size_t)(0 * 64 + b) * 1024 + d] = (bf16_t)(s1  * (1.f / L1C));
  Ub[(size_t)(1 * 64 + b) * 1024 + d] = (bf16_t)(s2c * (1.f / L1C));
  Ub[(size_t)(2 * 64 + b) * 1024 + d] = (bf16_t)(s2  * (1.f / L2C));
  Ub[(size_t)(3 * 64 + b) * 1024 + d] = (bf16_t)(s1c * (1.f / L2C));
}

// ---------------- host ----------------
extern "C" void kernel_launch(void* const* d_in, const int* in_sizes, int n_in,
                              void* d_out, int out_size, void* d_ws, size_t ws_size,
                              hipStream_t stream) {
  const float* r1 = (const float*)d_in[0];
  const float* r2 = (const float*)d_in[1];
  const float* W1 = (const float*)d_in[2];
  const float* b1 = (const float*)d_in[3];
  const float* W2 = (const float*)d_in[4];
  const float* b2 = (const float*)d_in[5];
  float* out = (float*)d_out;
  char* ws = (char*)d_ws;

  const size_t M1 = (size_t)L1C * BC;   // 16384
  const size_t M2 = (size_t)L2C * BC;   // 20480
  const size_t Mt = M1 + M2;            // 36864

  size_t off = 0;
  bf16_t* XB  = (bf16_t*)(ws + off); off += Mt * DC * 2;        // 72MB: A-bf16, then Z + O
  bf16_t* HB  = (bf16_t*)(ws + off); off += Mt * DC * 2;        // 72MB, h; head reused as Ppart
  bf16_t* WB1 = (bf16_t*)(ws + off); off += (size_t)DC * DC * 2;
  bf16_t* WB2 = (bf16_t*)(ws + off); off += (size_t)DC * DC * 2;
  bf16_t* W2T = (bf16_t*)(ws + off); off += (size_t)DC * DC * 2;
  bf16_t* GB  = (bf16_t*)(ws + off); off += (size_t)DC * DC * 2;
  float* w2b   = (float*)(ws + off); off += 4096;
  float* zb    = (float*)(ws + off); off += 4096;
  float* tT1   = (float*)(ws + off); off += BC * L1C * 4;
  float* tT2   = (float*)(ws + off); off += BC * L2C * 4;
  float* rowM  = (float*)(ws + off); off += BC * L1C * 4;
  float* rowIv = (float*)(ws + off); off += BC * L1C * 4;
  float* colM  = (float*)(ws + off); off += BC * L2C * 4;
  float* colIv = (float*)(ws + off); off += BC * L2C * 4;
  float* c1v   = (float*)(ws + off); off += BC * L2C * 4;
  float* c2v   = (float*)(ws + off); off += BC * L1C * 4;
  bf16_t* Ub   = (bf16_t*)(ws + off); off += 256 * DC * 2;

  bf16_t* Z = XB;                                   // 16384x1024 bf16 (32MB)
  float*  O = (float*)((char*)XB + 35651584);       // 21MB logits
  float*  Ppart = (float*)HB;                       // 8MB (8 slices), HB dead then
  bf16_t* H2 = HB + M1 * DC;

  // 1. fused prep (converts + W2T + w2b + zb)
  prep_kernel<<<10817, 256, 0, stream>>>(r1, r2, XB, W1, WB1, W2, WB2, W2T,
                                         b2, w2b, zb);

  // 2. fused: G = W2T.W2T^T (blocks 0..63) + h = relu(x W1^T + b1) (rest)
  g1g_kernel<<<2368, 256, 0, stream>>>(XB, WB1, b1, HB, W2T, GB);

  // 3. t = h . (W2^T b2)
  t_kernel<<<9216, 256, 0, stream>>>(HB, w2b, tT1, tT2);

  // 4. z1 = h1 G
  mlp_gemm8<<<256, 512, 0, stream>>>(HB, GB, zb, Z, 64, 0);

  // 5. oz[b,i,j] = z1 . h2
  logits_gemm<<<384, 256, 0, stream>>>(Z, H2, O);

  // 6. softmax stats with rank-1 corrections
  row_stats<<<4096, 256, 0, stream>>>(O, tT2, rowM, rowIv);
  col_stats_c1<<<320, 256, 0, stream>>>(O, tT1, tT2, rowM, rowIv, colM, colIv, c1v);
  c2_kernel<<<4096, 256, 0, stream>>>(O, tT1, colM, colIv, c2v);

  // 7. weighted h pools -> U;  out = U W2^T + b2, split-K + reduce
  u_kernel<<<256, 256, 0, stream>>>(HB, c1v, c2v, Ub);
  pool_gemmK<<<128, 256, 0, stream>>>(Ub, WB2, Ppart);
  pool_reduce<<<1024, 256, 0, stream>>>(Ppart, b2, out);
}